// Round 17
// baseline (1338.503 us; speedup 1.0000x reference)
//
#include <hip/hip_runtime.h>
#include <cstddef>

// SchNet fwd energy + force bwd, MI355X. Round 26: R16 verified base (1329us)
// + (1) first barrier eliminated in both edge kernels (phase-1 reads De
// directly -- 2 distinct broadcast values per wave; sD filled concurrently,
// existing post-phase-1 barrier covers it); (2) conditional H-save: fwd writes
// per-layer H to Hsv when ws_size has +3*NFE slack, bwd skips the bit-identical
// H recompute gemms (fallback = verified recompute path).

#define FD     128
#define NRBF   20
#define CUTF   5.0f
#define PI_F   3.14159265358979f
#define PW     136    // u16 pitch for sP/sWf/sA
#define WLSZ   40960  // u16 per layer in edge-weight workspace
#define W2LSZ  98304  // u16 per layer in dense-weight workspace (6 x 16384)
#define APM    32     // atoms per molecule

typedef unsigned short u16;
typedef unsigned int   u32;
typedef __attribute__((ext_vector_type(8))) short bf16x8;
typedef __attribute__((ext_vector_type(4))) float f32x4;

__device__ __forceinline__ float u16f(u16 x){ union{u32 i; float f;} v; v.i=((u32)x)<<16; return v.f; }
// Manual RNE bf16 rounding -- VERIFIED. Do NOT replace with inline-asm
// v_cvt_pk_bf16_f32: R10 isolated A/B proved that path numerically wrong here.
__device__ __forceinline__ u16 f16r(float f){ union{float f; u32 i;} v; v.f=f; u32 r=v.i+0x7fffu+((v.i>>16)&1u); return (u16)(r>>16); }
__device__ __forceinline__ float sspf(float x){
  return fmaxf(x,0.f) + __logf(1.f + __expf(-fabsf(x))) - 0.6931471805599453f;
}
__device__ __forceinline__ float sigf(float x){
  return __fdividef(1.f, 1.f + __expf(-x));
}
__device__ __forceinline__ float fcutf(float d){ return (d < CUTF) ? 0.5f*(__cosf(PI_F*d/CUTF)+1.f) : 0.f; }

__global__ __launch_bounds__(256) void k_zero(float* __restrict__ p, int n){
  int i = blockIdx.x*256 + threadIdx.x;
  if(i < n) p[i] = 0.f;
}

__global__ __launch_bounds__(256) void k_embed(const float* __restrict__ emb, const int* __restrict__ Z,
                                               float* __restrict__ X0, int n){
  int idx = blockIdx.x*256 + threadIdx.x;
  if(idx >= n) return;
  int a = idx >> 7, f = idx & 127;
  X0[idx] = emb[Z[a]*FD + f];
}

__global__ __launch_bounds__(256) void k_edge_geom(const float* __restrict__ pos,
    const int* __restrict__ Ii, const int* __restrict__ Ij,
    float* __restrict__ De, float* __restrict__ DBe, int E){
  int e = blockIdx.x*256 + threadIdx.x;
  if(e >= E) return;
  int i = Ii[e], j = Ij[e];
  float dx = pos[j*3+0]-pos[i*3+0];
  float dy = pos[j*3+1]-pos[i*3+1];
  float dz = pos[j*3+2]-pos[i*3+2];
  De[e] = sqrtf(dx*dx+dy*dy+dz*dz + 1e-12f);
  DBe[e] = 0.f;
}

// Edge-filter bf16 weight pre-conversion (once per launch).
__global__ __launch_bounds__(256) void k_prep(const float* __restrict__ fW1,
    const float* __restrict__ fW2, u16* __restrict__ WB){
  int idx = blockIdx.x*256 + threadIdx.x;
  if(idx >= 3*WLSZ) return;
  int l = idx / WLSZ, r = idx - l*WLSZ;
  const float* W1 = fW1 + l*2560;
  const float* W2 = fW2 + l*16384;
  u16* out = WB + l*WLSZ;
  if(r < 4096){
    int c = r >> 5, k = r & 31;
    out[r] = (k < NRBF) ? f16r(W1[k*128 + c]) : (u16)0;
  } else if(r < 8192){
    int rr = r - 4096;
    int k = rr >> 7, c = rr & 127;
    out[r] = (k < NRBF) ? f16r(W1[k*128 + c]) : (u16)0;
  } else if(r < 24576){
    out[r] = f16r(W2[r - 8192]);
  } else {
    int rr = r - 24576;
    int f = rr >> 7, c = rr & 127;
    out[r] = f16r(W2[c*128 + f]);
  }
}

// Dense-layer bf16 weight pre-conversion: per layer, 6 matrices of [n][k]:
//   0: in2f^T  1: in2f  2: oW1^T  3: oW1  4: oW2^T  5: oW2
__global__ __launch_bounds__(256) void k_prep2(const float* __restrict__ in2f,
    const float* __restrict__ oW1, const float* __restrict__ oW2,
    u16* __restrict__ WB2){
  int idx = blockIdx.x*256 + threadIdx.x;
  if(idx >= 3*W2LSZ) return;
  int l = idx / W2LSZ, r = idx - l*W2LSZ;
  int mat = r >> 14, q = r & 16383;
  int n = q >> 7, k = q & 127;
  const float* src = (mat < 2) ? (in2f + l*16384) : (mat < 4) ? (oW1 + l*16384) : (oW2 + l*16384);
  float v = (mat & 1) ? src[n*128 + k] : src[k*128 + n];
  WB2[idx] = f16r(v);
}

// Dense GEMM via bf16 MFMA (verified R9/R15).
__global__ __launch_bounds__(256) void k_gemmb(const float* __restrict__ A,
    const u16* __restrict__ Bn, const float* __restrict__ bias,
    const float* __restrict__ res, const float* __restrict__ mul,
    float* __restrict__ out1, float* __restrict__ out2, int act, int Nr){
  __shared__ u16 sA[32*PW];
  const int tid = threadIdx.x;
  const int rb = blockIdx.x * 32;
  #pragma unroll
  for(int q=0;q<4;q++){
    int e = q*256 + tid;
    int r = e >> 5, c4 = (e & 31)*4;
    int rr = rb + r; if(rr >= Nr) rr = Nr-1;
    float4 v = *(const float4*)(A + (size_t)rr*FD + c4);
    sA[r*PW + c4+0] = f16r(v.x);
    sA[r*PW + c4+1] = f16r(v.y);
    sA[r*PW + c4+2] = f16r(v.z);
    sA[r*PW + c4+3] = f16r(v.w);
  }
  __syncthreads();
  const int w = tid >> 6, lane = tid & 63;
  const int quad = lane >> 4, l16 = lane & 15;
  f32x4 acc[2][2];
  #pragma unroll
  for(int mm=0;mm<2;mm++){ acc[mm][0]=(f32x4){0,0,0,0}; acc[mm][1]=(f32x4){0,0,0,0}; }
  __builtin_amdgcn_s_setprio(1);
  #pragma unroll
  for(int ks=0;ks<4;ks++){
    bf16x8 va[2], vb[2];
    #pragma unroll
    for(int mm=0;mm<2;mm++)
      va[mm] = *(const bf16x8*)&sA[(mm*16+l16)*PW + ks*32 + quad*8];
    #pragma unroll
    for(int p=0;p<2;p++)
      vb[p] = *(const bf16x8*)(Bn + ((2*w+p)*16+l16)*128 + ks*32 + quad*8);
    #pragma unroll
    for(int mm=0;mm<2;mm++)
      #pragma unroll
      for(int p=0;p<2;p++)
        acc[mm][p] = __builtin_amdgcn_mfma_f32_16x16x32_bf16(va[mm], vb[p], acc[mm][p], 0,0,0);
  }
  __builtin_amdgcn_s_setprio(0);
  #pragma unroll
  for(int mm=0;mm<2;mm++)
    #pragma unroll
    for(int p=0;p<2;p++){
      const int f = (2*w+p)*16 + l16;
      float bb = bias ? bias[f] : 0.f;
      #pragma unroll
      for(int r=0;r<4;r++){
        int row = rb + mm*16 + quad*4 + r;
        if(row >= Nr) continue;
        size_t o = (size_t)row*FD + f;
        float y = acc[mm][p][r] + bb;
        if(res) y += res[o];
        if(mul) y *= mul[o];
        if(act){ out1[o] = sspf(y); out2[o] = sigf(y); }
        else out1[o] = y;
      }
    }
}

// Fused dependent-GEMM pair (verified R16).
__global__ __launch_bounds__(256) void k_gemmf(const float* __restrict__ A,
    const u16* __restrict__ B1n, const float* __restrict__ b1,
    const u16* __restrict__ B2n, const float* __restrict__ b2,
    const float* __restrict__ res, const float* __restrict__ mulSV,
    float* __restrict__ out1, float* __restrict__ outSV, int mode, int Nr){
  __shared__ u16 sA[32*PW];
  __shared__ u16 sB[32*PW];
  const int tid = threadIdx.x;
  const int rb = blockIdx.x * 32;
  #pragma unroll
  for(int q=0;q<4;q++){
    int e = q*256 + tid;
    int r = e >> 5, c4 = (e & 31)*4;
    int rr = rb + r; if(rr >= Nr) rr = Nr-1;
    float4 v = *(const float4*)(A + (size_t)rr*FD + c4);
    sA[r*PW + c4+0] = f16r(v.x);
    sA[r*PW + c4+1] = f16r(v.y);
    sA[r*PW + c4+2] = f16r(v.z);
    sA[r*PW + c4+3] = f16r(v.w);
  }
  __syncthreads();
  const int w = tid >> 6, lane = tid & 63;
  const int quad = lane >> 4, l16 = lane & 15;
  { // GEMM1
    f32x4 acc[2][2];
    #pragma unroll
    for(int mm=0;mm<2;mm++){ acc[mm][0]=(f32x4){0,0,0,0}; acc[mm][1]=(f32x4){0,0,0,0}; }
    __builtin_amdgcn_s_setprio(1);
    #pragma unroll
    for(int ks=0;ks<4;ks++){
      bf16x8 va[2], vb[2];
      #pragma unroll
      for(int mm=0;mm<2;mm++)
        va[mm] = *(const bf16x8*)&sA[(mm*16+l16)*PW + ks*32 + quad*8];
      #pragma unroll
      for(int p=0;p<2;p++)
        vb[p] = *(const bf16x8*)(B1n + ((2*w+p)*16+l16)*128 + ks*32 + quad*8);
      #pragma unroll
      for(int mm=0;mm<2;mm++)
        #pragma unroll
        for(int p=0;p<2;p++)
          acc[mm][p] = __builtin_amdgcn_mfma_f32_16x16x32_bf16(va[mm], vb[p], acc[mm][p], 0,0,0);
    }
    __builtin_amdgcn_s_setprio(0);
    #pragma unroll
    for(int mm=0;mm<2;mm++)
      #pragma unroll
      for(int p=0;p<2;p++){
        const int f = (2*w+p)*16 + l16;
        float bb = (mode && b1) ? b1[f] : 0.f;
        #pragma unroll
        for(int r=0;r<4;r++){
          const int lrow = mm*16 + quad*4 + r;
          int row = rb + lrow;
          if(row >= Nr) row = Nr-1;
          size_t o = (size_t)row*FD + f;
          float y = acc[mm][p][r] + bb;
          float t;
          if(mode){
            t = sspf(y);
            if(rb + lrow < Nr) outSV[o] = sigf(y);
          } else {
            t = y * mulSV[o];
          }
          sB[lrow*PW + f] = f16r(t);
        }
      }
  }
  __syncthreads();
  { // GEMM2
    f32x4 acc[2][2];
    #pragma unroll
    for(int mm=0;mm<2;mm++){ acc[mm][0]=(f32x4){0,0,0,0}; acc[mm][1]=(f32x4){0,0,0,0}; }
    __builtin_amdgcn_s_setprio(1);
    #pragma unroll
    for(int ks=0;ks<4;ks++){
      bf16x8 va[2], vb[2];
      #pragma unroll
      for(int mm=0;mm<2;mm++)
        va[mm] = *(const bf16x8*)&sB[(mm*16+l16)*PW + ks*32 + quad*8];
      #pragma unroll
      for(int p=0;p<2;p++)
        vb[p] = *(const bf16x8*)(B2n + ((2*w+p)*16+l16)*128 + ks*32 + quad*8);
      #pragma unroll
      for(int mm=0;mm<2;mm++)
        #pragma unroll
        for(int p=0;p<2;p++)
          acc[mm][p] = __builtin_amdgcn_mfma_f32_16x16x32_bf16(va[mm], vb[p], acc[mm][p], 0,0,0);
    }
    __builtin_amdgcn_s_setprio(0);
    #pragma unroll
    for(int mm=0;mm<2;mm++)
      #pragma unroll
      for(int p=0;p<2;p++){
        const int f = (2*w+p)*16 + l16;
        float bb = (mode && b2) ? b2[f] : 0.f;
        #pragma unroll
        for(int r=0;r<4;r++){
          int row = rb + mm*16 + quad*4 + r;
          if(row >= Nr) continue;
          size_t o = (size_t)row*FD + f;
          float y = acc[mm][p][r] + bb;
          if(res) y += res[o];
          out1[o] = y;
        }
      }
  }
}

// ---- Edge forward v12: first barrier removed (De direct in phase 1) ----
__global__ __launch_bounds__(256) void k_edge_fwd12(
    const float* __restrict__ h,
    const float* __restrict__ De,
    const u16* __restrict__ W1t, const float* __restrict__ b1,
    const u16* __restrict__ W2t, const float* __restrict__ b2,
    float* __restrict__ agg, int EPM){
  __shared__ u16 srbfb[32*32];
  __shared__ u16 sP [32*PW];
  __shared__ u16 sWf[32*PW];
  __shared__ float sD[32];
  __shared__ float sRed[4*128];
  const int tid = threadIdx.x;
  const int nb = gridDim.x;
  const int P = ((nb & 7) == 0) ? ((blockIdx.x & 7)*(nb >> 3) + (blockIdx.x >> 3)) : blockIdx.x;
  const int m = P >> 5, a = P & 31;
  const int a0 = m*APM;
  const int eb = m*EPM + a*(APM-1);
  const float step = CUTF/19.0f;
  const float coef = -0.5f/(step*step);
  if(tid < 32) sD[tid] = (tid < APM-1) ? De[eb + tid] : (CUTF + 1.f);
  { // phase 1: rbf fill from De directly (2 broadcast values per wave)
    #pragma unroll
    for(int q=0;q<4;q++){
      int idx = q*256 + tid;
      int lt = idx >> 5, k = idx & 31;
      float d = (lt < APM-1) ? De[eb + lt] : (CUTF + 1.f);
      float x = d - step*(float)k;
      srbfb[idx] = (k < NRBF) ? f16r(__expf(coef*x*x)) : (u16)0;
    }
  }
  __syncthreads();   // covers sD + srbfb
  const int w = tid >> 6, lane = tid & 63;
  const int quad = lane >> 4, l16 = lane & 15;
  { // phase 2: P = ssp(rbf @ W1 + b1)
    f32x4 acc[2][2];
    #pragma unroll
    for(int mm=0;mm<2;mm++){ acc[mm][0]=(f32x4){0,0,0,0}; acc[mm][1]=(f32x4){0,0,0,0}; }
    bf16x8 va[2], vb[2];
    #pragma unroll
    for(int mm=0;mm<2;mm++)
      va[mm] = *(const bf16x8*)&srbfb[(mm*16+l16)*32 + quad*8];
    #pragma unroll
    for(int p=0;p<2;p++)
      vb[p] = *(const bf16x8*)(W1t + ((2*w+p)*16+l16)*32 + quad*8);
    #pragma unroll
    for(int mm=0;mm<2;mm++)
      #pragma unroll
      for(int p=0;p<2;p++)
        acc[mm][p] = __builtin_amdgcn_mfma_f32_16x16x32_bf16(va[mm], vb[p], acc[mm][p], 0,0,0);
    #pragma unroll
    for(int mm=0;mm<2;mm++)
      #pragma unroll
      for(int p=0;p<2;p++){
        const int c = (2*w+p)*16 + l16;
        float bb = b1[c];
        #pragma unroll
        for(int r=0;r<4;r++)
          sP[(mm*16+quad*4+r)*PW + c] = f16r(sspf(acc[mm][p][r] + bb));
      }
  }
  __syncthreads();
  { // phase 3: Wf = P@W2 + b2
    f32x4 acc[2][2];
    #pragma unroll
    for(int mm=0;mm<2;mm++){ acc[mm][0]=(f32x4){0,0,0,0}; acc[mm][1]=(f32x4){0,0,0,0}; }
    __builtin_amdgcn_s_setprio(1);
    #pragma unroll
    for(int ks=0;ks<4;ks++){
      bf16x8 va[2], vb[2];
      #pragma unroll
      for(int mm=0;mm<2;mm++)
        va[mm] = *(const bf16x8*)&sP[(mm*16+l16)*PW + ks*32 + quad*8];
      #pragma unroll
      for(int p=0;p<2;p++)
        vb[p] = *(const bf16x8*)(W2t + ((2*w+p)*16+l16)*128 + ks*32 + quad*8);
      #pragma unroll
      for(int mm=0;mm<2;mm++)
        #pragma unroll
        for(int p=0;p<2;p++)
          acc[mm][p] = __builtin_amdgcn_mfma_f32_16x16x32_bf16(va[mm], vb[p], acc[mm][p], 0,0,0);
    }
    __builtin_amdgcn_s_setprio(0);
    #pragma unroll
    for(int mm=0;mm<2;mm++)
      #pragma unroll
      for(int p=0;p<2;p++){
        const int f = (2*w+p)*16 + l16;
        float bb = b2[f];
        #pragma unroll
        for(int r=0;r<4;r++)
          sWf[(mm*16+quad*4+r)*PW + f] = f16r(acc[mm][p][r] + bb);
      }
  }
  __syncthreads();
  { // phase 4: hoisted loads
    float h0v[8], h1v[8], w0v[8], w1v[8], fcv[8];
    #pragma unroll
    for(int s=0;s<8;s++){
      int lt = w*8 + s;
      int j = (lt < APM-1) ? (lt + (lt >= a ? 1 : 0)) : 0;
      fcv[s] = fcutf(sD[lt]);
      const float* hr = h + (size_t)(a0 + j)*FD;
      h0v[s] = hr[lane];
      h1v[s] = hr[lane + 64];
      w0v[s] = u16f(sWf[lt*PW + lane]);
      w1v[s] = u16f(sWf[lt*PW + lane + 64]);
    }
    float r0 = 0.f, r1 = 0.f;
    #pragma unroll
    for(int s=0;s<8;s++){
      r0 += h0v[s] * w0v[s] * fcv[s];
      r1 += h1v[s] * w1v[s] * fcv[s];
    }
    sRed[w*128 + lane]      = r0;
    sRed[w*128 + lane + 64] = r1;
  }
  __syncthreads();
  if(tid < 128){
    float v = sRed[tid] + sRed[128+tid] + sRed[256+tid] + sRed[384+tid];
    agg[(size_t)(a0+a)*FD + tid] = v;
  }
}

// ---- Edge backward v13: first barrier removed + R16 bwd12 structure ----
__global__ __launch_bounds__(256) void k_edge_bwd13(
    const float* __restrict__ h, const float* __restrict__ AB,
    const float* __restrict__ De,
    const u16* __restrict__ W1t, const float* __restrict__ b1,
    const u16* __restrict__ W1b, const u16* __restrict__ W2r,
    const u16* __restrict__ W2t, const float* __restrict__ b2,
    float* __restrict__ DBe, float* __restrict__ HB, int EPM){
  __shared__ u16 srbfb[32*32];
  __shared__ u16 sP [32*PW];
  __shared__ u16 sWf[32*PW];
  __shared__ float sD[32];
  __shared__ float sRed[4*128];
  __shared__ float sdb[32*2];
  __shared__ float sfb[32];
  const int tid = threadIdx.x;
  const int nb = gridDim.x;
  const int P = ((nb & 7) == 0) ? ((blockIdx.x & 7)*(nb >> 3) + (blockIdx.x >> 3)) : blockIdx.x;
  const int m = P >> 5, a = P & 31;
  const int a0 = m*APM;
  const int eb = m*EPM + a*(APM-1);
  const float step = CUTF/19.0f;
  const float coef = -0.5f/(step*step);
  if(tid < 32) sD[tid] = (tid < APM-1) ? De[eb + tid] : (CUTF + 1.f);
  { // phase 1: rbf fill from De directly
    #pragma unroll
    for(int q=0;q<4;q++){
      int idx = q*256 + tid;
      int lt = idx >> 5, k = idx & 31;
      float d = (lt < APM-1) ? De[eb + lt] : (CUTF + 1.f);
      float x = d - step*(float)k;
      srbfb[idx] = (k < NRBF) ? f16r(__expf(coef*x*x)) : (u16)0;
    }
  }
  __syncthreads();   // covers sD + srbfb
  const int w = tid >> 6, lane = tid & 63;
  const int quad = lane >> 4, l16 = lane & 15;
  { // phase 2
    f32x4 acc[2][2];
    #pragma unroll
    for(int mm=0;mm<2;mm++){ acc[mm][0]=(f32x4){0,0,0,0}; acc[mm][1]=(f32x4){0,0,0,0}; }
    bf16x8 va[2], vb[2];
    #pragma unroll
    for(int mm=0;mm<2;mm++)
      va[mm] = *(const bf16x8*)&srbfb[(mm*16+l16)*32 + quad*8];
    #pragma unroll
    for(int p=0;p<2;p++)
      vb[p] = *(const bf16x8*)(W1t + ((2*w+p)*16+l16)*32 + quad*8);
    #pragma unroll
    for(int mm=0;mm<2;mm++)
      #pragma unroll
      for(int p=0;p<2;p++)
        acc[mm][p] = __builtin_amdgcn_mfma_f32_16x16x32_bf16(va[mm], vb[p], acc[mm][p], 0,0,0);
    #pragma unroll
    for(int mm=0;mm<2;mm++)
      #pragma unroll
      for(int p=0;p<2;p++){
        const int c = (2*w+p)*16 + l16;
        float bb = b1[c];
        #pragma unroll
        for(int r=0;r<4;r++)
          sP[(mm*16+quad*4+r)*PW + c] = f16r(sspf(acc[mm][p][r] + bb));
      }
  }
  __syncthreads();
  { // phase 3
    f32x4 acc[2][2];
    #pragma unroll
    for(int mm=0;mm<2;mm++){ acc[mm][0]=(f32x4){0,0,0,0}; acc[mm][1]=(f32x4){0,0,0,0}; }
    __builtin_amdgcn_s_setprio(1);
    #pragma unroll
    for(int ks=0;ks<4;ks++){
      bf16x8 va[2], vb[2];
      #pragma unroll
      for(int mm=0;mm<2;mm++)
        va[mm] = *(const bf16x8*)&sP[(mm*16+l16)*PW + ks*32 + quad*8];
      #pragma unroll
      for(int p=0;p<2;p++)
        vb[p] = *(const bf16x8*)(W2t + ((2*w+p)*16+l16)*128 + ks*32 + quad*8);
      #pragma unroll
      for(int mm=0;mm<2;mm++)
        #pragma unroll
        for(int p=0;p<2;p++)
          acc[mm][p] = __builtin_amdgcn_mfma_f32_16x16x32_bf16(va[mm], vb[p], acc[mm][p], 0,0,0);
    }
    __builtin_amdgcn_s_setprio(0);
    #pragma unroll
    for(int mm=0;mm<2;mm++)
      #pragma unroll
      for(int p=0;p<2;p++){
        const int f = (2*w+p)*16 + l16;
        float bb = b2[f];
        #pragma unroll
        for(int r=0;r<4;r++)
          sWf[(mm*16+quad*4+r)*PW + f] = f16r(acc[mm][p][r] + bb);
      }
  }
  __syncthreads();
  { // phase 4: hoisted loads, batched butterfly
    float ab0 = AB[(size_t)(a0+a)*FD + lane];
    float ab1 = AB[(size_t)(a0+a)*FD + lane + 64];
    float h0v[8], h1v[8], a0v[8], a1v[8], w0v[8], w1v[8], fcv[8];
    #pragma unroll
    for(int s=0;s<8;s++){
      int lt = w*8 + s;
      int j = (lt < APM-1) ? (lt + (lt >= a ? 1 : 0)) : 0;
      fcv[s] = fcutf(sD[lt]);
      const float* hr  = h  + (size_t)(a0 + j)*FD;
      const float* abr = AB + (size_t)(a0 + j)*FD;
      h0v[s] = hr[lane];
      h1v[s] = hr[lane + 64];
      a0v[s] = abr[lane];
      a1v[s] = abr[lane + 64];
      w0v[s] = u16f(sWf[lt*PW + lane]);
      w1v[s] = u16f(sWf[lt*PW + lane + 64]);
    }
    float r0 = 0.f, r1 = 0.f;
    float pfv[8];
    #pragma unroll
    for(int s=0;s<8;s++){
      int lt = w*8 + s;
      float fc = fcv[s];
      r0 += a0v[s] * w0v[s] * fc;
      r1 += a1v[s] * w1v[s] * fc;
      float g0 = ab0*h0v[s], g1 = ab1*h1v[s];
      sWf[lt*PW + lane]      = f16r(g0*fc);
      sWf[lt*PW + lane + 64] = f16r(g1*fc);
      pfv[s] = g0*w0v[s] + g1*w1v[s];
    }
    #pragma unroll
    for(int d2=1; d2<64; d2<<=1){
      #pragma unroll
      for(int s=0;s<8;s++) pfv[s] += __shfl_xor(pfv[s], d2);
    }
    if(lane == 0){
      #pragma unroll
      for(int s=0;s<8;s++) sfb[w*8 + s] = pfv[s];
    }
    sRed[w*128 + lane]      = r0;
    sRed[w*128 + lane + 64] = r1;
  }
  __syncthreads();
  if(tid < 128){
    float v = sRed[tid] + sRed[128+tid] + sRed[256+tid] + sRed[384+tid];
    HB[(size_t)(a0+a)*FD + tid] = v;
  }
  { // phase 5+6 merged: GEMM2; sigma-trick; tbar -> sP (thread-local RMW)
    f32x4 acc[2][2];
    #pragma unroll
    for(int mm=0;mm<2;mm++){ acc[mm][0]=(f32x4){0,0,0,0}; acc[mm][1]=(f32x4){0,0,0,0}; }
    __builtin_amdgcn_s_setprio(1);
    #pragma unroll
    for(int ks=0;ks<4;ks++){
      bf16x8 va[2], vb[2];
      #pragma unroll
      for(int mm=0;mm<2;mm++)
        va[mm] = *(const bf16x8*)&sWf[(mm*16+l16)*PW + ks*32 + quad*8];
      #pragma unroll
      for(int p=0;p<2;p++)
        vb[p] = *(const bf16x8*)(W2r + ((2*w+p)*16+l16)*128 + ks*32 + quad*8);
      #pragma unroll
      for(int mm=0;mm<2;mm++)
        #pragma unroll
        for(int p=0;p<2;p++)
          acc[mm][p] = __builtin_amdgcn_mfma_f32_16x16x32_bf16(va[mm], vb[p], acc[mm][p], 0,0,0);
    }
    __builtin_amdgcn_s_setprio(0);
    #pragma unroll
    for(int mm=0;mm<2;mm++)
      #pragma unroll
      for(int p=0;p<2;p++){
        const int c = (2*w+p)*16 + l16;
        #pragma unroll
        for(int r=0;r<4;r++){
          const int row = mm*16 + quad*4 + r;
          float Pv = u16f(sP[row*PW + c]);
          float sig = 1.0f - 0.5f*__expf(-Pv);
          sP[row*PW + c] = f16r(acc[mm][p][r] * sig);
        }
      }
  }
  __syncthreads();
  { // phase 7: GEMM3 (A from sP); dbar partials, rbf recomputed
    const int m3 = w >> 1, p3 = w & 1;
    f32x4 acc = (f32x4){0,0,0,0};
    #pragma unroll
    for(int ks=0;ks<4;ks++){
      bf16x8 va = *(const bf16x8*)&sP[(m3*16+l16)*PW + ks*32 + quad*8];
      bf16x8 vb = *(const bf16x8*)(W1b + (p3*16+l16)*128 + ks*32 + quad*8);
      acc = __builtin_amdgcn_mfma_f32_16x16x32_bf16(va, vb, acc, 0,0,0);
    }
    const int kr = p3*16 + l16;
    float s0[4];
    #pragma unroll
    for(int r=0;r<4;r++){
      int lt = m3*16 + quad*4 + r;
      float v = 0.f;
      if(kr < NRBF){
        float x = sD[lt] - step*(float)kr;
        float rb = __expf(coef*x*x);
        v = acc[r] * rb * (2.f*coef*x);
      }
      s0[r] = v;
    }
    #pragma unroll
    for(int d2=1; d2<16; d2<<=1){
      #pragma unroll
      for(int r=0;r<4;r++) s0[r] += __shfl_xor(s0[r], d2);
    }
    if(l16 == 0){
      #pragma unroll
      for(int r=0;r<4;r++) sdb[(m3*16+quad*4+r)*2 + p3] = s0[r];
    }
  }
  __syncthreads();
  if(tid < APM-1){ // phase 8: DBe writeback
    const float d = sD[tid];
    float dfc = (d < CUTF) ? (-0.5f*(PI_F/CUTF)*__sinf(PI_F*d/CUTF)) : 0.f;
    DBe[eb + tid] += sdb[tid*2+0] + sdb[tid*2+1] + sfb[tid]*dfc;
  }
}

// fused atomwise head + head-backward (unchanged, verified)
__global__ __launch_bounds__(256) void k_head(const float* __restrict__ X3,
    const float* __restrict__ aW1, const float* __restrict__ ab1,
    const float* __restrict__ aW2, const float* __restrict__ ab2,
    const int* __restrict__ mol, float* __restrict__ Emol, float* __restrict__ XB, int N){
  __shared__ float sx[64*129];
  __shared__ float sg[64*65];
  const int tid = threadIdx.x;
  const int base = blockIdx.x*64;
  for(int q=0;q<8;q++){
    int ee = q*256 + tid;
    int r = ee >> 5, c = (ee & 31)*4;
    int row = base + r; if(row >= N) row = N-1;
    float4 v = *(const float4*)(X3 + (size_t)row*FD + c);
    sx[r*129 + c+0] = v.x; sx[r*129 + c+1] = v.y;
    sx[r*129 + c+2] = v.z; sx[r*129 + c+3] = v.w;
  }
  __syncthreads();
  {
    const int a = tid >> 2, q = tid & 3;
    float u[16];
    #pragma unroll
    for(int cc=0;cc<16;cc++) u[cc] = ab1[q*16 + cc];
    for(int f=0; f<128; f++){
      float xv = sx[a*129 + f];
      const float4* wp = (const float4*)(aW1 + f*64 + q*16);
      float4 w0 = wp[0], w1 = wp[1], w2 = wp[2], w3 = wp[3];
      u[0]+=xv*w0.x; u[1]+=xv*w0.y; u[2]+=xv*w0.z; u[3]+=xv*w0.w;
      u[4]+=xv*w1.x; u[5]+=xv*w1.y; u[6]+=xv*w1.z; u[7]+=xv*w1.w;
      u[8]+=xv*w2.x; u[9]+=xv*w2.y; u[10]+=xv*w2.z; u[11]+=xv*w2.w;
      u[12]+=xv*w3.x; u[13]+=xv*w3.y; u[14]+=xv*w3.z; u[15]+=xv*w3.w;
    }
    float pe = 0.f;
    #pragma unroll
    for(int cc=0;cc<16;cc++){
      int c = q*16 + cc;
      pe += sspf(u[cc])*aW2[c];
      sg[a*65 + c] = sigf(u[cc])*aW2[c];
    }
    pe += __shfl_xor(pe, 1);
    pe += __shfl_xor(pe, 2);
    if(q == 0 && base + a < N) atomicAdd(&Emol[mol[base + a]], pe + ab2[0]);
  }
  __syncthreads();
  {
    const int f = tid & 127, g2 = tid >> 7;
    float acc[32];
    #pragma unroll
    for(int q=0;q<32;q++) acc[q]=0.f;
    for(int c=0;c<64;c++){
      float w = aW1[f*64 + c];
      #pragma unroll
      for(int q=0;q<32;q++) acc[q] += sg[(g2*32+q)*65 + c]*w;
    }
    #pragma unroll
    for(int q=0;q<32;q++){
      int row = base + g2*32 + q;
      if(row < N) XB[(size_t)row*FD + f] = acc[q];
    }
  }
}

__global__ __launch_bounds__(256) void k_grad(const float* __restrict__ pos,
    const int* __restrict__ Ii, const int* __restrict__ Ij,
    const float* __restrict__ De, const float* __restrict__ DBe,
    float* __restrict__ G, int E){
  int e = blockIdx.x*256 + threadIdx.x;
  if(e >= E) return;
  if(De[e] >= CUTF) return;
  float s = DBe[e] / De[e];
  int i = Ii[e], j = Ij[e];
  float dx = s*(pos[i*3+0]-pos[j*3+0]);
  float dy = s*(pos[i*3+1]-pos[j*3+1]);
  float dz = s*(pos[i*3+2]-pos[j*3+2]);
  atomicAdd(&G[i*3+0], dx); atomicAdd(&G[i*3+1], dy); atomicAdd(&G[i*3+2], dz);
  atomicAdd(&G[j*3+0], -dx); atomicAdd(&G[j*3+1], -dy); atomicAdd(&G[j*3+2], -dz);
}

__global__ __launch_bounds__(256) void k_norm(const float* __restrict__ G,
    const int* __restrict__ mol, u32* __restrict__ maxnU, int N){
  int n = blockIdx.x*256 + threadIdx.x;
  if(n >= N) return;
  float ax = G[n*3], ay = G[n*3+1], az = G[n*3+2];
  float nrm = sqrtf(ax*ax+ay*ay+az*az);
  atomicMax(&maxnU[mol[n]], __float_as_uint(nrm));
}

__global__ __launch_bounds__(256) void k_apply(const float* __restrict__ G,
    const int* __restrict__ mol, const u32* __restrict__ maxnU,
    float* __restrict__ outA, int N){
  int n = blockIdx.x*256 + threadIdx.x;
  if(n >= N) return;
  float mx = __uint_as_float(maxnU[mol[n]]);
  float coefc = fminf(1.0f/fmaxf(mx, 1e-8f), 1.0f);
  outA[n*3+0] = -G[n*3+0]*coefc;
  outA[n*3+1] = -G[n*3+1]*coefc;
  outA[n*3+2] = -G[n*3+2]*coefc;
}

extern "C" void kernel_launch(void* const* d_in, const int* in_sizes, int n_in,
                              void* d_out, int out_size, void* d_ws, size_t ws_size,
                              hipStream_t stream) {
  (void)n_in;
  const float* pos  = (const float*)d_in[0];
  const float* emb  = (const float*)d_in[1];
  const float* in2f = (const float*)d_in[2];
  const float* fW1  = (const float*)d_in[3];
  const float* fb1  = (const float*)d_in[4];
  const float* fW2  = (const float*)d_in[5];
  const float* fb2  = (const float*)d_in[6];
  const float* oW1  = (const float*)d_in[7];
  const float* ob1  = (const float*)d_in[8];
  const float* oW2  = (const float*)d_in[9];
  const float* ob2  = (const float*)d_in[10];
  const float* aW1  = (const float*)d_in[11];
  const float* ab1  = (const float*)d_in[12];
  const float* aW2  = (const float*)d_in[13];
  const float* ab2  = (const float*)d_in[14];
  const int*   Z    = (const int*)d_in[15];
  const int*   Ii   = (const int*)d_in[16];
  const int*   Ij   = (const int*)d_in[17];
  const int*   mol  = (const int*)d_in[18];
  const int N = in_sizes[15];
  const int E = in_sizes[16];
  const int M = out_size - N*3;
  const int EPM = E / M;           // 992
  const size_t NFE = (size_t)N*FD;
  float* outF = (float*)d_out;
  float* outE = outF + (size_t)N*3;
  float* ws = (float*)d_ws;
  const size_t base_u32 = 11*NFE + 2*(size_t)E + 3*(WLSZ/2) + 3*(W2LSZ/2) + 64;
  if(ws_size < base_u32*4) return;
  const int hsave = (ws_size >= (base_u32 + 3*NFE)*4);

  float* X0  = ws;
  float* SV0 = ws + 4*NFE;
  float* H   = ws + 7*NFE;
  float* AGG = ws + 8*NFE;
  float* XB  = ws + 9*NFE;
  float* HB  = ws + 10*NFE;
  float* De  = ws + 11*NFE;
  float* DBe = De + E;
  u16*   WB  = (u16*)(DBe + E);
  u16*   WB2 = WB + 3*WLSZ;
  float* Hsv = (float*)(WB2 + 3*W2LSZ);   // 3*NFE floats (hsave only)
  float* G    = AGG;
  u32*  maxnU = (u32*)H;

  const int gN   = (int)((NFE + 255)/256);
  const int gE   = (E + 255)/256;
  const int gRow = (N + 31)/32;
  const int gHead= (N + 63)/64;

  k_embed<<<gN,256,0,stream>>>(emb, Z, X0, (int)NFE);
  k_edge_geom<<<gE,256,0,stream>>>(pos, Ii, Ij, De, DBe, E);
  k_prep<<<(3*WLSZ+255)/256,256,0,stream>>>(fW1, fW2, WB);
  k_prep2<<<(3*W2LSZ+255)/256,256,0,stream>>>(in2f, oW1, oW2, WB2);
  for(int l=0;l<3;l++){
    float* Xl  = X0 + (size_t)l*NFE;
    float* Xn  = X0 + (size_t)(l+1)*NFE;
    float* SVl = SV0 + (size_t)l*NFE;
    const u16* W1t = WB + l*WLSZ;
    const u16* W2t = W1t + 24576;
    const u16* d = WB2 + l*W2LSZ;
    const u16 *in2f_t = d, *oW1_t = d + 32768, *oW2_t = d + 65536;
    float* Hl = hsave ? (Hsv + (size_t)l*NFE) : H;
    k_gemmb<<<gRow,256,0,stream>>>(Xl, in2f_t, nullptr, nullptr, nullptr, Hl, nullptr, 0, N);
    k_edge_fwd12<<<N,256,0,stream>>>(Hl, De, W1t, fb1 + l*128, W2t, fb2 + l*128, AGG, EPM);
    k_gemmf<<<gRow,256,0,stream>>>(AGG, oW1_t, ob1 + l*128, oW2_t, ob2 + l*128, Xl, nullptr, Xn, SVl, 1, N);
  }
  k_zero<<<(M+255)/256,256,0,stream>>>(outE, M);
  k_head<<<gHead,256,0,stream>>>(X0 + 3*NFE, aW1, ab1, aW2, ab2, mol, outE, XB, N);
  for(int l=2;l>=0;l--){
    float* Xl  = X0 + (size_t)l*NFE;
    float* SVl = SV0 + (size_t)l*NFE;
    const u16* W1t = WB + l*WLSZ;
    const u16* W1b = W1t + 4096;
    const u16* W2r = W1t + 8192;
    const u16* W2t = W1t + 24576;
    const u16* d = WB2 + l*W2LSZ;
    const u16 *in2f_t = d, *in2f_d = d + 16384, *oW1_d = d + 49152, *oW2_d = d + 81920;
    k_gemmf<<<gRow,256,0,stream>>>(XB, oW2_d, nullptr, oW1_d, nullptr, nullptr, SVl, AGG, nullptr, 0, N);
    float* Hl;
    if(hsave){
      Hl = Hsv + (size_t)l*NFE;
    } else {
      Hl = H;
      k_gemmb<<<gRow,256,0,stream>>>(Xl, in2f_t, nullptr, nullptr, nullptr, H, nullptr, 0, N);
    }
    k_edge_bwd13<<<N,256,0,stream>>>(Hl, AGG, De, W1t, fb1 + l*128, W1b, W2r, W2t, fb2 + l*128, DBe, HB, EPM);
    k_gemmb<<<gRow,256,0,stream>>>(HB, in2f_d, nullptr, XB, nullptr, XB, nullptr, 0, N);
  }
  k_zero<<<(N*3+255)/256,256,0,stream>>>(G, N*3);
  k_zero<<<(M+255)/256,256,0,stream>>>((float*)maxnU, M);
  k_grad<<<gE,256,0,stream>>>(pos, Ii, Ij, De, DBe, G, E);
  k_norm<<<(N+255)/256,256,0,stream>>>(G, mol, maxnU, N);
  k_apply<<<(N+255)/256,256,0,stream>>>(G, mol, maxnU, outF, N);
}

// Round 18
// 1302.106 us; speedup vs baseline: 1.0280x; 1.0280x over previous
//
#include <hip/hip_runtime.h>
#include <cstddef>

// SchNet fwd energy + force bwd, MI355X. Round 27: recombination of verified
// components. Edge kernels = R16 verbatim (first barrier RESTORED; R17 A/B
// showed its removal cost ~8us/dispatch via De re-reads). Launch = R17's
// hsave (fwd saves per-layer H to Hsv when ws allows; bwd skips the
// bit-identical H recompute; fallback = verified recompute path).

#define FD     128
#define NRBF   20
#define CUTF   5.0f
#define PI_F   3.14159265358979f
#define PW     136    // u16 pitch for sP/sWf/sA
#define WLSZ   40960  // u16 per layer in edge-weight workspace
#define W2LSZ  98304  // u16 per layer in dense-weight workspace (6 x 16384)
#define APM    32     // atoms per molecule

typedef unsigned short u16;
typedef unsigned int   u32;
typedef __attribute__((ext_vector_type(8))) short bf16x8;
typedef __attribute__((ext_vector_type(4))) float f32x4;

__device__ __forceinline__ float u16f(u16 x){ union{u32 i; float f;} v; v.i=((u32)x)<<16; return v.f; }
// Manual RNE bf16 rounding -- VERIFIED. Do NOT replace with inline-asm
// v_cvt_pk_bf16_f32: R10 isolated A/B proved that path numerically wrong here.
__device__ __forceinline__ u16 f16r(float f){ union{float f; u32 i;} v; v.f=f; u32 r=v.i+0x7fffu+((v.i>>16)&1u); return (u16)(r>>16); }
__device__ __forceinline__ float sspf(float x){
  return fmaxf(x,0.f) + __logf(1.f + __expf(-fabsf(x))) - 0.6931471805599453f;
}
__device__ __forceinline__ float sigf(float x){
  return __fdividef(1.f, 1.f + __expf(-x));
}
__device__ __forceinline__ float fcutf(float d){ return (d < CUTF) ? 0.5f*(__cosf(PI_F*d/CUTF)+1.f) : 0.f; }

__global__ __launch_bounds__(256) void k_zero(float* __restrict__ p, int n){
  int i = blockIdx.x*256 + threadIdx.x;
  if(i < n) p[i] = 0.f;
}

__global__ __launch_bounds__(256) void k_embed(const float* __restrict__ emb, const int* __restrict__ Z,
                                               float* __restrict__ X0, int n){
  int idx = blockIdx.x*256 + threadIdx.x;
  if(idx >= n) return;
  int a = idx >> 7, f = idx & 127;
  X0[idx] = emb[Z[a]*FD + f];
}

__global__ __launch_bounds__(256) void k_edge_geom(const float* __restrict__ pos,
    const int* __restrict__ Ii, const int* __restrict__ Ij,
    float* __restrict__ De, float* __restrict__ DBe, int E){
  int e = blockIdx.x*256 + threadIdx.x;
  if(e >= E) return;
  int i = Ii[e], j = Ij[e];
  float dx = pos[j*3+0]-pos[i*3+0];
  float dy = pos[j*3+1]-pos[i*3+1];
  float dz = pos[j*3+2]-pos[i*3+2];
  De[e] = sqrtf(dx*dx+dy*dy+dz*dz + 1e-12f);
  DBe[e] = 0.f;
}

// Edge-filter bf16 weight pre-conversion (once per launch).
__global__ __launch_bounds__(256) void k_prep(const float* __restrict__ fW1,
    const float* __restrict__ fW2, u16* __restrict__ WB){
  int idx = blockIdx.x*256 + threadIdx.x;
  if(idx >= 3*WLSZ) return;
  int l = idx / WLSZ, r = idx - l*WLSZ;
  const float* W1 = fW1 + l*2560;
  const float* W2 = fW2 + l*16384;
  u16* out = WB + l*WLSZ;
  if(r < 4096){
    int c = r >> 5, k = r & 31;
    out[r] = (k < NRBF) ? f16r(W1[k*128 + c]) : (u16)0;
  } else if(r < 8192){
    int rr = r - 4096;
    int k = rr >> 7, c = rr & 127;
    out[r] = (k < NRBF) ? f16r(W1[k*128 + c]) : (u16)0;
  } else if(r < 24576){
    out[r] = f16r(W2[r - 8192]);
  } else {
    int rr = r - 24576;
    int f = rr >> 7, c = rr & 127;
    out[r] = f16r(W2[c*128 + f]);
  }
}

// Dense-layer bf16 weight pre-conversion: per layer, 6 matrices of [n][k]:
//   0: in2f^T  1: in2f  2: oW1^T  3: oW1  4: oW2^T  5: oW2
__global__ __launch_bounds__(256) void k_prep2(const float* __restrict__ in2f,
    const float* __restrict__ oW1, const float* __restrict__ oW2,
    u16* __restrict__ WB2){
  int idx = blockIdx.x*256 + threadIdx.x;
  if(idx >= 3*W2LSZ) return;
  int l = idx / W2LSZ, r = idx - l*W2LSZ;
  int mat = r >> 14, q = r & 16383;
  int n = q >> 7, k = q & 127;
  const float* src = (mat < 2) ? (in2f + l*16384) : (mat < 4) ? (oW1 + l*16384) : (oW2 + l*16384);
  float v = (mat & 1) ? src[n*128 + k] : src[k*128 + n];
  WB2[idx] = f16r(v);
}

// Dense GEMM via bf16 MFMA (verified R9/R15).
__global__ __launch_bounds__(256) void k_gemmb(const float* __restrict__ A,
    const u16* __restrict__ Bn, const float* __restrict__ bias,
    const float* __restrict__ res, const float* __restrict__ mul,
    float* __restrict__ out1, float* __restrict__ out2, int act, int Nr){
  __shared__ u16 sA[32*PW];
  const int tid = threadIdx.x;
  const int rb = blockIdx.x * 32;
  #pragma unroll
  for(int q=0;q<4;q++){
    int e = q*256 + tid;
    int r = e >> 5, c4 = (e & 31)*4;
    int rr = rb + r; if(rr >= Nr) rr = Nr-1;
    float4 v = *(const float4*)(A + (size_t)rr*FD + c4);
    sA[r*PW + c4+0] = f16r(v.x);
    sA[r*PW + c4+1] = f16r(v.y);
    sA[r*PW + c4+2] = f16r(v.z);
    sA[r*PW + c4+3] = f16r(v.w);
  }
  __syncthreads();
  const int w = tid >> 6, lane = tid & 63;
  const int quad = lane >> 4, l16 = lane & 15;
  f32x4 acc[2][2];
  #pragma unroll
  for(int mm=0;mm<2;mm++){ acc[mm][0]=(f32x4){0,0,0,0}; acc[mm][1]=(f32x4){0,0,0,0}; }
  __builtin_amdgcn_s_setprio(1);
  #pragma unroll
  for(int ks=0;ks<4;ks++){
    bf16x8 va[2], vb[2];
    #pragma unroll
    for(int mm=0;mm<2;mm++)
      va[mm] = *(const bf16x8*)&sA[(mm*16+l16)*PW + ks*32 + quad*8];
    #pragma unroll
    for(int p=0;p<2;p++)
      vb[p] = *(const bf16x8*)(Bn + ((2*w+p)*16+l16)*128 + ks*32 + quad*8);
    #pragma unroll
    for(int mm=0;mm<2;mm++)
      #pragma unroll
      for(int p=0;p<2;p++)
        acc[mm][p] = __builtin_amdgcn_mfma_f32_16x16x32_bf16(va[mm], vb[p], acc[mm][p], 0,0,0);
  }
  __builtin_amdgcn_s_setprio(0);
  #pragma unroll
  for(int mm=0;mm<2;mm++)
    #pragma unroll
    for(int p=0;p<2;p++){
      const int f = (2*w+p)*16 + l16;
      float bb = bias ? bias[f] : 0.f;
      #pragma unroll
      for(int r=0;r<4;r++){
        int row = rb + mm*16 + quad*4 + r;
        if(row >= Nr) continue;
        size_t o = (size_t)row*FD + f;
        float y = acc[mm][p][r] + bb;
        if(res) y += res[o];
        if(mul) y *= mul[o];
        if(act){ out1[o] = sspf(y); out2[o] = sigf(y); }
        else out1[o] = y;
      }
    }
}

// Fused dependent-GEMM pair (verified R16).
__global__ __launch_bounds__(256) void k_gemmf(const float* __restrict__ A,
    const u16* __restrict__ B1n, const float* __restrict__ b1,
    const u16* __restrict__ B2n, const float* __restrict__ b2,
    const float* __restrict__ res, const float* __restrict__ mulSV,
    float* __restrict__ out1, float* __restrict__ outSV, int mode, int Nr){
  __shared__ u16 sA[32*PW];
  __shared__ u16 sB[32*PW];
  const int tid = threadIdx.x;
  const int rb = blockIdx.x * 32;
  #pragma unroll
  for(int q=0;q<4;q++){
    int e = q*256 + tid;
    int r = e >> 5, c4 = (e & 31)*4;
    int rr = rb + r; if(rr >= Nr) rr = Nr-1;
    float4 v = *(const float4*)(A + (size_t)rr*FD + c4);
    sA[r*PW + c4+0] = f16r(v.x);
    sA[r*PW + c4+1] = f16r(v.y);
    sA[r*PW + c4+2] = f16r(v.z);
    sA[r*PW + c4+3] = f16r(v.w);
  }
  __syncthreads();
  const int w = tid >> 6, lane = tid & 63;
  const int quad = lane >> 4, l16 = lane & 15;
  { // GEMM1
    f32x4 acc[2][2];
    #pragma unroll
    for(int mm=0;mm<2;mm++){ acc[mm][0]=(f32x4){0,0,0,0}; acc[mm][1]=(f32x4){0,0,0,0}; }
    __builtin_amdgcn_s_setprio(1);
    #pragma unroll
    for(int ks=0;ks<4;ks++){
      bf16x8 va[2], vb[2];
      #pragma unroll
      for(int mm=0;mm<2;mm++)
        va[mm] = *(const bf16x8*)&sA[(mm*16+l16)*PW + ks*32 + quad*8];
      #pragma unroll
      for(int p=0;p<2;p++)
        vb[p] = *(const bf16x8*)(B1n + ((2*w+p)*16+l16)*128 + ks*32 + quad*8);
      #pragma unroll
      for(int mm=0;mm<2;mm++)
        #pragma unroll
        for(int p=0;p<2;p++)
          acc[mm][p] = __builtin_amdgcn_mfma_f32_16x16x32_bf16(va[mm], vb[p], acc[mm][p], 0,0,0);
    }
    __builtin_amdgcn_s_setprio(0);
    #pragma unroll
    for(int mm=0;mm<2;mm++)
      #pragma unroll
      for(int p=0;p<2;p++){
        const int f = (2*w+p)*16 + l16;
        float bb = (mode && b1) ? b1[f] : 0.f;
        #pragma unroll
        for(int r=0;r<4;r++){
          const int lrow = mm*16 + quad*4 + r;
          int row = rb + lrow;
          if(row >= Nr) row = Nr-1;
          size_t o = (size_t)row*FD + f;
          float y = acc[mm][p][r] + bb;
          float t;
          if(mode){
            t = sspf(y);
            if(rb + lrow < Nr) outSV[o] = sigf(y);
          } else {
            t = y * mulSV[o];
          }
          sB[lrow*PW + f] = f16r(t);
        }
      }
  }
  __syncthreads();
  { // GEMM2
    f32x4 acc[2][2];
    #pragma unroll
    for(int mm=0;mm<2;mm++){ acc[mm][0]=(f32x4){0,0,0,0}; acc[mm][1]=(f32x4){0,0,0,0}; }
    __builtin_amdgcn_s_setprio(1);
    #pragma unroll
    for(int ks=0;ks<4;ks++){
      bf16x8 va[2], vb[2];
      #pragma unroll
      for(int mm=0;mm<2;mm++)
        va[mm] = *(const bf16x8*)&sB[(mm*16+l16)*PW + ks*32 + quad*8];
      #pragma unroll
      for(int p=0;p<2;p++)
        vb[p] = *(const bf16x8*)(B2n + ((2*w+p)*16+l16)*128 + ks*32 + quad*8);
      #pragma unroll
      for(int mm=0;mm<2;mm++)
        #pragma unroll
        for(int p=0;p<2;p++)
          acc[mm][p] = __builtin_amdgcn_mfma_f32_16x16x32_bf16(va[mm], vb[p], acc[mm][p], 0,0,0);
    }
    __builtin_amdgcn_s_setprio(0);
    #pragma unroll
    for(int mm=0;mm<2;mm++)
      #pragma unroll
      for(int p=0;p<2;p++){
        const int f = (2*w+p)*16 + l16;
        float bb = (mode && b2) ? b2[f] : 0.f;
        #pragma unroll
        for(int r=0;r<4;r++){
          int row = rb + mm*16 + quad*4 + r;
          if(row >= Nr) continue;
          size_t o = (size_t)row*FD + f;
          float y = acc[mm][p][r] + bb;
          if(res) y += res[o];
          out1[o] = y;
        }
      }
  }
}

// ---- Edge forward v11 (R15/R16 verified: first barrier present) ----
__global__ __launch_bounds__(256) void k_edge_fwd11(
    const float* __restrict__ h,
    const float* __restrict__ De,
    const u16* __restrict__ W1t, const float* __restrict__ b1,
    const u16* __restrict__ W2t, const float* __restrict__ b2,
    float* __restrict__ agg, int EPM){
  __shared__ u16 srbfb[32*32];
  __shared__ u16 sP [32*PW];
  __shared__ u16 sWf[32*PW];
  __shared__ float sD[32];
  __shared__ float sRed[4*128];
  const int tid = threadIdx.x;
  const int nb = gridDim.x;
  const int P = ((nb & 7) == 0) ? ((blockIdx.x & 7)*(nb >> 3) + (blockIdx.x >> 3)) : blockIdx.x;
  const int m = P >> 5, a = P & 31;
  const int a0 = m*APM;
  const int eb = m*EPM + a*(APM-1);
  if(tid < 32) sD[tid] = (tid < APM-1) ? De[eb + tid] : (CUTF + 1.f);
  __syncthreads();
  const float step = CUTF/19.0f;
  const float coef = -0.5f/(step*step);
  {
    #pragma unroll
    for(int q=0;q<4;q++){
      int idx = q*256 + tid;
      int lt = idx >> 5, k = idx & 31;
      float x = sD[lt] - step*(float)k;
      srbfb[idx] = (k < NRBF) ? f16r(__expf(coef*x*x)) : (u16)0;
    }
  }
  __syncthreads();
  const int w = tid >> 6, lane = tid & 63;
  const int quad = lane >> 4, l16 = lane & 15;
  {
    f32x4 acc[2][2];
    #pragma unroll
    for(int mm=0;mm<2;mm++){ acc[mm][0]=(f32x4){0,0,0,0}; acc[mm][1]=(f32x4){0,0,0,0}; }
    bf16x8 va[2], vb[2];
    #pragma unroll
    for(int mm=0;mm<2;mm++)
      va[mm] = *(const bf16x8*)&srbfb[(mm*16+l16)*32 + quad*8];
    #pragma unroll
    for(int p=0;p<2;p++)
      vb[p] = *(const bf16x8*)(W1t + ((2*w+p)*16+l16)*32 + quad*8);
    #pragma unroll
    for(int mm=0;mm<2;mm++)
      #pragma unroll
      for(int p=0;p<2;p++)
        acc[mm][p] = __builtin_amdgcn_mfma_f32_16x16x32_bf16(va[mm], vb[p], acc[mm][p], 0,0,0);
    #pragma unroll
    for(int mm=0;mm<2;mm++)
      #pragma unroll
      for(int p=0;p<2;p++){
        const int c = (2*w+p)*16 + l16;
        float bb = b1[c];
        #pragma unroll
        for(int r=0;r<4;r++)
          sP[(mm*16+quad*4+r)*PW + c] = f16r(sspf(acc[mm][p][r] + bb));
      }
  }
  __syncthreads();
  {
    f32x4 acc[2][2];
    #pragma unroll
    for(int mm=0;mm<2;mm++){ acc[mm][0]=(f32x4){0,0,0,0}; acc[mm][1]=(f32x4){0,0,0,0}; }
    __builtin_amdgcn_s_setprio(1);
    #pragma unroll
    for(int ks=0;ks<4;ks++){
      bf16x8 va[2], vb[2];
      #pragma unroll
      for(int mm=0;mm<2;mm++)
        va[mm] = *(const bf16x8*)&sP[(mm*16+l16)*PW + ks*32 + quad*8];
      #pragma unroll
      for(int p=0;p<2;p++)
        vb[p] = *(const bf16x8*)(W2t + ((2*w+p)*16+l16)*128 + ks*32 + quad*8);
      #pragma unroll
      for(int mm=0;mm<2;mm++)
        #pragma unroll
        for(int p=0;p<2;p++)
          acc[mm][p] = __builtin_amdgcn_mfma_f32_16x16x32_bf16(va[mm], vb[p], acc[mm][p], 0,0,0);
    }
    __builtin_amdgcn_s_setprio(0);
    #pragma unroll
    for(int mm=0;mm<2;mm++)
      #pragma unroll
      for(int p=0;p<2;p++){
        const int f = (2*w+p)*16 + l16;
        float bb = b2[f];
        #pragma unroll
        for(int r=0;r<4;r++)
          sWf[(mm*16+quad*4+r)*PW + f] = f16r(acc[mm][p][r] + bb);
      }
  }
  __syncthreads();
  {
    float h0v[8], h1v[8], w0v[8], w1v[8], fcv[8];
    #pragma unroll
    for(int s=0;s<8;s++){
      int lt = w*8 + s;
      int j = (lt < APM-1) ? (lt + (lt >= a ? 1 : 0)) : 0;
      fcv[s] = fcutf(sD[lt]);
      const float* hr = h + (size_t)(a0 + j)*FD;
      h0v[s] = hr[lane];
      h1v[s] = hr[lane + 64];
      w0v[s] = u16f(sWf[lt*PW + lane]);
      w1v[s] = u16f(sWf[lt*PW + lane + 64]);
    }
    float r0 = 0.f, r1 = 0.f;
    #pragma unroll
    for(int s=0;s<8;s++){
      r0 += h0v[s] * w0v[s] * fcv[s];
      r1 += h1v[s] * w1v[s] * fcv[s];
    }
    sRed[w*128 + lane]      = r0;
    sRed[w*128 + lane + 64] = r1;
  }
  __syncthreads();
  if(tid < 128){
    float v = sRed[tid] + sRed[128+tid] + sRed[256+tid] + sRed[384+tid];
    agg[(size_t)(a0+a)*FD + tid] = v;
  }
}

// ---- Edge backward v12 (R16 verified: first barrier present) ----
__global__ __launch_bounds__(256) void k_edge_bwd12(
    const float* __restrict__ h, const float* __restrict__ AB,
    const float* __restrict__ De,
    const u16* __restrict__ W1t, const float* __restrict__ b1,
    const u16* __restrict__ W1b, const u16* __restrict__ W2r,
    const u16* __restrict__ W2t, const float* __restrict__ b2,
    float* __restrict__ DBe, float* __restrict__ HB, int EPM){
  __shared__ u16 srbfb[32*32];
  __shared__ u16 sP [32*PW];
  __shared__ u16 sWf[32*PW];
  __shared__ float sD[32];
  __shared__ float sRed[4*128];
  __shared__ float sdb[32*2];
  __shared__ float sfb[32];
  const int tid = threadIdx.x;
  const int nb = gridDim.x;
  const int P = ((nb & 7) == 0) ? ((blockIdx.x & 7)*(nb >> 3) + (blockIdx.x >> 3)) : blockIdx.x;
  const int m = P >> 5, a = P & 31;
  const int a0 = m*APM;
  const int eb = m*EPM + a*(APM-1);
  if(tid < 32) sD[tid] = (tid < APM-1) ? De[eb + tid] : (CUTF + 1.f);
  __syncthreads();
  const float step = CUTF/19.0f;
  const float coef = -0.5f/(step*step);
  {
    #pragma unroll
    for(int q=0;q<4;q++){
      int idx = q*256 + tid;
      int lt = idx >> 5, k = idx & 31;
      float x = sD[lt] - step*(float)k;
      srbfb[idx] = (k < NRBF) ? f16r(__expf(coef*x*x)) : (u16)0;
    }
  }
  __syncthreads();
  const int w = tid >> 6, lane = tid & 63;
  const int quad = lane >> 4, l16 = lane & 15;
  {
    f32x4 acc[2][2];
    #pragma unroll
    for(int mm=0;mm<2;mm++){ acc[mm][0]=(f32x4){0,0,0,0}; acc[mm][1]=(f32x4){0,0,0,0}; }
    bf16x8 va[2], vb[2];
    #pragma unroll
    for(int mm=0;mm<2;mm++)
      va[mm] = *(const bf16x8*)&srbfb[(mm*16+l16)*32 + quad*8];
    #pragma unroll
    for(int p=0;p<2;p++)
      vb[p] = *(const bf16x8*)(W1t + ((2*w+p)*16+l16)*32 + quad*8);
    #pragma unroll
    for(int mm=0;mm<2;mm++)
      #pragma unroll
      for(int p=0;p<2;p++)
        acc[mm][p] = __builtin_amdgcn_mfma_f32_16x16x32_bf16(va[mm], vb[p], acc[mm][p], 0,0,0);
    #pragma unroll
    for(int mm=0;mm<2;mm++)
      #pragma unroll
      for(int p=0;p<2;p++){
        const int c = (2*w+p)*16 + l16;
        float bb = b1[c];
        #pragma unroll
        for(int r=0;r<4;r++)
          sP[(mm*16+quad*4+r)*PW + c] = f16r(sspf(acc[mm][p][r] + bb));
      }
  }
  __syncthreads();
  {
    f32x4 acc[2][2];
    #pragma unroll
    for(int mm=0;mm<2;mm++){ acc[mm][0]=(f32x4){0,0,0,0}; acc[mm][1]=(f32x4){0,0,0,0}; }
    __builtin_amdgcn_s_setprio(1);
    #pragma unroll
    for(int ks=0;ks<4;ks++){
      bf16x8 va[2], vb[2];
      #pragma unroll
      for(int mm=0;mm<2;mm++)
        va[mm] = *(const bf16x8*)&sP[(mm*16+l16)*PW + ks*32 + quad*8];
      #pragma unroll
      for(int p=0;p<2;p++)
        vb[p] = *(const bf16x8*)(W2t + ((2*w+p)*16+l16)*128 + ks*32 + quad*8);
      #pragma unroll
      for(int mm=0;mm<2;mm++)
        #pragma unroll
        for(int p=0;p<2;p++)
          acc[mm][p] = __builtin_amdgcn_mfma_f32_16x16x32_bf16(va[mm], vb[p], acc[mm][p], 0,0,0);
    }
    __builtin_amdgcn_s_setprio(0);
    #pragma unroll
    for(int mm=0;mm<2;mm++)
      #pragma unroll
      for(int p=0;p<2;p++){
        const int f = (2*w+p)*16 + l16;
        float bb = b2[f];
        #pragma unroll
        for(int r=0;r<4;r++)
          sWf[(mm*16+quad*4+r)*PW + f] = f16r(acc[mm][p][r] + bb);
      }
  }
  __syncthreads();
  {
    float ab0 = AB[(size_t)(a0+a)*FD + lane];
    float ab1 = AB[(size_t)(a0+a)*FD + lane + 64];
    float h0v[8], h1v[8], a0v[8], a1v[8], w0v[8], w1v[8], fcv[8];
    #pragma unroll
    for(int s=0;s<8;s++){
      int lt = w*8 + s;
      int j = (lt < APM-1) ? (lt + (lt >= a ? 1 : 0)) : 0;
      fcv[s] = fcutf(sD[lt]);
      const float* hr  = h  + (size_t)(a0 + j)*FD;
      const float* abr = AB + (size_t)(a0 + j)*FD;
      h0v[s] = hr[lane];
      h1v[s] = hr[lane + 64];
      a0v[s] = abr[lane];
      a1v[s] = abr[lane + 64];
      w0v[s] = u16f(sWf[lt*PW + lane]);
      w1v[s] = u16f(sWf[lt*PW + lane + 64]);
    }
    float r0 = 0.f, r1 = 0.f;
    float pfv[8];
    #pragma unroll
    for(int s=0;s<8;s++){
      int lt = w*8 + s;
      float fc = fcv[s];
      r0 += a0v[s] * w0v[s] * fc;
      r1 += a1v[s] * w1v[s] * fc;
      float g0 = ab0*h0v[s], g1 = ab1*h1v[s];
      sWf[lt*PW + lane]      = f16r(g0*fc);
      sWf[lt*PW + lane + 64] = f16r(g1*fc);
      pfv[s] = g0*w0v[s] + g1*w1v[s];
    }
    #pragma unroll
    for(int d2=1; d2<64; d2<<=1){
      #pragma unroll
      for(int s=0;s<8;s++) pfv[s] += __shfl_xor(pfv[s], d2);
    }
    if(lane == 0){
      #pragma unroll
      for(int s=0;s<8;s++) sfb[w*8 + s] = pfv[s];
    }
    sRed[w*128 + lane]      = r0;
    sRed[w*128 + lane + 64] = r1;
  }
  __syncthreads();
  if(tid < 128){
    float v = sRed[tid] + sRed[128+tid] + sRed[256+tid] + sRed[384+tid];
    HB[(size_t)(a0+a)*FD + tid] = v;
  }
  { // phase 5+6 merged: GEMM2; sigma-trick; tbar -> sP (thread-local RMW)
    f32x4 acc[2][2];
    #pragma unroll
    for(int mm=0;mm<2;mm++){ acc[mm][0]=(f32x4){0,0,0,0}; acc[mm][1]=(f32x4){0,0,0,0}; }
    __builtin_amdgcn_s_setprio(1);
    #pragma unroll
    for(int ks=0;ks<4;ks++){
      bf16x8 va[2], vb[2];
      #pragma unroll
      for(int mm=0;mm<2;mm++)
        va[mm] = *(const bf16x8*)&sWf[(mm*16+l16)*PW + ks*32 + quad*8];
      #pragma unroll
      for(int p=0;p<2;p++)
        vb[p] = *(const bf16x8*)(W2r + ((2*w+p)*16+l16)*128 + ks*32 + quad*8);
      #pragma unroll
      for(int mm=0;mm<2;mm++)
        #pragma unroll
        for(int p=0;p<2;p++)
          acc[mm][p] = __builtin_amdgcn_mfma_f32_16x16x32_bf16(va[mm], vb[p], acc[mm][p], 0,0,0);
    }
    __builtin_amdgcn_s_setprio(0);
    #pragma unroll
    for(int mm=0;mm<2;mm++)
      #pragma unroll
      for(int p=0;p<2;p++){
        const int c = (2*w+p)*16 + l16;
        #pragma unroll
        for(int r=0;r<4;r++){
          const int row = mm*16 + quad*4 + r;
          float Pv = u16f(sP[row*PW + c]);
          float sig = 1.0f - 0.5f*__expf(-Pv);
          sP[row*PW + c] = f16r(acc[mm][p][r] * sig);
        }
      }
  }
  __syncthreads();
  { // phase 7: GEMM3 (A from sP); dbar partials, rbf recomputed
    const int m3 = w >> 1, p3 = w & 1;
    f32x4 acc = (f32x4){0,0,0,0};
    #pragma unroll
    for(int ks=0;ks<4;ks++){
      bf16x8 va = *(const bf16x8*)&sP[(m3*16+l16)*PW + ks*32 + quad*8];
      bf16x8 vb = *(const bf16x8*)(W1b + (p3*16+l16)*128 + ks*32 + quad*8);
      acc = __builtin_amdgcn_mfma_f32_16x16x32_bf16(va, vb, acc, 0,0,0);
    }
    const int kr = p3*16 + l16;
    float s0[4];
    #pragma unroll
    for(int r=0;r<4;r++){
      int lt = m3*16 + quad*4 + r;
      float v = 0.f;
      if(kr < NRBF){
        float x = sD[lt] - step*(float)kr;
        float rb = __expf(coef*x*x);
        v = acc[r] * rb * (2.f*coef*x);
      }
      s0[r] = v;
    }
    #pragma unroll
    for(int d2=1; d2<16; d2<<=1){
      #pragma unroll
      for(int r=0;r<4;r++) s0[r] += __shfl_xor(s0[r], d2);
    }
    if(l16 == 0){
      #pragma unroll
      for(int r=0;r<4;r++) sdb[(m3*16+quad*4+r)*2 + p3] = s0[r];
    }
  }
  __syncthreads();
  if(tid < APM-1){
    const float d = sD[tid];
    float dfc = (d < CUTF) ? (-0.5f*(PI_F/CUTF)*__sinf(PI_F*d/CUTF)) : 0.f;
    DBe[eb + tid] += sdb[tid*2+0] + sdb[tid*2+1] + sfb[tid]*dfc;
  }
}

// fused atomwise head + head-backward (unchanged, verified)
__global__ __launch_bounds__(256) void k_head(const float* __restrict__ X3,
    const float* __restrict__ aW1, const float* __restrict__ ab1,
    const float* __restrict__ aW2, const float* __restrict__ ab2,
    const int* __restrict__ mol, float* __restrict__ Emol, float* __restrict__ XB, int N){
  __shared__ float sx[64*129];
  __shared__ float sg[64*65];
  const int tid = threadIdx.x;
  const int base = blockIdx.x*64;
  for(int q=0;q<8;q++){
    int ee = q*256 + tid;
    int r = ee >> 5, c = (ee & 31)*4;
    int row = base + r; if(row >= N) row = N-1;
    float4 v = *(const float4*)(X3 + (size_t)row*FD + c);
    sx[r*129 + c+0] = v.x; sx[r*129 + c+1] = v.y;
    sx[r*129 + c+2] = v.z; sx[r*129 + c+3] = v.w;
  }
  __syncthreads();
  {
    const int a = tid >> 2, q = tid & 3;
    float u[16];
    #pragma unroll
    for(int cc=0;cc<16;cc++) u[cc] = ab1[q*16 + cc];
    for(int f=0; f<128; f++){
      float xv = sx[a*129 + f];
      const float4* wp = (const float4*)(aW1 + f*64 + q*16);
      float4 w0 = wp[0], w1 = wp[1], w2 = wp[2], w3 = wp[3];
      u[0]+=xv*w0.x; u[1]+=xv*w0.y; u[2]+=xv*w0.z; u[3]+=xv*w0.w;
      u[4]+=xv*w1.x; u[5]+=xv*w1.y; u[6]+=xv*w1.z; u[7]+=xv*w1.w;
      u[8]+=xv*w2.x; u[9]+=xv*w2.y; u[10]+=xv*w2.z; u[11]+=xv*w2.w;
      u[12]+=xv*w3.x; u[13]+=xv*w3.y; u[14]+=xv*w3.z; u[15]+=xv*w3.w;
    }
    float pe = 0.f;
    #pragma unroll
    for(int cc=0;cc<16;cc++){
      int c = q*16 + cc;
      pe += sspf(u[cc])*aW2[c];
      sg[a*65 + c] = sigf(u[cc])*aW2[c];
    }
    pe += __shfl_xor(pe, 1);
    pe += __shfl_xor(pe, 2);
    if(q == 0 && base + a < N) atomicAdd(&Emol[mol[base + a]], pe + ab2[0]);
  }
  __syncthreads();
  {
    const int f = tid & 127, g2 = tid >> 7;
    float acc[32];
    #pragma unroll
    for(int q=0;q<32;q++) acc[q]=0.f;
    for(int c=0;c<64;c++){
      float w = aW1[f*64 + c];
      #pragma unroll
      for(int q=0;q<32;q++) acc[q] += sg[(g2*32+q)*65 + c]*w;
    }
    #pragma unroll
    for(int q=0;q<32;q++){
      int row = base + g2*32 + q;
      if(row < N) XB[(size_t)row*FD + f] = acc[q];
    }
  }
}

__global__ __launch_bounds__(256) void k_grad(const float* __restrict__ pos,
    const int* __restrict__ Ii, const int* __restrict__ Ij,
    const float* __restrict__ De, const float* __restrict__ DBe,
    float* __restrict__ G, int E){
  int e = blockIdx.x*256 + threadIdx.x;
  if(e >= E) return;
  if(De[e] >= CUTF) return;
  float s = DBe[e] / De[e];
  int i = Ii[e], j = Ij[e];
  float dx = s*(pos[i*3+0]-pos[j*3+0]);
  float dy = s*(pos[i*3+1]-pos[j*3+1]);
  float dz = s*(pos[i*3+2]-pos[j*3+2]);
  atomicAdd(&G[i*3+0], dx); atomicAdd(&G[i*3+1], dy); atomicAdd(&G[i*3+2], dz);
  atomicAdd(&G[j*3+0], -dx); atomicAdd(&G[j*3+1], -dy); atomicAdd(&G[j*3+2], -dz);
}

__global__ __launch_bounds__(256) void k_norm(const float* __restrict__ G,
    const int* __restrict__ mol, u32* __restrict__ maxnU, int N){
  int n = blockIdx.x*256 + threadIdx.x;
  if(n >= N) return;
  float ax = G[n*3], ay = G[n*3+1], az = G[n*3+2];
  float nrm = sqrtf(ax*ax+ay*ay+az*az);
  atomicMax(&maxnU[mol[n]], __float_as_uint(nrm));
}

__global__ __launch_bounds__(256) void k_apply(const float* __restrict__ G,
    const int* __restrict__ mol, const u32* __restrict__ maxnU,
    float* __restrict__ outA, int N){
  int n = blockIdx.x*256 + threadIdx.x;
  if(n >= N) return;
  float mx = __uint_as_float(maxnU[mol[n]]);
  float coefc = fminf(1.0f/fmaxf(mx, 1e-8f), 1.0f);
  outA[n*3+0] = -G[n*3+0]*coefc;
  outA[n*3+1] = -G[n*3+1]*coefc;
  outA[n*3+2] = -G[n*3+2]*coefc;
}

extern "C" void kernel_launch(void* const* d_in, const int* in_sizes, int n_in,
                              void* d_out, int out_size, void* d_ws, size_t ws_size,
                              hipStream_t stream) {
  (void)n_in;
  const float* pos  = (const float*)d_in[0];
  const float* emb  = (const float*)d_in[1];
  const float* in2f = (const float*)d_in[2];
  const float* fW1  = (const float*)d_in[3];
  const float* fb1  = (const float*)d_in[4];
  const float* fW2  = (const float*)d_in[5];
  const float* fb2  = (const float*)d_in[6];
  const float* oW1  = (const float*)d_in[7];
  const float* ob1  = (const float*)d_in[8];
  const float* oW2  = (const float*)d_in[9];
  const float* ob2  = (const float*)d_in[10];
  const float* aW1  = (const float*)d_in[11];
  const float* ab1  = (const float*)d_in[12];
  const float* aW2  = (const float*)d_in[13];
  const float* ab2  = (const float*)d_in[14];
  const int*   Z    = (const int*)d_in[15];
  const int*   Ii   = (const int*)d_in[16];
  const int*   Ij   = (const int*)d_in[17];
  const int*   mol  = (const int*)d_in[18];
  const int N = in_sizes[15];
  const int E = in_sizes[16];
  const int M = out_size - N*3;
  const int EPM = E / M;           // 992
  const size_t NFE = (size_t)N*FD;
  float* outF = (float*)d_out;
  float* outE = outF + (size_t)N*3;
  float* ws = (float*)d_ws;
  const size_t base_u32 = 11*NFE + 2*(size_t)E + 3*(WLSZ/2) + 3*(W2LSZ/2) + 64;
  if(ws_size < base_u32*4) return;
  const int hsave = (ws_size >= (base_u32 + 3*NFE)*4);

  float* X0  = ws;
  float* SV0 = ws + 4*NFE;
  float* H   = ws + 7*NFE;
  float* AGG = ws + 8*NFE;
  float* XB  = ws + 9*NFE;
  float* HB  = ws + 10*NFE;
  float* De  = ws + 11*NFE;
  float* DBe = De + E;
  u16*   WB  = (u16*)(DBe + E);
  u16*   WB2 = WB + 3*WLSZ;
  float* Hsv = (float*)(WB2 + 3*W2LSZ);   // 3*NFE floats (hsave only)
  float* G    = AGG;
  u32*  maxnU = (u32*)H;

  const int gN   = (int)((NFE + 255)/256);
  const int gE   = (E + 255)/256;
  const int gRow = (N + 31)/32;
  const int gHead= (N + 63)/64;

  k_embed<<<gN,256,0,stream>>>(emb, Z, X0, (int)NFE);
  k_edge_geom<<<gE,256,0,stream>>>(pos, Ii, Ij, De, DBe, E);
  k_prep<<<(3*WLSZ+255)/256,256,0,stream>>>(fW1, fW2, WB);
  k_prep2<<<(3*W2LSZ+255)/256,256,0,stream>>>(in2f, oW1, oW2, WB2);
  for(int l=0;l<3;l++){
    float* Xl  = X0 + (size_t)l*NFE;
    float* Xn  = X0 + (size_t)(l+1)*NFE;
    float* SVl = SV0 + (size_t)l*NFE;
    const u16* W1t = WB + l*WLSZ;
    const u16* W2t = W1t + 24576;
    const u16* d = WB2 + l*W2LSZ;
    const u16 *in2f_t = d, *oW1_t = d + 32768, *oW2_t = d + 65536;
    float* Hl = hsave ? (Hsv + (size_t)l*NFE) : H;
    k_gemmb<<<gRow,256,0,stream>>>(Xl, in2f_t, nullptr, nullptr, nullptr, Hl, nullptr, 0, N);
    k_edge_fwd11<<<N,256,0,stream>>>(Hl, De, W1t, fb1 + l*128, W2t, fb2 + l*128, AGG, EPM);
    k_gemmf<<<gRow,256,0,stream>>>(AGG, oW1_t, ob1 + l*128, oW2_t, ob2 + l*128, Xl, nullptr, Xn, SVl, 1, N);
  }
  k_zero<<<(M+255)/256,256,0,stream>>>(outE, M);
  k_head<<<gHead,256,0,stream>>>(X0 + 3*NFE, aW1, ab1, aW2, ab2, mol, outE, XB, N);
  for(int l=2;l>=0;l--){
    float* Xl  = X0 + (size_t)l*NFE;
    float* SVl = SV0 + (size_t)l*NFE;
    const u16* W1t = WB + l*WLSZ;
    const u16* W1b = W1t + 4096;
    const u16* W2r = W1t + 8192;
    const u16* W2t = W1t + 24576;
    const u16* d = WB2 + l*W2LSZ;
    const u16 *in2f_t = d, *in2f_d = d + 16384, *oW1_d = d + 49152, *oW2_d = d + 81920;
    k_gemmf<<<gRow,256,0,stream>>>(XB, oW2_d, nullptr, oW1_d, nullptr, nullptr, SVl, AGG, nullptr, 0, N);
    float* Hl;
    if(hsave){
      Hl = Hsv + (size_t)l*NFE;
    } else {
      Hl = H;
      k_gemmb<<<gRow,256,0,stream>>>(Xl, in2f_t, nullptr, nullptr, nullptr, H, nullptr, 0, N);
    }
    k_edge_bwd12<<<N,256,0,stream>>>(Hl, AGG, De, W1t, fb1 + l*128, W1b, W2r, W2t, fb2 + l*128, DBe, HB, EPM);
    k_gemmb<<<gRow,256,0,stream>>>(HB, in2f_d, nullptr, XB, nullptr, XB, nullptr, 0, N);
  }
  k_zero<<<(N*3+255)/256,256,0,stream>>>(G, N*3);
  k_zero<<<(M+255)/256,256,0,stream>>>((float*)maxnU, M);
  k_grad<<<gE,256,0,stream>>>(pos, Ii, Ij, De, DBe, G, E);
  k_norm<<<(N+255)/256,256,0,stream>>>(G, mol, maxnU, N);
  k_apply<<<(N+255)/256,256,0,stream>>>(G, mol, maxnU, outF, N);
}

// Round 19
// 1269.978 us; speedup vs baseline: 1.0540x; 1.0253x over previous
//
#include <hip/hip_runtime.h>
#include <cstddef>

// SchNet fwd energy + force bwd, MI355X. Round 28: R18 verbatim (1302us
// verified) + k_head converted to MFMA (k_head_m): phase A U=X3@aW1 and
// phase B XB=sg@aW1^T use the verified 16x16x32 bf16 fragment pattern;
// aW1 pre-converted to two bf16 layouts by k_prep3; pe row-reduce via
// batched 16-lane butterfly; sg intermediate bf16 in LDS (pitch 72,
// 16B-aligned rows). All other kernels byte-identical to R18.

#define FD     128
#define NRBF   20
#define CUTF   5.0f
#define PI_F   3.14159265358979f
#define PW     136    // u16 pitch for sP/sWf/sA
#define WLSZ   40960  // u16 per layer in edge-weight workspace
#define W2LSZ  98304  // u16 per layer in dense-weight workspace (6 x 16384)
#define APM    32     // atoms per molecule

typedef unsigned short u16;
typedef unsigned int   u32;
typedef __attribute__((ext_vector_type(8))) short bf16x8;
typedef __attribute__((ext_vector_type(4))) float f32x4;

__device__ __forceinline__ float u16f(u16 x){ union{u32 i; float f;} v; v.i=((u32)x)<<16; return v.f; }
// Manual RNE bf16 rounding -- VERIFIED. Do NOT replace with inline-asm
// v_cvt_pk_bf16_f32: R10 isolated A/B proved that path numerically wrong here.
__device__ __forceinline__ u16 f16r(float f){ union{float f; u32 i;} v; v.f=f; u32 r=v.i+0x7fffu+((v.i>>16)&1u); return (u16)(r>>16); }
__device__ __forceinline__ float sspf(float x){
  return fmaxf(x,0.f) + __logf(1.f + __expf(-fabsf(x))) - 0.6931471805599453f;
}
__device__ __forceinline__ float sigf(float x){
  return __fdividef(1.f, 1.f + __expf(-x));
}
__device__ __forceinline__ float fcutf(float d){ return (d < CUTF) ? 0.5f*(__cosf(PI_F*d/CUTF)+1.f) : 0.f; }

__global__ __launch_bounds__(256) void k_zero(float* __restrict__ p, int n){
  int i = blockIdx.x*256 + threadIdx.x;
  if(i < n) p[i] = 0.f;
}

__global__ __launch_bounds__(256) void k_embed(const float* __restrict__ emb, const int* __restrict__ Z,
                                               float* __restrict__ X0, int n){
  int idx = blockIdx.x*256 + threadIdx.x;
  if(idx >= n) return;
  int a = idx >> 7, f = idx & 127;
  X0[idx] = emb[Z[a]*FD + f];
}

__global__ __launch_bounds__(256) void k_edge_geom(const float* __restrict__ pos,
    const int* __restrict__ Ii, const int* __restrict__ Ij,
    float* __restrict__ De, float* __restrict__ DBe, int E){
  int e = blockIdx.x*256 + threadIdx.x;
  if(e >= E) return;
  int i = Ii[e], j = Ij[e];
  float dx = pos[j*3+0]-pos[i*3+0];
  float dy = pos[j*3+1]-pos[i*3+1];
  float dz = pos[j*3+2]-pos[i*3+2];
  De[e] = sqrtf(dx*dx+dy*dy+dz*dz + 1e-12f);
  DBe[e] = 0.f;
}

// Edge-filter bf16 weight pre-conversion (once per launch).
__global__ __launch_bounds__(256) void k_prep(const float* __restrict__ fW1,
    const float* __restrict__ fW2, u16* __restrict__ WB){
  int idx = blockIdx.x*256 + threadIdx.x;
  if(idx >= 3*WLSZ) return;
  int l = idx / WLSZ, r = idx - l*WLSZ;
  const float* W1 = fW1 + l*2560;
  const float* W2 = fW2 + l*16384;
  u16* out = WB + l*WLSZ;
  if(r < 4096){
    int c = r >> 5, k = r & 31;
    out[r] = (k < NRBF) ? f16r(W1[k*128 + c]) : (u16)0;
  } else if(r < 8192){
    int rr = r - 4096;
    int k = rr >> 7, c = rr & 127;
    out[r] = (k < NRBF) ? f16r(W1[k*128 + c]) : (u16)0;
  } else if(r < 24576){
    out[r] = f16r(W2[r - 8192]);
  } else {
    int rr = r - 24576;
    int f = rr >> 7, c = rr & 127;
    out[r] = f16r(W2[c*128 + f]);
  }
}

// Dense-layer bf16 weight pre-conversion: per layer, 6 matrices of [n][k]:
//   0: in2f^T  1: in2f  2: oW1^T  3: oW1  4: oW2^T  5: oW2
__global__ __launch_bounds__(256) void k_prep2(const float* __restrict__ in2f,
    const float* __restrict__ oW1, const float* __restrict__ oW2,
    u16* __restrict__ WB2){
  int idx = blockIdx.x*256 + threadIdx.x;
  if(idx >= 3*W2LSZ) return;
  int l = idx / W2LSZ, r = idx - l*W2LSZ;
  int mat = r >> 14, q = r & 16383;
  int n = q >> 7, k = q & 127;
  const float* src = (mat < 2) ? (in2f + l*16384) : (mat < 4) ? (oW1 + l*16384) : (oW2 + l*16384);
  float v = (mat & 1) ? src[n*128 + k] : src[k*128 + n];
  WB2[idx] = f16r(v);
}

// Head-weight bf16 pre-conversion: A1t [c=64][k=128] then A1d [f=128][c=64].
__global__ __launch_bounds__(256) void k_prep3(const float* __restrict__ aW1,
    u16* __restrict__ WB3){
  int idx = blockIdx.x*256 + threadIdx.x;
  if(idx >= 16384) return;
  if(idx < 8192){
    int c = idx >> 7, f = idx & 127;
    WB3[idx] = f16r(aW1[f*64 + c]);
  } else {
    WB3[idx] = f16r(aW1[idx - 8192]);   // [f][c] row-major direct
  }
}

// Dense GEMM via bf16 MFMA (verified R9/R15).
__global__ __launch_bounds__(256) void k_gemmb(const float* __restrict__ A,
    const u16* __restrict__ Bn, const float* __restrict__ bias,
    const float* __restrict__ res, const float* __restrict__ mul,
    float* __restrict__ out1, float* __restrict__ out2, int act, int Nr){
  __shared__ u16 sA[32*PW];
  const int tid = threadIdx.x;
  const int rb = blockIdx.x * 32;
  #pragma unroll
  for(int q=0;q<4;q++){
    int e = q*256 + tid;
    int r = e >> 5, c4 = (e & 31)*4;
    int rr = rb + r; if(rr >= Nr) rr = Nr-1;
    float4 v = *(const float4*)(A + (size_t)rr*FD + c4);
    sA[r*PW + c4+0] = f16r(v.x);
    sA[r*PW + c4+1] = f16r(v.y);
    sA[r*PW + c4+2] = f16r(v.z);
    sA[r*PW + c4+3] = f16r(v.w);
  }
  __syncthreads();
  const int w = tid >> 6, lane = tid & 63;
  const int quad = lane >> 4, l16 = lane & 15;
  f32x4 acc[2][2];
  #pragma unroll
  for(int mm=0;mm<2;mm++){ acc[mm][0]=(f32x4){0,0,0,0}; acc[mm][1]=(f32x4){0,0,0,0}; }
  __builtin_amdgcn_s_setprio(1);
  #pragma unroll
  for(int ks=0;ks<4;ks++){
    bf16x8 va[2], vb[2];
    #pragma unroll
    for(int mm=0;mm<2;mm++)
      va[mm] = *(const bf16x8*)&sA[(mm*16+l16)*PW + ks*32 + quad*8];
    #pragma unroll
    for(int p=0;p<2;p++)
      vb[p] = *(const bf16x8*)(Bn + ((2*w+p)*16+l16)*128 + ks*32 + quad*8);
    #pragma unroll
    for(int mm=0;mm<2;mm++)
      #pragma unroll
      for(int p=0;p<2;p++)
        acc[mm][p] = __builtin_amdgcn_mfma_f32_16x16x32_bf16(va[mm], vb[p], acc[mm][p], 0,0,0);
  }
  __builtin_amdgcn_s_setprio(0);
  #pragma unroll
  for(int mm=0;mm<2;mm++)
    #pragma unroll
    for(int p=0;p<2;p++){
      const int f = (2*w+p)*16 + l16;
      float bb = bias ? bias[f] : 0.f;
      #pragma unroll
      for(int r=0;r<4;r++){
        int row = rb + mm*16 + quad*4 + r;
        if(row >= Nr) continue;
        size_t o = (size_t)row*FD + f;
        float y = acc[mm][p][r] + bb;
        if(res) y += res[o];
        if(mul) y *= mul[o];
        if(act){ out1[o] = sspf(y); out2[o] = sigf(y); }
        else out1[o] = y;
      }
    }
}

// Fused dependent-GEMM pair (verified R16).
__global__ __launch_bounds__(256) void k_gemmf(const float* __restrict__ A,
    const u16* __restrict__ B1n, const float* __restrict__ b1,
    const u16* __restrict__ B2n, const float* __restrict__ b2,
    const float* __restrict__ res, const float* __restrict__ mulSV,
    float* __restrict__ out1, float* __restrict__ outSV, int mode, int Nr){
  __shared__ u16 sA[32*PW];
  __shared__ u16 sB[32*PW];
  const int tid = threadIdx.x;
  const int rb = blockIdx.x * 32;
  #pragma unroll
  for(int q=0;q<4;q++){
    int e = q*256 + tid;
    int r = e >> 5, c4 = (e & 31)*4;
    int rr = rb + r; if(rr >= Nr) rr = Nr-1;
    float4 v = *(const float4*)(A + (size_t)rr*FD + c4);
    sA[r*PW + c4+0] = f16r(v.x);
    sA[r*PW + c4+1] = f16r(v.y);
    sA[r*PW + c4+2] = f16r(v.z);
    sA[r*PW + c4+3] = f16r(v.w);
  }
  __syncthreads();
  const int w = tid >> 6, lane = tid & 63;
  const int quad = lane >> 4, l16 = lane & 15;
  { // GEMM1
    f32x4 acc[2][2];
    #pragma unroll
    for(int mm=0;mm<2;mm++){ acc[mm][0]=(f32x4){0,0,0,0}; acc[mm][1]=(f32x4){0,0,0,0}; }
    __builtin_amdgcn_s_setprio(1);
    #pragma unroll
    for(int ks=0;ks<4;ks++){
      bf16x8 va[2], vb[2];
      #pragma unroll
      for(int mm=0;mm<2;mm++)
        va[mm] = *(const bf16x8*)&sA[(mm*16+l16)*PW + ks*32 + quad*8];
      #pragma unroll
      for(int p=0;p<2;p++)
        vb[p] = *(const bf16x8*)(B1n + ((2*w+p)*16+l16)*128 + ks*32 + quad*8);
      #pragma unroll
      for(int mm=0;mm<2;mm++)
        #pragma unroll
        for(int p=0;p<2;p++)
          acc[mm][p] = __builtin_amdgcn_mfma_f32_16x16x32_bf16(va[mm], vb[p], acc[mm][p], 0,0,0);
    }
    __builtin_amdgcn_s_setprio(0);
    #pragma unroll
    for(int mm=0;mm<2;mm++)
      #pragma unroll
      for(int p=0;p<2;p++){
        const int f = (2*w+p)*16 + l16;
        float bb = (mode && b1) ? b1[f] : 0.f;
        #pragma unroll
        for(int r=0;r<4;r++){
          const int lrow = mm*16 + quad*4 + r;
          int row = rb + lrow;
          if(row >= Nr) row = Nr-1;
          size_t o = (size_t)row*FD + f;
          float y = acc[mm][p][r] + bb;
          float t;
          if(mode){
            t = sspf(y);
            if(rb + lrow < Nr) outSV[o] = sigf(y);
          } else {
            t = y * mulSV[o];
          }
          sB[lrow*PW + f] = f16r(t);
        }
      }
  }
  __syncthreads();
  { // GEMM2
    f32x4 acc[2][2];
    #pragma unroll
    for(int mm=0;mm<2;mm++){ acc[mm][0]=(f32x4){0,0,0,0}; acc[mm][1]=(f32x4){0,0,0,0}; }
    __builtin_amdgcn_s_setprio(1);
    #pragma unroll
    for(int ks=0;ks<4;ks++){
      bf16x8 va[2], vb[2];
      #pragma unroll
      for(int mm=0;mm<2;mm++)
        va[mm] = *(const bf16x8*)&sB[(mm*16+l16)*PW + ks*32 + quad*8];
      #pragma unroll
      for(int p=0;p<2;p++)
        vb[p] = *(const bf16x8*)(B2n + ((2*w+p)*16+l16)*128 + ks*32 + quad*8);
      #pragma unroll
      for(int mm=0;mm<2;mm++)
        #pragma unroll
        for(int p=0;p<2;p++)
          acc[mm][p] = __builtin_amdgcn_mfma_f32_16x16x32_bf16(va[mm], vb[p], acc[mm][p], 0,0,0);
    }
    __builtin_amdgcn_s_setprio(0);
    #pragma unroll
    for(int mm=0;mm<2;mm++)
      #pragma unroll
      for(int p=0;p<2;p++){
        const int f = (2*w+p)*16 + l16;
        float bb = (mode && b2) ? b2[f] : 0.f;
        #pragma unroll
        for(int r=0;r<4;r++){
          int row = rb + mm*16 + quad*4 + r;
          if(row >= Nr) continue;
          size_t o = (size_t)row*FD + f;
          float y = acc[mm][p][r] + bb;
          if(res) y += res[o];
          out1[o] = y;
        }
      }
  }
}

// ---- Edge forward v11 (verified) ----
__global__ __launch_bounds__(256) void k_edge_fwd11(
    const float* __restrict__ h,
    const float* __restrict__ De,
    const u16* __restrict__ W1t, const float* __restrict__ b1,
    const u16* __restrict__ W2t, const float* __restrict__ b2,
    float* __restrict__ agg, int EPM){
  __shared__ u16 srbfb[32*32];
  __shared__ u16 sP [32*PW];
  __shared__ u16 sWf[32*PW];
  __shared__ float sD[32];
  __shared__ float sRed[4*128];
  const int tid = threadIdx.x;
  const int nb = gridDim.x;
  const int P = ((nb & 7) == 0) ? ((blockIdx.x & 7)*(nb >> 3) + (blockIdx.x >> 3)) : blockIdx.x;
  const int m = P >> 5, a = P & 31;
  const int a0 = m*APM;
  const int eb = m*EPM + a*(APM-1);
  if(tid < 32) sD[tid] = (tid < APM-1) ? De[eb + tid] : (CUTF + 1.f);
  __syncthreads();
  const float step = CUTF/19.0f;
  const float coef = -0.5f/(step*step);
  {
    #pragma unroll
    for(int q=0;q<4;q++){
      int idx = q*256 + tid;
      int lt = idx >> 5, k = idx & 31;
      float x = sD[lt] - step*(float)k;
      srbfb[idx] = (k < NRBF) ? f16r(__expf(coef*x*x)) : (u16)0;
    }
  }
  __syncthreads();
  const int w = tid >> 6, lane = tid & 63;
  const int quad = lane >> 4, l16 = lane & 15;
  {
    f32x4 acc[2][2];
    #pragma unroll
    for(int mm=0;mm<2;mm++){ acc[mm][0]=(f32x4){0,0,0,0}; acc[mm][1]=(f32x4){0,0,0,0}; }
    bf16x8 va[2], vb[2];
    #pragma unroll
    for(int mm=0;mm<2;mm++)
      va[mm] = *(const bf16x8*)&srbfb[(mm*16+l16)*32 + quad*8];
    #pragma unroll
    for(int p=0;p<2;p++)
      vb[p] = *(const bf16x8*)(W1t + ((2*w+p)*16+l16)*32 + quad*8);
    #pragma unroll
    for(int mm=0;mm<2;mm++)
      #pragma unroll
      for(int p=0;p<2;p++)
        acc[mm][p] = __builtin_amdgcn_mfma_f32_16x16x32_bf16(va[mm], vb[p], acc[mm][p], 0,0,0);
    #pragma unroll
    for(int mm=0;mm<2;mm++)
      #pragma unroll
      for(int p=0;p<2;p++){
        const int c = (2*w+p)*16 + l16;
        float bb = b1[c];
        #pragma unroll
        for(int r=0;r<4;r++)
          sP[(mm*16+quad*4+r)*PW + c] = f16r(sspf(acc[mm][p][r] + bb));
      }
  }
  __syncthreads();
  {
    f32x4 acc[2][2];
    #pragma unroll
    for(int mm=0;mm<2;mm++){ acc[mm][0]=(f32x4){0,0,0,0}; acc[mm][1]=(f32x4){0,0,0,0}; }
    __builtin_amdgcn_s_setprio(1);
    #pragma unroll
    for(int ks=0;ks<4;ks++){
      bf16x8 va[2], vb[2];
      #pragma unroll
      for(int mm=0;mm<2;mm++)
        va[mm] = *(const bf16x8*)&sP[(mm*16+l16)*PW + ks*32 + quad*8];
      #pragma unroll
      for(int p=0;p<2;p++)
        vb[p] = *(const bf16x8*)(W2t + ((2*w+p)*16+l16)*128 + ks*32 + quad*8);
      #pragma unroll
      for(int mm=0;mm<2;mm++)
        #pragma unroll
        for(int p=0;p<2;p++)
          acc[mm][p] = __builtin_amdgcn_mfma_f32_16x16x32_bf16(va[mm], vb[p], acc[mm][p], 0,0,0);
    }
    __builtin_amdgcn_s_setprio(0);
    #pragma unroll
    for(int mm=0;mm<2;mm++)
      #pragma unroll
      for(int p=0;p<2;p++){
        const int f = (2*w+p)*16 + l16;
        float bb = b2[f];
        #pragma unroll
        for(int r=0;r<4;r++)
          sWf[(mm*16+quad*4+r)*PW + f] = f16r(acc[mm][p][r] + bb);
      }
  }
  __syncthreads();
  {
    float h0v[8], h1v[8], w0v[8], w1v[8], fcv[8];
    #pragma unroll
    for(int s=0;s<8;s++){
      int lt = w*8 + s;
      int j = (lt < APM-1) ? (lt + (lt >= a ? 1 : 0)) : 0;
      fcv[s] = fcutf(sD[lt]);
      const float* hr = h + (size_t)(a0 + j)*FD;
      h0v[s] = hr[lane];
      h1v[s] = hr[lane + 64];
      w0v[s] = u16f(sWf[lt*PW + lane]);
      w1v[s] = u16f(sWf[lt*PW + lane + 64]);
    }
    float r0 = 0.f, r1 = 0.f;
    #pragma unroll
    for(int s=0;s<8;s++){
      r0 += h0v[s] * w0v[s] * fcv[s];
      r1 += h1v[s] * w1v[s] * fcv[s];
    }
    sRed[w*128 + lane]      = r0;
    sRed[w*128 + lane + 64] = r1;
  }
  __syncthreads();
  if(tid < 128){
    float v = sRed[tid] + sRed[128+tid] + sRed[256+tid] + sRed[384+tid];
    agg[(size_t)(a0+a)*FD + tid] = v;
  }
}

// ---- Edge backward v12 (verified) ----
__global__ __launch_bounds__(256) void k_edge_bwd12(
    const float* __restrict__ h, const float* __restrict__ AB,
    const float* __restrict__ De,
    const u16* __restrict__ W1t, const float* __restrict__ b1,
    const u16* __restrict__ W1b, const u16* __restrict__ W2r,
    const u16* __restrict__ W2t, const float* __restrict__ b2,
    float* __restrict__ DBe, float* __restrict__ HB, int EPM){
  __shared__ u16 srbfb[32*32];
  __shared__ u16 sP [32*PW];
  __shared__ u16 sWf[32*PW];
  __shared__ float sD[32];
  __shared__ float sRed[4*128];
  __shared__ float sdb[32*2];
  __shared__ float sfb[32];
  const int tid = threadIdx.x;
  const int nb = gridDim.x;
  const int P = ((nb & 7) == 0) ? ((blockIdx.x & 7)*(nb >> 3) + (blockIdx.x >> 3)) : blockIdx.x;
  const int m = P >> 5, a = P & 31;
  const int a0 = m*APM;
  const int eb = m*EPM + a*(APM-1);
  if(tid < 32) sD[tid] = (tid < APM-1) ? De[eb + tid] : (CUTF + 1.f);
  __syncthreads();
  const float step = CUTF/19.0f;
  const float coef = -0.5f/(step*step);
  {
    #pragma unroll
    for(int q=0;q<4;q++){
      int idx = q*256 + tid;
      int lt = idx >> 5, k = idx & 31;
      float x = sD[lt] - step*(float)k;
      srbfb[idx] = (k < NRBF) ? f16r(__expf(coef*x*x)) : (u16)0;
    }
  }
  __syncthreads();
  const int w = tid >> 6, lane = tid & 63;
  const int quad = lane >> 4, l16 = lane & 15;
  {
    f32x4 acc[2][2];
    #pragma unroll
    for(int mm=0;mm<2;mm++){ acc[mm][0]=(f32x4){0,0,0,0}; acc[mm][1]=(f32x4){0,0,0,0}; }
    bf16x8 va[2], vb[2];
    #pragma unroll
    for(int mm=0;mm<2;mm++)
      va[mm] = *(const bf16x8*)&srbfb[(mm*16+l16)*32 + quad*8];
    #pragma unroll
    for(int p=0;p<2;p++)
      vb[p] = *(const bf16x8*)(W1t + ((2*w+p)*16+l16)*32 + quad*8);
    #pragma unroll
    for(int mm=0;mm<2;mm++)
      #pragma unroll
      for(int p=0;p<2;p++)
        acc[mm][p] = __builtin_amdgcn_mfma_f32_16x16x32_bf16(va[mm], vb[p], acc[mm][p], 0,0,0);
    #pragma unroll
    for(int mm=0;mm<2;mm++)
      #pragma unroll
      for(int p=0;p<2;p++){
        const int c = (2*w+p)*16 + l16;
        float bb = b1[c];
        #pragma unroll
        for(int r=0;r<4;r++)
          sP[(mm*16+quad*4+r)*PW + c] = f16r(sspf(acc[mm][p][r] + bb));
      }
  }
  __syncthreads();
  {
    f32x4 acc[2][2];
    #pragma unroll
    for(int mm=0;mm<2;mm++){ acc[mm][0]=(f32x4){0,0,0,0}; acc[mm][1]=(f32x4){0,0,0,0}; }
    __builtin_amdgcn_s_setprio(1);
    #pragma unroll
    for(int ks=0;ks<4;ks++){
      bf16x8 va[2], vb[2];
      #pragma unroll
      for(int mm=0;mm<2;mm++)
        va[mm] = *(const bf16x8*)&sP[(mm*16+l16)*PW + ks*32 + quad*8];
      #pragma unroll
      for(int p=0;p<2;p++)
        vb[p] = *(const bf16x8*)(W2t + ((2*w+p)*16+l16)*128 + ks*32 + quad*8);
      #pragma unroll
      for(int mm=0;mm<2;mm++)
        #pragma unroll
        for(int p=0;p<2;p++)
          acc[mm][p] = __builtin_amdgcn_mfma_f32_16x16x32_bf16(va[mm], vb[p], acc[mm][p], 0,0,0);
    }
    __builtin_amdgcn_s_setprio(0);
    #pragma unroll
    for(int mm=0;mm<2;mm++)
      #pragma unroll
      for(int p=0;p<2;p++){
        const int f = (2*w+p)*16 + l16;
        float bb = b2[f];
        #pragma unroll
        for(int r=0;r<4;r++)
          sWf[(mm*16+quad*4+r)*PW + f] = f16r(acc[mm][p][r] + bb);
      }
  }
  __syncthreads();
  {
    float ab0 = AB[(size_t)(a0+a)*FD + lane];
    float ab1 = AB[(size_t)(a0+a)*FD + lane + 64];
    float h0v[8], h1v[8], a0v[8], a1v[8], w0v[8], w1v[8], fcv[8];
    #pragma unroll
    for(int s=0;s<8;s++){
      int lt = w*8 + s;
      int j = (lt < APM-1) ? (lt + (lt >= a ? 1 : 0)) : 0;
      fcv[s] = fcutf(sD[lt]);
      const float* hr  = h  + (size_t)(a0 + j)*FD;
      const float* abr = AB + (size_t)(a0 + j)*FD;
      h0v[s] = hr[lane];
      h1v[s] = hr[lane + 64];
      a0v[s] = abr[lane];
      a1v[s] = abr[lane + 64];
      w0v[s] = u16f(sWf[lt*PW + lane]);
      w1v[s] = u16f(sWf[lt*PW + lane + 64]);
    }
    float r0 = 0.f, r1 = 0.f;
    float pfv[8];
    #pragma unroll
    for(int s=0;s<8;s++){
      int lt = w*8 + s;
      float fc = fcv[s];
      r0 += a0v[s] * w0v[s] * fc;
      r1 += a1v[s] * w1v[s] * fc;
      float g0 = ab0*h0v[s], g1 = ab1*h1v[s];
      sWf[lt*PW + lane]      = f16r(g0*fc);
      sWf[lt*PW + lane + 64] = f16r(g1*fc);
      pfv[s] = g0*w0v[s] + g1*w1v[s];
    }
    #pragma unroll
    for(int d2=1; d2<64; d2<<=1){
      #pragma unroll
      for(int s=0;s<8;s++) pfv[s] += __shfl_xor(pfv[s], d2);
    }
    if(lane == 0){
      #pragma unroll
      for(int s=0;s<8;s++) sfb[w*8 + s] = pfv[s];
    }
    sRed[w*128 + lane]      = r0;
    sRed[w*128 + lane + 64] = r1;
  }
  __syncthreads();
  if(tid < 128){
    float v = sRed[tid] + sRed[128+tid] + sRed[256+tid] + sRed[384+tid];
    HB[(size_t)(a0+a)*FD + tid] = v;
  }
  {
    f32x4 acc[2][2];
    #pragma unroll
    for(int mm=0;mm<2;mm++){ acc[mm][0]=(f32x4){0,0,0,0}; acc[mm][1]=(f32x4){0,0,0,0}; }
    __builtin_amdgcn_s_setprio(1);
    #pragma unroll
    for(int ks=0;ks<4;ks++){
      bf16x8 va[2], vb[2];
      #pragma unroll
      for(int mm=0;mm<2;mm++)
        va[mm] = *(const bf16x8*)&sWf[(mm*16+l16)*PW + ks*32 + quad*8];
      #pragma unroll
      for(int p=0;p<2;p++)
        vb[p] = *(const bf16x8*)(W2r + ((2*w+p)*16+l16)*128 + ks*32 + quad*8);
      #pragma unroll
      for(int mm=0;mm<2;mm++)
        #pragma unroll
        for(int p=0;p<2;p++)
          acc[mm][p] = __builtin_amdgcn_mfma_f32_16x16x32_bf16(va[mm], vb[p], acc[mm][p], 0,0,0);
    }
    __builtin_amdgcn_s_setprio(0);
    #pragma unroll
    for(int mm=0;mm<2;mm++)
      #pragma unroll
      for(int p=0;p<2;p++){
        const int c = (2*w+p)*16 + l16;
        #pragma unroll
        for(int r=0;r<4;r++){
          const int row = mm*16 + quad*4 + r;
          float Pv = u16f(sP[row*PW + c]);
          float sig = 1.0f - 0.5f*__expf(-Pv);
          sP[row*PW + c] = f16r(acc[mm][p][r] * sig);
        }
      }
  }
  __syncthreads();
  {
    const int m3 = w >> 1, p3 = w & 1;
    f32x4 acc = (f32x4){0,0,0,0};
    #pragma unroll
    for(int ks=0;ks<4;ks++){
      bf16x8 va = *(const bf16x8*)&sP[(m3*16+l16)*PW + ks*32 + quad*8];
      bf16x8 vb = *(const bf16x8*)(W1b + (p3*16+l16)*128 + ks*32 + quad*8);
      acc = __builtin_amdgcn_mfma_f32_16x16x32_bf16(va, vb, acc, 0,0,0);
    }
    const int kr = p3*16 + l16;
    float s0[4];
    #pragma unroll
    for(int r=0;r<4;r++){
      int lt = m3*16 + quad*4 + r;
      float v = 0.f;
      if(kr < NRBF){
        float x = sD[lt] - step*(float)kr;
        float rb = __expf(coef*x*x);
        v = acc[r] * rb * (2.f*coef*x);
      }
      s0[r] = v;
    }
    #pragma unroll
    for(int d2=1; d2<16; d2<<=1){
      #pragma unroll
      for(int r=0;r<4;r++) s0[r] += __shfl_xor(s0[r], d2);
    }
    if(l16 == 0){
      #pragma unroll
      for(int r=0;r<4;r++) sdb[(m3*16+quad*4+r)*2 + p3] = s0[r];
    }
  }
  __syncthreads();
  if(tid < APM-1){
    const float d = sD[tid];
    float dfc = (d < CUTF) ? (-0.5f*(PI_F/CUTF)*__sinf(PI_F*d/CUTF)) : 0.f;
    DBe[eb + tid] += sdb[tid*2+0] + sdb[tid*2+1] + sfb[tid]*dfc;
  }
}

// ---- Head via MFMA: U = X3@aW1 (+ssp/sig, pe reduce), XB = sg@aW1^T ----
__global__ __launch_bounds__(256) void k_head_m(const float* __restrict__ X3,
    const u16* __restrict__ A1t, const u16* __restrict__ A1d,
    const float* __restrict__ ab1, const float* __restrict__ aW2,
    const float* __restrict__ ab2, const int* __restrict__ mol,
    float* __restrict__ Emol, float* __restrict__ XB, int N){
  __shared__ u16 sx[64*PW];      // X3 bf16
  __shared__ u16 sg[64*72];      // sig*aW2 bf16 (pitch 72: 144B rows, 16B-aligned)
  __shared__ float spe[64*4];    // per-wave pe partials
  const int tid = threadIdx.x;
  const int base = blockIdx.x*64;
  #pragma unroll
  for(int q=0;q<8;q++){
    int e = q*256 + tid;
    int r = e >> 5, c4 = (e & 31)*4;
    int row = base + r; if(row >= N) row = N-1;
    float4 v = *(const float4*)(X3 + (size_t)row*FD + c4);
    sx[r*PW + c4+0] = f16r(v.x);
    sx[r*PW + c4+1] = f16r(v.y);
    sx[r*PW + c4+2] = f16r(v.z);
    sx[r*PW + c4+3] = f16r(v.w);
  }
  __syncthreads();
  const int w = tid >> 6, lane = tid & 63;
  const int quad = lane >> 4, l16 = lane & 15;
  { // Phase A: U[64][64] = sx @ A1t^T; wave w owns n-tile w (cols w*16+l16)
    f32x4 acc[4];
    #pragma unroll
    for(int mt=0;mt<4;mt++) acc[mt] = (f32x4){0,0,0,0};
    __builtin_amdgcn_s_setprio(1);
    #pragma unroll
    for(int ks=0;ks<4;ks++){
      bf16x8 vb = *(const bf16x8*)(A1t + (w*16+l16)*128 + ks*32 + quad*8);
      #pragma unroll
      for(int mt=0;mt<4;mt++){
        bf16x8 va = *(const bf16x8*)&sx[(mt*16+l16)*PW + ks*32 + quad*8];
        acc[mt] = __builtin_amdgcn_mfma_f32_16x16x32_bf16(va, vb, acc[mt], 0,0,0);
      }
    }
    __builtin_amdgcn_s_setprio(0);
    const int c = w*16 + l16;
    const float b1c = ab1[c];
    const float aw2c = aW2[c];
    float pv[16];
    #pragma unroll
    for(int mt=0;mt<4;mt++)
      #pragma unroll
      for(int r=0;r<4;r++){
        float y = acc[mt][r] + b1c;
        pv[mt*4+r] = sspf(y)*aw2c;
        sg[(mt*16+quad*4+r)*72 + c] = f16r(sigf(y)*aw2c);
      }
    #pragma unroll
    for(int d2=1; d2<16; d2<<=1){
      #pragma unroll
      for(int t2=0;t2<16;t2++) pv[t2] += __shfl_xor(pv[t2], d2);
    }
    if(l16 == 0){
      #pragma unroll
      for(int mt=0;mt<4;mt++)
        #pragma unroll
        for(int r=0;r<4;r++)
          spe[(mt*16+quad*4+r)*4 + w] = pv[mt*4+r];
    }
  }
  __syncthreads();
  if(tid < 64){
    int row = base + tid;
    if(row < N){
      float pe = spe[tid*4+0] + spe[tid*4+1] + spe[tid*4+2] + spe[tid*4+3] + ab2[0];
      atomicAdd(&Emol[mol[row]], pe);
    }
  }
  { // Phase B: XB[64][128] = sg @ A1d^T; wave w owns n-tiles {2w,2w+1}
    f32x4 acc[4][2];
    #pragma unroll
    for(int mt=0;mt<4;mt++){ acc[mt][0]=(f32x4){0,0,0,0}; acc[mt][1]=(f32x4){0,0,0,0}; }
    __builtin_amdgcn_s_setprio(1);
    #pragma unroll
    for(int ks=0;ks<2;ks++){
      bf16x8 vb[2];
      #pragma unroll
      for(int p=0;p<2;p++)
        vb[p] = *(const bf16x8*)(A1d + ((2*w+p)*16+l16)*64 + ks*32 + quad*8);
      #pragma unroll
      for(int mt=0;mt<4;mt++){
        bf16x8 va = *(const bf16x8*)&sg[(mt*16+l16)*72 + ks*32 + quad*8];
        #pragma unroll
        for(int p=0;p<2;p++)
          acc[mt][p] = __builtin_amdgcn_mfma_f32_16x16x32_bf16(va, vb[p], acc[mt][p], 0,0,0);
      }
    }
    __builtin_amdgcn_s_setprio(0);
    #pragma unroll
    for(int mt=0;mt<4;mt++)
      #pragma unroll
      for(int p=0;p<2;p++){
        const int f = (2*w+p)*16 + l16;
        #pragma unroll
        for(int r=0;r<4;r++){
          int row = base + mt*16 + quad*4 + r;
          if(row < N) XB[(size_t)row*FD + f] = acc[mt][p][r];
        }
      }
  }
}

__global__ __launch_bounds__(256) void k_grad(const float* __restrict__ pos,
    const int* __restrict__ Ii, const int* __restrict__ Ij,
    const float* __restrict__ De, const float* __restrict__ DBe,
    float* __restrict__ G, int E){
  int e = blockIdx.x*256 + threadIdx.x;
  if(e >= E) return;
  if(De[e] >= CUTF) return;
  float s = DBe[e] / De[e];
  int i = Ii[e], j = Ij[e];
  float dx = s*(pos[i*3+0]-pos[j*3+0]);
  float dy = s*(pos[i*3+1]-pos[j*3+1]);
  float dz = s*(pos[i*3+2]-pos[j*3+2]);
  atomicAdd(&G[i*3+0], dx); atomicAdd(&G[i*3+1], dy); atomicAdd(&G[i*3+2], dz);
  atomicAdd(&G[j*3+0], -dx); atomicAdd(&G[j*3+1], -dy); atomicAdd(&G[j*3+2], -dz);
}

__global__ __launch_bounds__(256) void k_norm(const float* __restrict__ G,
    const int* __restrict__ mol, u32* __restrict__ maxnU, int N){
  int n = blockIdx.x*256 + threadIdx.x;
  if(n >= N) return;
  float ax = G[n*3], ay = G[n*3+1], az = G[n*3+2];
  float nrm = sqrtf(ax*ax+ay*ay+az*az);
  atomicMax(&maxnU[mol[n]], __float_as_uint(nrm));
}

__global__ __launch_bounds__(256) void k_apply(const float* __restrict__ G,
    const int* __restrict__ mol, const u32* __restrict__ maxnU,
    float* __restrict__ outA, int N){
  int n = blockIdx.x*256 + threadIdx.x;
  if(n >= N) return;
  float mx = __uint_as_float(maxnU[mol[n]]);
  float coefc = fminf(1.0f/fmaxf(mx, 1e-8f), 1.0f);
  outA[n*3+0] = -G[n*3+0]*coefc;
  outA[n*3+1] = -G[n*3+1]*coefc;
  outA[n*3+2] = -G[n*3+2]*coefc;
}

extern "C" void kernel_launch(void* const* d_in, const int* in_sizes, int n_in,
                              void* d_out, int out_size, void* d_ws, size_t ws_size,
                              hipStream_t stream) {
  (void)n_in;
  const float* pos  = (const float*)d_in[0];
  const float* emb  = (const float*)d_in[1];
  const float* in2f = (const float*)d_in[2];
  const float* fW1  = (const float*)d_in[3];
  const float* fb1  = (const float*)d_in[4];
  const float* fW2  = (const float*)d_in[5];
  const float* fb2  = (const float*)d_in[6];
  const float* oW1  = (const float*)d_in[7];
  const float* ob1  = (const float*)d_in[8];
  const float* oW2  = (const float*)d_in[9];
  const float* ob2  = (const float*)d_in[10];
  const float* aW1  = (const float*)d_in[11];
  const float* ab1  = (const float*)d_in[12];
  const float* aW2  = (const float*)d_in[13];
  const float* ab2  = (const float*)d_in[14];
  const int*   Z    = (const int*)d_in[15];
  const int*   Ii   = (const int*)d_in[16];
  const int*   Ij   = (const int*)d_in[17];
  const int*   mol  = (const int*)d_in[18];
  const int N = in_sizes[15];
  const int E = in_sizes[16];
  const int M = out_size - N*3;
  const int EPM = E / M;           // 992
  const size_t NFE = (size_t)N*FD;
  float* outF = (float*)d_out;
  float* outE = outF + (size_t)N*3;
  float* ws = (float*)d_ws;
  const size_t base_u32 = 11*NFE + 2*(size_t)E + 3*(WLSZ/2) + 3*(W2LSZ/2) + 8192 + 64;
  if(ws_size < base_u32*4) return;
  const int hsave = (ws_size >= (base_u32 + 3*NFE)*4);

  float* X0  = ws;
  float* SV0 = ws + 4*NFE;
  float* H   = ws + 7*NFE;
  float* AGG = ws + 8*NFE;
  float* XB  = ws + 9*NFE;
  float* HB  = ws + 10*NFE;
  float* De  = ws + 11*NFE;
  float* DBe = De + E;
  u16*   WB  = (u16*)(DBe + E);
  u16*   WB2 = WB + 3*WLSZ;
  u16*   WB3 = WB2 + 3*W2LSZ;             // 16384 u16 (head weights)
  float* Hsv = (float*)(WB3 + 16384);     // 3*NFE floats (hsave only)
  float* G    = AGG;
  u32*  maxnU = (u32*)H;

  const int gN   = (int)((NFE + 255)/256);
  const int gE   = (E + 255)/256;
  const int gRow = (N + 31)/32;
  const int gHead= (N + 63)/64;

  k_embed<<<gN,256,0,stream>>>(emb, Z, X0, (int)NFE);
  k_edge_geom<<<gE,256,0,stream>>>(pos, Ii, Ij, De, DBe, E);
  k_prep<<<(3*WLSZ+255)/256,256,0,stream>>>(fW1, fW2, WB);
  k_prep2<<<(3*W2LSZ+255)/256,256,0,stream>>>(in2f, oW1, oW2, WB2);
  k_prep3<<<64,256,0,stream>>>(aW1, WB3);
  for(int l=0;l<3;l++){
    float* Xl  = X0 + (size_t)l*NFE;
    float* Xn  = X0 + (size_t)(l+1)*NFE;
    float* SVl = SV0 + (size_t)l*NFE;
    const u16* W1t = WB + l*WLSZ;
    const u16* W2t = W1t + 24576;
    const u16* d = WB2 + l*W2LSZ;
    const u16 *in2f_t = d, *oW1_t = d + 32768, *oW2_t = d + 65536;
    float* Hl = hsave ? (Hsv + (size_t)l*NFE) : H;
    k_gemmb<<<gRow,256,0,stream>>>(Xl, in2f_t, nullptr, nullptr, nullptr, Hl, nullptr, 0, N);
    k_edge_fwd11<<<N,256,0,stream>>>(Hl, De, W1t, fb1 + l*128, W2t, fb2 + l*128, AGG, EPM);
    k_gemmf<<<gRow,256,0,stream>>>(AGG, oW1_t, ob1 + l*128, oW2_t, ob2 + l*128, Xl, nullptr, Xn, SVl, 1, N);
  }
  k_zero<<<(M+255)/256,256,0,stream>>>(outE, M);
  k_head_m<<<gHead,256,0,stream>>>(X0 + 3*NFE, WB3, WB3 + 8192, ab1, aW2, ab2, mol, outE, XB, N);
  for(int l=2;l>=0;l--){
    float* Xl  = X0 + (size_t)l*NFE;
    float* SVl = SV0 + (size_t)l*NFE;
    const u16* W1t = WB + l*WLSZ;
    const u16* W1b = W1t + 4096;
    const u16* W2r = W1t + 8192;
    const u16* W2t = W1t + 24576;
    const u16* d = WB2 + l*W2LSZ;
    const u16 *in2f_t = d, *in2f_d = d + 16384, *oW1_d = d + 49152, *oW2_d = d + 81920;
    k_gemmf<<<gRow,256,0,stream>>>(XB, oW2_d, nullptr, oW1_d, nullptr, nullptr, SVl, AGG, nullptr, 0, N);
    float* Hl;
    if(hsave){
      Hl = Hsv + (size_t)l*NFE;
    } else {
      Hl = H;
      k_gemmb<<<gRow,256,0,stream>>>(Xl, in2f_t, nullptr, nullptr, nullptr, H, nullptr, 0, N);
    }
    k_edge_bwd12<<<N,256,0,stream>>>(Hl, AGG, De, W1t, fb1 + l*128, W1b, W2r, W2t, fb2 + l*128, DBe, HB, EPM);
    k_gemmb<<<gRow,256,0,stream>>>(HB, in2f_d, nullptr, XB, nullptr, XB, nullptr, 0, N);
  }
  k_zero<<<(N*3+255)/256,256,0,stream>>>(G, N*3);
  k_zero<<<(M+255)/256,256,0,stream>>>((float*)maxnU, M);
  k_grad<<<gE,256,0,stream>>>(pos, Ii, Ij, De, DBe, G, E);
  k_norm<<<(N+255)/256,256,0,stream>>>(G, mol, maxnU, N);
  k_apply<<<(N+255)/256,256,0,stream>>>(G, mol, maxnU, outF, N);
}

// Round 20
// 1266.160 us; speedup vs baseline: 1.0571x; 1.0030x over previous
//
#include <hip/hip_runtime.h>
#include <cstddef>

// SchNet fwd energy + force bwd, MI355X. Round 29: R19 base (1270us verified)
// + (1) bwd phase-7/8 merged: phase-7 waves atomicAdd their reduced dbar
// partials straight into DBe (sfb*dfc folded into the p3==0 contribution) --
// drops the 7th barrier, sdb staging, and phase 8 (FP delta = commutation of
// two adds, 1-ulp class); (2) __launch_bounds__(256,8) on edge kernels
// (VGPR 56 <= 64 so codegen unchanged; removes declared-occupancy cap).

#define FD     128
#define NRBF   20
#define CUTF   5.0f
#define PI_F   3.14159265358979f
#define PW     136    // u16 pitch for sP/sWf/sA
#define WLSZ   40960  // u16 per layer in edge-weight workspace
#define W2LSZ  98304  // u16 per layer in dense-weight workspace (6 x 16384)
#define APM    32     // atoms per molecule

typedef unsigned short u16;
typedef unsigned int   u32;
typedef __attribute__((ext_vector_type(8))) short bf16x8;
typedef __attribute__((ext_vector_type(4))) float f32x4;

__device__ __forceinline__ float u16f(u16 x){ union{u32 i; float f;} v; v.i=((u32)x)<<16; return v.f; }
// Manual RNE bf16 rounding -- VERIFIED. Do NOT replace with inline-asm
// v_cvt_pk_bf16_f32: R10 isolated A/B proved that path numerically wrong here.
__device__ __forceinline__ u16 f16r(float f){ union{float f; u32 i;} v; v.f=f; u32 r=v.i+0x7fffu+((v.i>>16)&1u); return (u16)(r>>16); }
__device__ __forceinline__ float sspf(float x){
  return fmaxf(x,0.f) + __logf(1.f + __expf(-fabsf(x))) - 0.6931471805599453f;
}
__device__ __forceinline__ float sigf(float x){
  return __fdividef(1.f, 1.f + __expf(-x));
}
__device__ __forceinline__ float fcutf(float d){ return (d < CUTF) ? 0.5f*(__cosf(PI_F*d/CUTF)+1.f) : 0.f; }

__global__ __launch_bounds__(256) void k_zero(float* __restrict__ p, int n){
  int i = blockIdx.x*256 + threadIdx.x;
  if(i < n) p[i] = 0.f;
}

__global__ __launch_bounds__(256) void k_embed(const float* __restrict__ emb, const int* __restrict__ Z,
                                               float* __restrict__ X0, int n){
  int idx = blockIdx.x*256 + threadIdx.x;
  if(idx >= n) return;
  int a = idx >> 7, f = idx & 127;
  X0[idx] = emb[Z[a]*FD + f];
}

__global__ __launch_bounds__(256) void k_edge_geom(const float* __restrict__ pos,
    const int* __restrict__ Ii, const int* __restrict__ Ij,
    float* __restrict__ De, float* __restrict__ DBe, int E){
  int e = blockIdx.x*256 + threadIdx.x;
  if(e >= E) return;
  int i = Ii[e], j = Ij[e];
  float dx = pos[j*3+0]-pos[i*3+0];
  float dy = pos[j*3+1]-pos[i*3+1];
  float dz = pos[j*3+2]-pos[i*3+2];
  De[e] = sqrtf(dx*dx+dy*dy+dz*dz + 1e-12f);
  DBe[e] = 0.f;
}

// Edge-filter bf16 weight pre-conversion (once per launch).
__global__ __launch_bounds__(256) void k_prep(const float* __restrict__ fW1,
    const float* __restrict__ fW2, u16* __restrict__ WB){
  int idx = blockIdx.x*256 + threadIdx.x;
  if(idx >= 3*WLSZ) return;
  int l = idx / WLSZ, r = idx - l*WLSZ;
  const float* W1 = fW1 + l*2560;
  const float* W2 = fW2 + l*16384;
  u16* out = WB + l*WLSZ;
  if(r < 4096){
    int c = r >> 5, k = r & 31;
    out[r] = (k < NRBF) ? f16r(W1[k*128 + c]) : (u16)0;
  } else if(r < 8192){
    int rr = r - 4096;
    int k = rr >> 7, c = rr & 127;
    out[r] = (k < NRBF) ? f16r(W1[k*128 + c]) : (u16)0;
  } else if(r < 24576){
    out[r] = f16r(W2[r - 8192]);
  } else {
    int rr = r - 24576;
    int f = rr >> 7, c = rr & 127;
    out[r] = f16r(W2[c*128 + f]);
  }
}

// Dense-layer bf16 weight pre-conversion: per layer, 6 matrices of [n][k]:
//   0: in2f^T  1: in2f  2: oW1^T  3: oW1  4: oW2^T  5: oW2
__global__ __launch_bounds__(256) void k_prep2(const float* __restrict__ in2f,
    const float* __restrict__ oW1, const float* __restrict__ oW2,
    u16* __restrict__ WB2){
  int idx = blockIdx.x*256 + threadIdx.x;
  if(idx >= 3*W2LSZ) return;
  int l = idx / W2LSZ, r = idx - l*W2LSZ;
  int mat = r >> 14, q = r & 16383;
  int n = q >> 7, k = q & 127;
  const float* src = (mat < 2) ? (in2f + l*16384) : (mat < 4) ? (oW1 + l*16384) : (oW2 + l*16384);
  float v = (mat & 1) ? src[n*128 + k] : src[k*128 + n];
  WB2[idx] = f16r(v);
}

// Head-weight bf16 pre-conversion: A1t [c=64][k=128] then A1d [f=128][c=64].
__global__ __launch_bounds__(256) void k_prep3(const float* __restrict__ aW1,
    u16* __restrict__ WB3){
  int idx = blockIdx.x*256 + threadIdx.x;
  if(idx >= 16384) return;
  if(idx < 8192){
    int c = idx >> 7, f = idx & 127;
    WB3[idx] = f16r(aW1[f*64 + c]);
  } else {
    WB3[idx] = f16r(aW1[idx - 8192]);   // [f][c] row-major direct
  }
}

// Dense GEMM via bf16 MFMA (verified R9/R15).
__global__ __launch_bounds__(256) void k_gemmb(const float* __restrict__ A,
    const u16* __restrict__ Bn, const float* __restrict__ bias,
    const float* __restrict__ res, const float* __restrict__ mul,
    float* __restrict__ out1, float* __restrict__ out2, int act, int Nr){
  __shared__ u16 sA[32*PW];
  const int tid = threadIdx.x;
  const int rb = blockIdx.x * 32;
  #pragma unroll
  for(int q=0;q<4;q++){
    int e = q*256 + tid;
    int r = e >> 5, c4 = (e & 31)*4;
    int rr = rb + r; if(rr >= Nr) rr = Nr-1;
    float4 v = *(const float4*)(A + (size_t)rr*FD + c4);
    sA[r*PW + c4+0] = f16r(v.x);
    sA[r*PW + c4+1] = f16r(v.y);
    sA[r*PW + c4+2] = f16r(v.z);
    sA[r*PW + c4+3] = f16r(v.w);
  }
  __syncthreads();
  const int w = tid >> 6, lane = tid & 63;
  const int quad = lane >> 4, l16 = lane & 15;
  f32x4 acc[2][2];
  #pragma unroll
  for(int mm=0;mm<2;mm++){ acc[mm][0]=(f32x4){0,0,0,0}; acc[mm][1]=(f32x4){0,0,0,0}; }
  __builtin_amdgcn_s_setprio(1);
  #pragma unroll
  for(int ks=0;ks<4;ks++){
    bf16x8 va[2], vb[2];
    #pragma unroll
    for(int mm=0;mm<2;mm++)
      va[mm] = *(const bf16x8*)&sA[(mm*16+l16)*PW + ks*32 + quad*8];
    #pragma unroll
    for(int p=0;p<2;p++)
      vb[p] = *(const bf16x8*)(Bn + ((2*w+p)*16+l16)*128 + ks*32 + quad*8);
    #pragma unroll
    for(int mm=0;mm<2;mm++)
      #pragma unroll
      for(int p=0;p<2;p++)
        acc[mm][p] = __builtin_amdgcn_mfma_f32_16x16x32_bf16(va[mm], vb[p], acc[mm][p], 0,0,0);
  }
  __builtin_amdgcn_s_setprio(0);
  #pragma unroll
  for(int mm=0;mm<2;mm++)
    #pragma unroll
    for(int p=0;p<2;p++){
      const int f = (2*w+p)*16 + l16;
      float bb = bias ? bias[f] : 0.f;
      #pragma unroll
      for(int r=0;r<4;r++){
        int row = rb + mm*16 + quad*4 + r;
        if(row >= Nr) continue;
        size_t o = (size_t)row*FD + f;
        float y = acc[mm][p][r] + bb;
        if(res) y += res[o];
        if(mul) y *= mul[o];
        if(act){ out1[o] = sspf(y); out2[o] = sigf(y); }
        else out1[o] = y;
      }
    }
}

// Fused dependent-GEMM pair (verified R16).
__global__ __launch_bounds__(256) void k_gemmf(const float* __restrict__ A,
    const u16* __restrict__ B1n, const float* __restrict__ b1,
    const u16* __restrict__ B2n, const float* __restrict__ b2,
    const float* __restrict__ res, const float* __restrict__ mulSV,
    float* __restrict__ out1, float* __restrict__ outSV, int mode, int Nr){
  __shared__ u16 sA[32*PW];
  __shared__ u16 sB[32*PW];
  const int tid = threadIdx.x;
  const int rb = blockIdx.x * 32;
  #pragma unroll
  for(int q=0;q<4;q++){
    int e = q*256 + tid;
    int r = e >> 5, c4 = (e & 31)*4;
    int rr = rb + r; if(rr >= Nr) rr = Nr-1;
    float4 v = *(const float4*)(A + (size_t)rr*FD + c4);
    sA[r*PW + c4+0] = f16r(v.x);
    sA[r*PW + c4+1] = f16r(v.y);
    sA[r*PW + c4+2] = f16r(v.z);
    sA[r*PW + c4+3] = f16r(v.w);
  }
  __syncthreads();
  const int w = tid >> 6, lane = tid & 63;
  const int quad = lane >> 4, l16 = lane & 15;
  { // GEMM1
    f32x4 acc[2][2];
    #pragma unroll
    for(int mm=0;mm<2;mm++){ acc[mm][0]=(f32x4){0,0,0,0}; acc[mm][1]=(f32x4){0,0,0,0}; }
    __builtin_amdgcn_s_setprio(1);
    #pragma unroll
    for(int ks=0;ks<4;ks++){
      bf16x8 va[2], vb[2];
      #pragma unroll
      for(int mm=0;mm<2;mm++)
        va[mm] = *(const bf16x8*)&sA[(mm*16+l16)*PW + ks*32 + quad*8];
      #pragma unroll
      for(int p=0;p<2;p++)
        vb[p] = *(const bf16x8*)(B1n + ((2*w+p)*16+l16)*128 + ks*32 + quad*8);
      #pragma unroll
      for(int mm=0;mm<2;mm++)
        #pragma unroll
        for(int p=0;p<2;p++)
          acc[mm][p] = __builtin_amdgcn_mfma_f32_16x16x32_bf16(va[mm], vb[p], acc[mm][p], 0,0,0);
    }
    __builtin_amdgcn_s_setprio(0);
    #pragma unroll
    for(int mm=0;mm<2;mm++)
      #pragma unroll
      for(int p=0;p<2;p++){
        const int f = (2*w+p)*16 + l16;
        float bb = (mode && b1) ? b1[f] : 0.f;
        #pragma unroll
        for(int r=0;r<4;r++){
          const int lrow = mm*16 + quad*4 + r;
          int row = rb + lrow;
          if(row >= Nr) row = Nr-1;
          size_t o = (size_t)row*FD + f;
          float y = acc[mm][p][r] + bb;
          float t;
          if(mode){
            t = sspf(y);
            if(rb + lrow < Nr) outSV[o] = sigf(y);
          } else {
            t = y * mulSV[o];
          }
          sB[lrow*PW + f] = f16r(t);
        }
      }
  }
  __syncthreads();
  { // GEMM2
    f32x4 acc[2][2];
    #pragma unroll
    for(int mm=0;mm<2;mm++){ acc[mm][0]=(f32x4){0,0,0,0}; acc[mm][1]=(f32x4){0,0,0,0}; }
    __builtin_amdgcn_s_setprio(1);
    #pragma unroll
    for(int ks=0;ks<4;ks++){
      bf16x8 va[2], vb[2];
      #pragma unroll
      for(int mm=0;mm<2;mm++)
        va[mm] = *(const bf16x8*)&sB[(mm*16+l16)*PW + ks*32 + quad*8];
      #pragma unroll
      for(int p=0;p<2;p++)
        vb[p] = *(const bf16x8*)(B2n + ((2*w+p)*16+l16)*128 + ks*32 + quad*8);
      #pragma unroll
      for(int mm=0;mm<2;mm++)
        #pragma unroll
        for(int p=0;p<2;p++)
          acc[mm][p] = __builtin_amdgcn_mfma_f32_16x16x32_bf16(va[mm], vb[p], acc[mm][p], 0,0,0);
    }
    __builtin_amdgcn_s_setprio(0);
    #pragma unroll
    for(int mm=0;mm<2;mm++)
      #pragma unroll
      for(int p=0;p<2;p++){
        const int f = (2*w+p)*16 + l16;
        float bb = (mode && b2) ? b2[f] : 0.f;
        #pragma unroll
        for(int r=0;r<4;r++){
          int row = rb + mm*16 + quad*4 + r;
          if(row >= Nr) continue;
          size_t o = (size_t)row*FD + f;
          float y = acc[mm][p][r] + bb;
          if(res) y += res[o];
          out1[o] = y;
        }
      }
  }
}

// ---- Edge forward v11 (verified) + occupancy hint ----
__global__ __launch_bounds__(256, 8) void k_edge_fwd11(
    const float* __restrict__ h,
    const float* __restrict__ De,
    const u16* __restrict__ W1t, const float* __restrict__ b1,
    const u16* __restrict__ W2t, const float* __restrict__ b2,
    float* __restrict__ agg, int EPM){
  __shared__ u16 srbfb[32*32];
  __shared__ u16 sP [32*PW];
  __shared__ u16 sWf[32*PW];
  __shared__ float sD[32];
  __shared__ float sRed[4*128];
  const int tid = threadIdx.x;
  const int nb = gridDim.x;
  const int P = ((nb & 7) == 0) ? ((blockIdx.x & 7)*(nb >> 3) + (blockIdx.x >> 3)) : blockIdx.x;
  const int m = P >> 5, a = P & 31;
  const int a0 = m*APM;
  const int eb = m*EPM + a*(APM-1);
  if(tid < 32) sD[tid] = (tid < APM-1) ? De[eb + tid] : (CUTF + 1.f);
  __syncthreads();
  const float step = CUTF/19.0f;
  const float coef = -0.5f/(step*step);
  {
    #pragma unroll
    for(int q=0;q<4;q++){
      int idx = q*256 + tid;
      int lt = idx >> 5, k = idx & 31;
      float x = sD[lt] - step*(float)k;
      srbfb[idx] = (k < NRBF) ? f16r(__expf(coef*x*x)) : (u16)0;
    }
  }
  __syncthreads();
  const int w = tid >> 6, lane = tid & 63;
  const int quad = lane >> 4, l16 = lane & 15;
  {
    f32x4 acc[2][2];
    #pragma unroll
    for(int mm=0;mm<2;mm++){ acc[mm][0]=(f32x4){0,0,0,0}; acc[mm][1]=(f32x4){0,0,0,0}; }
    bf16x8 va[2], vb[2];
    #pragma unroll
    for(int mm=0;mm<2;mm++)
      va[mm] = *(const bf16x8*)&srbfb[(mm*16+l16)*32 + quad*8];
    #pragma unroll
    for(int p=0;p<2;p++)
      vb[p] = *(const bf16x8*)(W1t + ((2*w+p)*16+l16)*32 + quad*8);
    #pragma unroll
    for(int mm=0;mm<2;mm++)
      #pragma unroll
      for(int p=0;p<2;p++)
        acc[mm][p] = __builtin_amdgcn_mfma_f32_16x16x32_bf16(va[mm], vb[p], acc[mm][p], 0,0,0);
    #pragma unroll
    for(int mm=0;mm<2;mm++)
      #pragma unroll
      for(int p=0;p<2;p++){
        const int c = (2*w+p)*16 + l16;
        float bb = b1[c];
        #pragma unroll
        for(int r=0;r<4;r++)
          sP[(mm*16+quad*4+r)*PW + c] = f16r(sspf(acc[mm][p][r] + bb));
      }
  }
  __syncthreads();
  {
    f32x4 acc[2][2];
    #pragma unroll
    for(int mm=0;mm<2;mm++){ acc[mm][0]=(f32x4){0,0,0,0}; acc[mm][1]=(f32x4){0,0,0,0}; }
    __builtin_amdgcn_s_setprio(1);
    #pragma unroll
    for(int ks=0;ks<4;ks++){
      bf16x8 va[2], vb[2];
      #pragma unroll
      for(int mm=0;mm<2;mm++)
        va[mm] = *(const bf16x8*)&sP[(mm*16+l16)*PW + ks*32 + quad*8];
      #pragma unroll
      for(int p=0;p<2;p++)
        vb[p] = *(const bf16x8*)(W2t + ((2*w+p)*16+l16)*128 + ks*32 + quad*8);
      #pragma unroll
      for(int mm=0;mm<2;mm++)
        #pragma unroll
        for(int p=0;p<2;p++)
          acc[mm][p] = __builtin_amdgcn_mfma_f32_16x16x32_bf16(va[mm], vb[p], acc[mm][p], 0,0,0);
    }
    __builtin_amdgcn_s_setprio(0);
    #pragma unroll
    for(int mm=0;mm<2;mm++)
      #pragma unroll
      for(int p=0;p<2;p++){
        const int f = (2*w+p)*16 + l16;
        float bb = b2[f];
        #pragma unroll
        for(int r=0;r<4;r++)
          sWf[(mm*16+quad*4+r)*PW + f] = f16r(acc[mm][p][r] + bb);
      }
  }
  __syncthreads();
  {
    float h0v[8], h1v[8], w0v[8], w1v[8], fcv[8];
    #pragma unroll
    for(int s=0;s<8;s++){
      int lt = w*8 + s;
      int j = (lt < APM-1) ? (lt + (lt >= a ? 1 : 0)) : 0;
      fcv[s] = fcutf(sD[lt]);
      const float* hr = h + (size_t)(a0 + j)*FD;
      h0v[s] = hr[lane];
      h1v[s] = hr[lane + 64];
      w0v[s] = u16f(sWf[lt*PW + lane]);
      w1v[s] = u16f(sWf[lt*PW + lane + 64]);
    }
    float r0 = 0.f, r1 = 0.f;
    #pragma unroll
    for(int s=0;s<8;s++){
      r0 += h0v[s] * w0v[s] * fcv[s];
      r1 += h1v[s] * w1v[s] * fcv[s];
    }
    sRed[w*128 + lane]      = r0;
    sRed[w*128 + lane + 64] = r1;
  }
  __syncthreads();
  if(tid < 128){
    float v = sRed[tid] + sRed[128+tid] + sRed[256+tid] + sRed[384+tid];
    agg[(size_t)(a0+a)*FD + tid] = v;
  }
}

// ---- Edge backward v13: R19 bwd12 + phase-7/8 merged via DBe atomics ----
__global__ __launch_bounds__(256, 8) void k_edge_bwd13(
    const float* __restrict__ h, const float* __restrict__ AB,
    const float* __restrict__ De,
    const u16* __restrict__ W1t, const float* __restrict__ b1,
    const u16* __restrict__ W1b, const u16* __restrict__ W2r,
    const u16* __restrict__ W2t, const float* __restrict__ b2,
    float* __restrict__ DBe, float* __restrict__ HB, int EPM){
  __shared__ u16 srbfb[32*32];
  __shared__ u16 sP [32*PW];
  __shared__ u16 sWf[32*PW];
  __shared__ float sD[32];
  __shared__ float sRed[4*128];
  __shared__ float sfb[32];
  const int tid = threadIdx.x;
  const int nb = gridDim.x;
  const int P = ((nb & 7) == 0) ? ((blockIdx.x & 7)*(nb >> 3) + (blockIdx.x >> 3)) : blockIdx.x;
  const int m = P >> 5, a = P & 31;
  const int a0 = m*APM;
  const int eb = m*EPM + a*(APM-1);
  if(tid < 32) sD[tid] = (tid < APM-1) ? De[eb + tid] : (CUTF + 1.f);
  __syncthreads();
  const float step = CUTF/19.0f;
  const float coef = -0.5f/(step*step);
  { // phase 1: rbf fill
    #pragma unroll
    for(int q=0;q<4;q++){
      int idx = q*256 + tid;
      int lt = idx >> 5, k = idx & 31;
      float x = sD[lt] - step*(float)k;
      srbfb[idx] = (k < NRBF) ? f16r(__expf(coef*x*x)) : (u16)0;
    }
  }
  __syncthreads();
  const int w = tid >> 6, lane = tid & 63;
  const int quad = lane >> 4, l16 = lane & 15;
  { // phase 2: P = ssp(rbf @ W1 + b1)
    f32x4 acc[2][2];
    #pragma unroll
    for(int mm=0;mm<2;mm++){ acc[mm][0]=(f32x4){0,0,0,0}; acc[mm][1]=(f32x4){0,0,0,0}; }
    bf16x8 va[2], vb[2];
    #pragma unroll
    for(int mm=0;mm<2;mm++)
      va[mm] = *(const bf16x8*)&srbfb[(mm*16+l16)*32 + quad*8];
    #pragma unroll
    for(int p=0;p<2;p++)
      vb[p] = *(const bf16x8*)(W1t + ((2*w+p)*16+l16)*32 + quad*8);
    #pragma unroll
    for(int mm=0;mm<2;mm++)
      #pragma unroll
      for(int p=0;p<2;p++)
        acc[mm][p] = __builtin_amdgcn_mfma_f32_16x16x32_bf16(va[mm], vb[p], acc[mm][p], 0,0,0);
    #pragma unroll
    for(int mm=0;mm<2;mm++)
      #pragma unroll
      for(int p=0;p<2;p++){
        const int c = (2*w+p)*16 + l16;
        float bb = b1[c];
        #pragma unroll
        for(int r=0;r<4;r++)
          sP[(mm*16+quad*4+r)*PW + c] = f16r(sspf(acc[mm][p][r] + bb));
      }
  }
  __syncthreads();
  { // phase 3: Wf = P@W2 + b2
    f32x4 acc[2][2];
    #pragma unroll
    for(int mm=0;mm<2;mm++){ acc[mm][0]=(f32x4){0,0,0,0}; acc[mm][1]=(f32x4){0,0,0,0}; }
    __builtin_amdgcn_s_setprio(1);
    #pragma unroll
    for(int ks=0;ks<4;ks++){
      bf16x8 va[2], vb[2];
      #pragma unroll
      for(int mm=0;mm<2;mm++)
        va[mm] = *(const bf16x8*)&sP[(mm*16+l16)*PW + ks*32 + quad*8];
      #pragma unroll
      for(int p=0;p<2;p++)
        vb[p] = *(const bf16x8*)(W2t + ((2*w+p)*16+l16)*128 + ks*32 + quad*8);
      #pragma unroll
      for(int mm=0;mm<2;mm++)
        #pragma unroll
        for(int p=0;p<2;p++)
          acc[mm][p] = __builtin_amdgcn_mfma_f32_16x16x32_bf16(va[mm], vb[p], acc[mm][p], 0,0,0);
    }
    __builtin_amdgcn_s_setprio(0);
    #pragma unroll
    for(int mm=0;mm<2;mm++)
      #pragma unroll
      for(int p=0;p<2;p++){
        const int f = (2*w+p)*16 + l16;
        float bb = b2[f];
        #pragma unroll
        for(int r=0;r<4;r++)
          sWf[(mm*16+quad*4+r)*PW + f] = f16r(acc[mm][p][r] + bb);
      }
  }
  __syncthreads();
  { // phase 4: HB accum + Wbar in-place + fbar (hoisted loads, batched butterfly)
    float ab0 = AB[(size_t)(a0+a)*FD + lane];
    float ab1 = AB[(size_t)(a0+a)*FD + lane + 64];
    float h0v[8], h1v[8], a0v[8], a1v[8], w0v[8], w1v[8], fcv[8];
    #pragma unroll
    for(int s=0;s<8;s++){
      int lt = w*8 + s;
      int j = (lt < APM-1) ? (lt + (lt >= a ? 1 : 0)) : 0;
      fcv[s] = fcutf(sD[lt]);
      const float* hr  = h  + (size_t)(a0 + j)*FD;
      const float* abr = AB + (size_t)(a0 + j)*FD;
      h0v[s] = hr[lane];
      h1v[s] = hr[lane + 64];
      a0v[s] = abr[lane];
      a1v[s] = abr[lane + 64];
      w0v[s] = u16f(sWf[lt*PW + lane]);
      w1v[s] = u16f(sWf[lt*PW + lane + 64]);
    }
    float r0 = 0.f, r1 = 0.f;
    float pfv[8];
    #pragma unroll
    for(int s=0;s<8;s++){
      int lt = w*8 + s;
      float fc = fcv[s];
      r0 += a0v[s] * w0v[s] * fc;
      r1 += a1v[s] * w1v[s] * fc;
      float g0 = ab0*h0v[s], g1 = ab1*h1v[s];
      sWf[lt*PW + lane]      = f16r(g0*fc);
      sWf[lt*PW + lane + 64] = f16r(g1*fc);
      pfv[s] = g0*w0v[s] + g1*w1v[s];
    }
    #pragma unroll
    for(int d2=1; d2<64; d2<<=1){
      #pragma unroll
      for(int s=0;s<8;s++) pfv[s] += __shfl_xor(pfv[s], d2);
    }
    if(lane == 0){
      #pragma unroll
      for(int s=0;s<8;s++) sfb[w*8 + s] = pfv[s];
    }
    sRed[w*128 + lane]      = r0;
    sRed[w*128 + lane + 64] = r1;
  }
  __syncthreads();
  if(tid < 128){
    float v = sRed[tid] + sRed[128+tid] + sRed[256+tid] + sRed[384+tid];
    HB[(size_t)(a0+a)*FD + tid] = v;
  }
  { // phase 5+6 merged: GEMM2; sigma-trick; tbar -> sP (thread-local RMW)
    f32x4 acc[2][2];
    #pragma unroll
    for(int mm=0;mm<2;mm++){ acc[mm][0]=(f32x4){0,0,0,0}; acc[mm][1]=(f32x4){0,0,0,0}; }
    __builtin_amdgcn_s_setprio(1);
    #pragma unroll
    for(int ks=0;ks<4;ks++){
      bf16x8 va[2], vb[2];
      #pragma unroll
      for(int mm=0;mm<2;mm++)
        va[mm] = *(const bf16x8*)&sWf[(mm*16+l16)*PW + ks*32 + quad*8];
      #pragma unroll
      for(int p=0;p<2;p++)
        vb[p] = *(const bf16x8*)(W2r + ((2*w+p)*16+l16)*128 + ks*32 + quad*8);
      #pragma unroll
      for(int mm=0;mm<2;mm++)
        #pragma unroll
        for(int p=0;p<2;p++)
          acc[mm][p] = __builtin_amdgcn_mfma_f32_16x16x32_bf16(va[mm], vb[p], acc[mm][p], 0,0,0);
    }
    __builtin_amdgcn_s_setprio(0);
    #pragma unroll
    for(int mm=0;mm<2;mm++)
      #pragma unroll
      for(int p=0;p<2;p++){
        const int c = (2*w+p)*16 + l16;
        #pragma unroll
        for(int r=0;r<4;r++){
          const int row = mm*16 + quad*4 + r;
          float Pv = u16f(sP[row*PW + c]);
          float sig = 1.0f - 0.5f*__expf(-Pv);
          sP[row*PW + c] = f16r(acc[mm][p][r] * sig);
        }
      }
  }
  __syncthreads();
  { // phase 7: GEMM3 (A from sP); dbar partials -> DBe via atomicAdd (no phase 8)
    const int m3 = w >> 1, p3 = w & 1;
    f32x4 acc = (f32x4){0,0,0,0};
    #pragma unroll
    for(int ks=0;ks<4;ks++){
      bf16x8 va = *(const bf16x8*)&sP[(m3*16+l16)*PW + ks*32 + quad*8];
      bf16x8 vb = *(const bf16x8*)(W1b + (p3*16+l16)*128 + ks*32 + quad*8);
      acc = __builtin_amdgcn_mfma_f32_16x16x32_bf16(va, vb, acc, 0,0,0);
    }
    const int kr = p3*16 + l16;
    float s0[4];
    #pragma unroll
    for(int r=0;r<4;r++){
      int lt = m3*16 + quad*4 + r;
      float v = 0.f;
      if(kr < NRBF){
        float x = sD[lt] - step*(float)kr;
        float rb = __expf(coef*x*x);
        v = acc[r] * rb * (2.f*coef*x);
      }
      s0[r] = v;
    }
    #pragma unroll
    for(int d2=1; d2<16; d2<<=1){
      #pragma unroll
      for(int r=0;r<4;r++) s0[r] += __shfl_xor(s0[r], d2);
    }
    if(l16 == 0){
      #pragma unroll
      for(int r=0;r<4;r++){
        int lt = m3*16 + quad*4 + r;
        if(lt < APM-1){
          float add = s0[r];
          if(p3 == 0){
            const float d = sD[lt];
            float dfc = (d < CUTF) ? (-0.5f*(PI_F/CUTF)*__sinf(PI_F*d/CUTF)) : 0.f;
            add += sfb[lt]*dfc;
          }
          atomicAdd(&DBe[eb + lt], add);
        }
      }
    }
  }
}

// ---- Head via MFMA (verified R19) ----
__global__ __launch_bounds__(256) void k_head_m(const float* __restrict__ X3,
    const u16* __restrict__ A1t, const u16* __restrict__ A1d,
    const float* __restrict__ ab1, const float* __restrict__ aW2,
    const float* __restrict__ ab2, const int* __restrict__ mol,
    float* __restrict__ Emol, float* __restrict__ XB, int N){
  __shared__ u16 sx[64*PW];
  __shared__ u16 sg[64*72];
  __shared__ float spe[64*4];
  const int tid = threadIdx.x;
  const int base = blockIdx.x*64;
  #pragma unroll
  for(int q=0;q<8;q++){
    int e = q*256 + tid;
    int r = e >> 5, c4 = (e & 31)*4;
    int row = base + r; if(row >= N) row = N-1;
    float4 v = *(const float4*)(X3 + (size_t)row*FD + c4);
    sx[r*PW + c4+0] = f16r(v.x);
    sx[r*PW + c4+1] = f16r(v.y);
    sx[r*PW + c4+2] = f16r(v.z);
    sx[r*PW + c4+3] = f16r(v.w);
  }
  __syncthreads();
  const int w = tid >> 6, lane = tid & 63;
  const int quad = lane >> 4, l16 = lane & 15;
  {
    f32x4 acc[4];
    #pragma unroll
    for(int mt=0;mt<4;mt++) acc[mt] = (f32x4){0,0,0,0};
    __builtin_amdgcn_s_setprio(1);
    #pragma unroll
    for(int ks=0;ks<4;ks++){
      bf16x8 vb = *(const bf16x8*)(A1t + (w*16+l16)*128 + ks*32 + quad*8);
      #pragma unroll
      for(int mt=0;mt<4;mt++){
        bf16x8 va = *(const bf16x8*)&sx[(mt*16+l16)*PW + ks*32 + quad*8];
        acc[mt] = __builtin_amdgcn_mfma_f32_16x16x32_bf16(va, vb, acc[mt], 0,0,0);
      }
    }
    __builtin_amdgcn_s_setprio(0);
    const int c = w*16 + l16;
    const float b1c = ab1[c];
    const float aw2c = aW2[c];
    float pv[16];
    #pragma unroll
    for(int mt=0;mt<4;mt++)
      #pragma unroll
      for(int r=0;r<4;r++){
        float y = acc[mt][r] + b1c;
        pv[mt*4+r] = sspf(y)*aw2c;
        sg[(mt*16+quad*4+r)*72 + c] = f16r(sigf(y)*aw2c);
      }
    #pragma unroll
    for(int d2=1; d2<16; d2<<=1){
      #pragma unroll
      for(int t2=0;t2<16;t2++) pv[t2] += __shfl_xor(pv[t2], d2);
    }
    if(l16 == 0){
      #pragma unroll
      for(int mt=0;mt<4;mt++)
        #pragma unroll
        for(int r=0;r<4;r++)
          spe[(mt*16+quad*4+r)*4 + w] = pv[mt*4+r];
    }
  }
  __syncthreads();
  if(tid < 64){
    int row = base + tid;
    if(row < N){
      float pe = spe[tid*4+0] + spe[tid*4+1] + spe[tid*4+2] + spe[tid*4+3] + ab2[0];
      atomicAdd(&Emol[mol[row]], pe);
    }
  }
  {
    f32x4 acc[4][2];
    #pragma unroll
    for(int mt=0;mt<4;mt++){ acc[mt][0]=(f32x4){0,0,0,0}; acc[mt][1]=(f32x4){0,0,0,0}; }
    __builtin_amdgcn_s_setprio(1);
    #pragma unroll
    for(int ks=0;ks<2;ks++){
      bf16x8 vb[2];
      #pragma unroll
      for(int p=0;p<2;p++)
        vb[p] = *(const bf16x8*)(A1d + ((2*w+p)*16+l16)*64 + ks*32 + quad*8);
      #pragma unroll
      for(int mt=0;mt<4;mt++){
        bf16x8 va = *(const bf16x8*)&sg[(mt*16+l16)*72 + ks*32 + quad*8];
        #pragma unroll
        for(int p=0;p<2;p++)
          acc[mt][p] = __builtin_amdgcn_mfma_f32_16x16x32_bf16(va, vb[p], acc[mt][p], 0,0,0);
      }
    }
    __builtin_amdgcn_s_setprio(0);
    #pragma unroll
    for(int mt=0;mt<4;mt++)
      #pragma unroll
      for(int p=0;p<2;p++){
        const int f = (2*w+p)*16 + l16;
        #pragma unroll
        for(int r=0;r<4;r++){
          int row = base + mt*16 + quad*4 + r;
          if(row < N) XB[(size_t)row*FD + f] = acc[mt][p][r];
        }
      }
  }
}

__global__ __launch_bounds__(256) void k_grad(const float* __restrict__ pos,
    const int* __restrict__ Ii, const int* __restrict__ Ij,
    const float* __restrict__ De, const float* __restrict__ DBe,
    float* __restrict__ G, int E){
  int e = blockIdx.x*256 + threadIdx.x;
  if(e >= E) return;
  if(De[e] >= CUTF) return;
  float s = DBe[e] / De[e];
  int i = Ii[e], j = Ij[e];
  float dx = s*(pos[i*3+0]-pos[j*3+0]);
  float dy = s*(pos[i*3+1]-pos[j*3+1]);
  float dz = s*(pos[i*3+2]-pos[j*3+2]);
  atomicAdd(&G[i*3+0], dx); atomicAdd(&G[i*3+1], dy); atomicAdd(&G[i*3+2], dz);
  atomicAdd(&G[j*3+0], -dx); atomicAdd(&G[j*3+1], -dy); atomicAdd(&G[j*3+2], -dz);
}

__global__ __launch_bounds__(256) void k_norm(const float* __restrict__ G,
    const int* __restrict__ mol, u32* __restrict__ maxnU, int N){
  int n = blockIdx.x*256 + threadIdx.x;
  if(n >= N) return;
  float ax = G[n*3], ay = G[n*3+1], az = G[n*3+2];
  float nrm = sqrtf(ax*ax+ay*ay+az*az);
  atomicMax(&maxnU[mol[n]], __float_as_uint(nrm));
}

__global__ __launch_bounds__(256) void k_apply(const float* __restrict__ G,
    const int* __restrict__ mol, const u32* __restrict__ maxnU,
    float* __restrict__ outA, int N){
  int n = blockIdx.x*256 + threadIdx.x;
  if(n >= N) return;
  float mx = __uint_as_float(maxnU[mol[n]]);
  float coefc = fminf(1.0f/fmaxf(mx, 1e-8f), 1.0f);
  outA[n*3+0] = -G[n*3+0]*coefc;
  outA[n*3+1] = -G[n*3+1]*coefc;
  outA[n*3+2] = -G[n*3+2]*coefc;
}

extern "C" void kernel_launch(void* const* d_in, const int* in_sizes, int n_in,
                              void* d_out, int out_size, void* d_ws, size_t ws_size,
                              hipStream_t stream) {
  (void)n_in;
  const float* pos  = (const float*)d_in[0];
  const float* emb  = (const float*)d_in[1];
  const float* in2f = (const float*)d_in[2];
  const float* fW1  = (const float*)d_in[3];
  const float* fb1  = (const float*)d_in[4];
  const float* fW2  = (const float*)d_in[5];
  const float* fb2  = (const float*)d_in[6];
  const float* oW1  = (const float*)d_in[7];
  const float* ob1  = (const float*)d_in[8];
  const float* oW2  = (const float*)d_in[9];
  const float* ob2  = (const float*)d_in[10];
  const float* aW1  = (const float*)d_in[11];
  const float* ab1  = (const float*)d_in[12];
  const float* aW2  = (const float*)d_in[13];
  const float* ab2  = (const float*)d_in[14];
  const int*   Z    = (const int*)d_in[15];
  const int*   Ii   = (const int*)d_in[16];
  const int*   Ij   = (const int*)d_in[17];
  const int*   mol  = (const int*)d_in[18];
  const int N = in_sizes[15];
  const int E = in_sizes[16];
  const int M = out_size - N*3;
  const int EPM = E / M;           // 992
  const size_t NFE = (size_t)N*FD;
  float* outF = (float*)d_out;
  float* outE = outF + (size_t)N*3;
  float* ws = (float*)d_ws;
  const size_t base_u32 = 11*NFE + 2*(size_t)E + 3*(WLSZ/2) + 3*(W2LSZ/2) + 8192 + 64;
  if(ws_size < base_u32*4) return;
  const int hsave = (ws_size >= (base_u32 + 3*NFE)*4);

  float* X0  = ws;
  float* SV0 = ws + 4*NFE;
  float* H   = ws + 7*NFE;
  float* AGG = ws + 8*NFE;
  float* XB  = ws + 9*NFE;
  float* HB  = ws + 10*NFE;
  float* De  = ws + 11*NFE;
  float* DBe = De + E;
  u16*   WB  = (u16*)(DBe + E);
  u16*   WB2 = WB + 3*WLSZ;
  u16*   WB3 = WB2 + 3*W2LSZ;             // 16384 u16 (head weights)
  float* Hsv = (float*)(WB3 + 16384);     // 3*NFE floats (hsave only)
  float* G    = AGG;
  u32*  maxnU = (u32*)H;

  const int gN   = (int)((NFE + 255)/256);
  const int gE   = (E + 255)/256;
  const int gRow = (N + 31)/32;
  const int gHead= (N + 63)/64;

  k_embed<<<gN,256,0,stream>>>(emb, Z, X0, (int)NFE);
  k_edge_geom<<<gE,256,0,stream>>>(pos, Ii, Ij, De, DBe, E);
  k_prep<<<(3*WLSZ+255)/256,256,0,stream>>>(fW1, fW2, WB);
  k_prep2<<<(3*W2LSZ+255)/256,256,0,stream>>>(in2f, oW1, oW2, WB2);
  k_prep3<<<64,256,0,stream>>>(aW1, WB3);
  for(int l=0;l<3;l++){
    float* Xl  = X0 + (size_t)l*NFE;
    float* Xn  = X0 + (size_t)(l+1)*NFE;
    float* SVl = SV0 + (size_t)l*NFE;
    const u16* W1t = WB + l*WLSZ;
    const u16* W2t = W1t + 24576;
    const u16* d = WB2 + l*W2LSZ;
    const u16 *in2f_t = d, *oW1_t = d + 32768, *oW2_t = d + 65536;
    float* Hl = hsave ? (Hsv + (size_t)l*NFE) : H;
    k_gemmb<<<gRow,256,0,stream>>>(Xl, in2f_t, nullptr, nullptr, nullptr, Hl, nullptr, 0, N);
    k_edge_fwd11<<<N,256,0,stream>>>(Hl, De, W1t, fb1 + l*128, W2t, fb2 + l*128, AGG, EPM);
    k_gemmf<<<gRow,256,0,stream>>>(AGG, oW1_t, ob1 + l*128, oW2_t, ob2 + l*128, Xl, nullptr, Xn, SVl, 1, N);
  }
  k_zero<<<(M+255)/256,256,0,stream>>>(outE, M);
  k_head_m<<<gHead,256,0,stream>>>(X0 + 3*NFE, WB3, WB3 + 8192, ab1, aW2, ab2, mol, outE, XB, N);
  for(int l=2;l>=0;l--){
    float* Xl  = X0 + (size_t)l*NFE;
    float* SVl = SV0 + (size_t)l*NFE;
    const u16* W1t = WB + l*WLSZ;
    const u16* W1b = W1t + 4096;
    const u16* W2r = W1t + 8192;
    const u16* W2t = W1t + 24576;
    const u16* d = WB2 + l*W2LSZ;
    const u16 *in2f_t = d, *in2f_d = d + 16384, *oW1_d = d + 49152, *oW2_d = d + 81920;
    k_gemmf<<<gRow,256,0,stream>>>(XB, oW2_d, nullptr, oW1_d, nullptr, nullptr, SVl, AGG, nullptr, 0, N);
    float* Hl;
    if(hsave){
      Hl = Hsv + (size_t)l*NFE;
    } else {
      Hl = H;
      k_gemmb<<<gRow,256,0,stream>>>(Xl, in2f_t, nullptr, nullptr, nullptr, H, nullptr, 0, N);
    }
    k_edge_bwd13<<<N,256,0,stream>>>(Hl, AGG, De, W1t, fb1 + l*128, W1b, W2r, W2t, fb2 + l*128, DBe, HB, EPM);
    k_gemmb<<<gRow,256,0,stream>>>(HB, in2f_d, nullptr, XB, nullptr, XB, nullptr, 0, N);
  }
  k_zero<<<(N*3+255)/256,256,0,stream>>>(G, N*3);
  k_zero<<<(M+255)/256,256,0,stream>>>((float*)maxnU, M);
  k_grad<<<gE,256,0,stream>>>(pos, Ii, Ij, De, DBe, G, E);
  k_norm<<<(N+255)/256,256,0,stream>>>(G, mol, maxnU, N);
  k_apply<<<(N+255)/256,256,0,stream>>>(G, mol, maxnU, outF, N);
}

// Round 21
// 1265.228 us; speedup vs baseline: 1.0579x; 1.0007x over previous
//
#include <hip/hip_runtime.h>
#include <cstddef>

// SchNet fwd energy + force bwd, MI355X. Round 30 (final polish):
// recombination of verified winners. bwd = R19's bwd12 verbatim (sdb staging
// + phase 8; R20's DBe-atomic merge regressed per-dispatch 240->247us) WITH
// R20's __launch_bounds__(256,8) hint (which helped). fwd/gemms/head = R20
// verbatim. Session: 3820 -> ~1255us.

#define FD     128
#define NRBF   20
#define CUTF   5.0f
#define PI_F   3.14159265358979f
#define PW     136    // u16 pitch for sP/sWf/sA
#define WLSZ   40960  // u16 per layer in edge-weight workspace
#define W2LSZ  98304  // u16 per layer in dense-weight workspace (6 x 16384)
#define APM    32     // atoms per molecule

typedef unsigned short u16;
typedef unsigned int   u32;
typedef __attribute__((ext_vector_type(8))) short bf16x8;
typedef __attribute__((ext_vector_type(4))) float f32x4;

__device__ __forceinline__ float u16f(u16 x){ union{u32 i; float f;} v; v.i=((u32)x)<<16; return v.f; }
// Manual RNE bf16 rounding -- VERIFIED. Do NOT replace with inline-asm
// v_cvt_pk_bf16_f32: R10 isolated A/B proved that path numerically wrong here.
__device__ __forceinline__ u16 f16r(float f){ union{float f; u32 i;} v; v.f=f; u32 r=v.i+0x7fffu+((v.i>>16)&1u); return (u16)(r>>16); }
__device__ __forceinline__ float sspf(float x){
  return fmaxf(x,0.f) + __logf(1.f + __expf(-fabsf(x))) - 0.6931471805599453f;
}
__device__ __forceinline__ float sigf(float x){
  return __fdividef(1.f, 1.f + __expf(-x));
}
__device__ __forceinline__ float fcutf(float d){ return (d < CUTF) ? 0.5f*(__cosf(PI_F*d/CUTF)+1.f) : 0.f; }

__global__ __launch_bounds__(256) void k_zero(float* __restrict__ p, int n){
  int i = blockIdx.x*256 + threadIdx.x;
  if(i < n) p[i] = 0.f;
}

__global__ __launch_bounds__(256) void k_embed(const float* __restrict__ emb, const int* __restrict__ Z,
                                               float* __restrict__ X0, int n){
  int idx = blockIdx.x*256 + threadIdx.x;
  if(idx >= n) return;
  int a = idx >> 7, f = idx & 127;
  X0[idx] = emb[Z[a]*FD + f];
}

__global__ __launch_bounds__(256) void k_edge_geom(const float* __restrict__ pos,
    const int* __restrict__ Ii, const int* __restrict__ Ij,
    float* __restrict__ De, float* __restrict__ DBe, int E){
  int e = blockIdx.x*256 + threadIdx.x;
  if(e >= E) return;
  int i = Ii[e], j = Ij[e];
  float dx = pos[j*3+0]-pos[i*3+0];
  float dy = pos[j*3+1]-pos[i*3+1];
  float dz = pos[j*3+2]-pos[i*3+2];
  De[e] = sqrtf(dx*dx+dy*dy+dz*dz + 1e-12f);
  DBe[e] = 0.f;
}

// Edge-filter bf16 weight pre-conversion (once per launch).
__global__ __launch_bounds__(256) void k_prep(const float* __restrict__ fW1,
    const float* __restrict__ fW2, u16* __restrict__ WB){
  int idx = blockIdx.x*256 + threadIdx.x;
  if(idx >= 3*WLSZ) return;
  int l = idx / WLSZ, r = idx - l*WLSZ;
  const float* W1 = fW1 + l*2560;
  const float* W2 = fW2 + l*16384;
  u16* out = WB + l*WLSZ;
  if(r < 4096){
    int c = r >> 5, k = r & 31;
    out[r] = (k < NRBF) ? f16r(W1[k*128 + c]) : (u16)0;
  } else if(r < 8192){
    int rr = r - 4096;
    int k = rr >> 7, c = rr & 127;
    out[r] = (k < NRBF) ? f16r(W1[k*128 + c]) : (u16)0;
  } else if(r < 24576){
    out[r] = f16r(W2[r - 8192]);
  } else {
    int rr = r - 24576;
    int f = rr >> 7, c = rr & 127;
    out[r] = f16r(W2[c*128 + f]);
  }
}

// Dense-layer bf16 weight pre-conversion: per layer, 6 matrices of [n][k]:
//   0: in2f^T  1: in2f  2: oW1^T  3: oW1  4: oW2^T  5: oW2
__global__ __launch_bounds__(256) void k_prep2(const float* __restrict__ in2f,
    const float* __restrict__ oW1, const float* __restrict__ oW2,
    u16* __restrict__ WB2){
  int idx = blockIdx.x*256 + threadIdx.x;
  if(idx >= 3*W2LSZ) return;
  int l = idx / W2LSZ, r = idx - l*W2LSZ;
  int mat = r >> 14, q = r & 16383;
  int n = q >> 7, k = q & 127;
  const float* src = (mat < 2) ? (in2f + l*16384) : (mat < 4) ? (oW1 + l*16384) : (oW2 + l*16384);
  float v = (mat & 1) ? src[n*128 + k] : src[k*128 + n];
  WB2[idx] = f16r(v);
}

// Head-weight bf16 pre-conversion: A1t [c=64][k=128] then A1d [f=128][c=64].
__global__ __launch_bounds__(256) void k_prep3(const float* __restrict__ aW1,
    u16* __restrict__ WB3){
  int idx = blockIdx.x*256 + threadIdx.x;
  if(idx >= 16384) return;
  if(idx < 8192){
    int c = idx >> 7, f = idx & 127;
    WB3[idx] = f16r(aW1[f*64 + c]);
  } else {
    WB3[idx] = f16r(aW1[idx - 8192]);   // [f][c] row-major direct
  }
}

// Dense GEMM via bf16 MFMA (verified R9/R15).
__global__ __launch_bounds__(256) void k_gemmb(const float* __restrict__ A,
    const u16* __restrict__ Bn, const float* __restrict__ bias,
    const float* __restrict__ res, const float* __restrict__ mul,
    float* __restrict__ out1, float* __restrict__ out2, int act, int Nr){
  __shared__ u16 sA[32*PW];
  const int tid = threadIdx.x;
  const int rb = blockIdx.x * 32;
  #pragma unroll
  for(int q=0;q<4;q++){
    int e = q*256 + tid;
    int r = e >> 5, c4 = (e & 31)*4;
    int rr = rb + r; if(rr >= Nr) rr = Nr-1;
    float4 v = *(const float4*)(A + (size_t)rr*FD + c4);
    sA[r*PW + c4+0] = f16r(v.x);
    sA[r*PW + c4+1] = f16r(v.y);
    sA[r*PW + c4+2] = f16r(v.z);
    sA[r*PW + c4+3] = f16r(v.w);
  }
  __syncthreads();
  const int w = tid >> 6, lane = tid & 63;
  const int quad = lane >> 4, l16 = lane & 15;
  f32x4 acc[2][2];
  #pragma unroll
  for(int mm=0;mm<2;mm++){ acc[mm][0]=(f32x4){0,0,0,0}; acc[mm][1]=(f32x4){0,0,0,0}; }
  __builtin_amdgcn_s_setprio(1);
  #pragma unroll
  for(int ks=0;ks<4;ks++){
    bf16x8 va[2], vb[2];
    #pragma unroll
    for(int mm=0;mm<2;mm++)
      va[mm] = *(const bf16x8*)&sA[(mm*16+l16)*PW + ks*32 + quad*8];
    #pragma unroll
    for(int p=0;p<2;p++)
      vb[p] = *(const bf16x8*)(Bn + ((2*w+p)*16+l16)*128 + ks*32 + quad*8);
    #pragma unroll
    for(int mm=0;mm<2;mm++)
      #pragma unroll
      for(int p=0;p<2;p++)
        acc[mm][p] = __builtin_amdgcn_mfma_f32_16x16x32_bf16(va[mm], vb[p], acc[mm][p], 0,0,0);
  }
  __builtin_amdgcn_s_setprio(0);
  #pragma unroll
  for(int mm=0;mm<2;mm++)
    #pragma unroll
    for(int p=0;p<2;p++){
      const int f = (2*w+p)*16 + l16;
      float bb = bias ? bias[f] : 0.f;
      #pragma unroll
      for(int r=0;r<4;r++){
        int row = rb + mm*16 + quad*4 + r;
        if(row >= Nr) continue;
        size_t o = (size_t)row*FD + f;
        float y = acc[mm][p][r] + bb;
        if(res) y += res[o];
        if(mul) y *= mul[o];
        if(act){ out1[o] = sspf(y); out2[o] = sigf(y); }
        else out1[o] = y;
      }
    }
}

// Fused dependent-GEMM pair (verified R16).
__global__ __launch_bounds__(256) void k_gemmf(const float* __restrict__ A,
    const u16* __restrict__ B1n, const float* __restrict__ b1,
    const u16* __restrict__ B2n, const float* __restrict__ b2,
    const float* __restrict__ res, const float* __restrict__ mulSV,
    float* __restrict__ out1, float* __restrict__ outSV, int mode, int Nr){
  __shared__ u16 sA[32*PW];
  __shared__ u16 sB[32*PW];
  const int tid = threadIdx.x;
  const int rb = blockIdx.x * 32;
  #pragma unroll
  for(int q=0;q<4;q++){
    int e = q*256 + tid;
    int r = e >> 5, c4 = (e & 31)*4;
    int rr = rb + r; if(rr >= Nr) rr = Nr-1;
    float4 v = *(const float4*)(A + (size_t)rr*FD + c4);
    sA[r*PW + c4+0] = f16r(v.x);
    sA[r*PW + c4+1] = f16r(v.y);
    sA[r*PW + c4+2] = f16r(v.z);
    sA[r*PW + c4+3] = f16r(v.w);
  }
  __syncthreads();
  const int w = tid >> 6, lane = tid & 63;
  const int quad = lane >> 4, l16 = lane & 15;
  { // GEMM1
    f32x4 acc[2][2];
    #pragma unroll
    for(int mm=0;mm<2;mm++){ acc[mm][0]=(f32x4){0,0,0,0}; acc[mm][1]=(f32x4){0,0,0,0}; }
    __builtin_amdgcn_s_setprio(1);
    #pragma unroll
    for(int ks=0;ks<4;ks++){
      bf16x8 va[2], vb[2];
      #pragma unroll
      for(int mm=0;mm<2;mm++)
        va[mm] = *(const bf16x8*)&sA[(mm*16+l16)*PW + ks*32 + quad*8];
      #pragma unroll
      for(int p=0;p<2;p++)
        vb[p] = *(const bf16x8*)(B1n + ((2*w+p)*16+l16)*128 + ks*32 + quad*8);
      #pragma unroll
      for(int mm=0;mm<2;mm++)
        #pragma unroll
        for(int p=0;p<2;p++)
          acc[mm][p] = __builtin_amdgcn_mfma_f32_16x16x32_bf16(va[mm], vb[p], acc[mm][p], 0,0,0);
    }
    __builtin_amdgcn_s_setprio(0);
    #pragma unroll
    for(int mm=0;mm<2;mm++)
      #pragma unroll
      for(int p=0;p<2;p++){
        const int f = (2*w+p)*16 + l16;
        float bb = (mode && b1) ? b1[f] : 0.f;
        #pragma unroll
        for(int r=0;r<4;r++){
          const int lrow = mm*16 + quad*4 + r;
          int row = rb + lrow;
          if(row >= Nr) row = Nr-1;
          size_t o = (size_t)row*FD + f;
          float y = acc[mm][p][r] + bb;
          float t;
          if(mode){
            t = sspf(y);
            if(rb + lrow < Nr) outSV[o] = sigf(y);
          } else {
            t = y * mulSV[o];
          }
          sB[lrow*PW + f] = f16r(t);
        }
      }
  }
  __syncthreads();
  { // GEMM2
    f32x4 acc[2][2];
    #pragma unroll
    for(int mm=0;mm<2;mm++){ acc[mm][0]=(f32x4){0,0,0,0}; acc[mm][1]=(f32x4){0,0,0,0}; }
    __builtin_amdgcn_s_setprio(1);
    #pragma unroll
    for(int ks=0;ks<4;ks++){
      bf16x8 va[2], vb[2];
      #pragma unroll
      for(int mm=0;mm<2;mm++)
        va[mm] = *(const bf16x8*)&sB[(mm*16+l16)*PW + ks*32 + quad*8];
      #pragma unroll
      for(int p=0;p<2;p++)
        vb[p] = *(const bf16x8*)(B2n + ((2*w+p)*16+l16)*128 + ks*32 + quad*8);
      #pragma unroll
      for(int mm=0;mm<2;mm++)
        #pragma unroll
        for(int p=0;p<2;p++)
          acc[mm][p] = __builtin_amdgcn_mfma_f32_16x16x32_bf16(va[mm], vb[p], acc[mm][p], 0,0,0);
    }
    __builtin_amdgcn_s_setprio(0);
    #pragma unroll
    for(int mm=0;mm<2;mm++)
      #pragma unroll
      for(int p=0;p<2;p++){
        const int f = (2*w+p)*16 + l16;
        float bb = (mode && b2) ? b2[f] : 0.f;
        #pragma unroll
        for(int r=0;r<4;r++){
          int row = rb + mm*16 + quad*4 + r;
          if(row >= Nr) continue;
          size_t o = (size_t)row*FD + f;
          float y = acc[mm][p][r] + bb;
          if(res) y += res[o];
          out1[o] = y;
        }
      }
  }
}

// ---- Edge forward v11 (verified) + occupancy hint ----
__global__ __launch_bounds__(256, 8) void k_edge_fwd11(
    const float* __restrict__ h,
    const float* __restrict__ De,
    const u16* __restrict__ W1t, const float* __restrict__ b1,
    const u16* __restrict__ W2t, const float* __restrict__ b2,
    float* __restrict__ agg, int EPM){
  __shared__ u16 srbfb[32*32];
  __shared__ u16 sP [32*PW];
  __shared__ u16 sWf[32*PW];
  __shared__ float sD[32];
  __shared__ float sRed[4*128];
  const int tid = threadIdx.x;
  const int nb = gridDim.x;
  const int P = ((nb & 7) == 0) ? ((blockIdx.x & 7)*(nb >> 3) + (blockIdx.x >> 3)) : blockIdx.x;
  const int m = P >> 5, a = P & 31;
  const int a0 = m*APM;
  const int eb = m*EPM + a*(APM-1);
  if(tid < 32) sD[tid] = (tid < APM-1) ? De[eb + tid] : (CUTF + 1.f);
  __syncthreads();
  const float step = CUTF/19.0f;
  const float coef = -0.5f/(step*step);
  {
    #pragma unroll
    for(int q=0;q<4;q++){
      int idx = q*256 + tid;
      int lt = idx >> 5, k = idx & 31;
      float x = sD[lt] - step*(float)k;
      srbfb[idx] = (k < NRBF) ? f16r(__expf(coef*x*x)) : (u16)0;
    }
  }
  __syncthreads();
  const int w = tid >> 6, lane = tid & 63;
  const int quad = lane >> 4, l16 = lane & 15;
  {
    f32x4 acc[2][2];
    #pragma unroll
    for(int mm=0;mm<2;mm++){ acc[mm][0]=(f32x4){0,0,0,0}; acc[mm][1]=(f32x4){0,0,0,0}; }
    bf16x8 va[2], vb[2];
    #pragma unroll
    for(int mm=0;mm<2;mm++)
      va[mm] = *(const bf16x8*)&srbfb[(mm*16+l16)*32 + quad*8];
    #pragma unroll
    for(int p=0;p<2;p++)
      vb[p] = *(const bf16x8*)(W1t + ((2*w+p)*16+l16)*32 + quad*8);
    #pragma unroll
    for(int mm=0;mm<2;mm++)
      #pragma unroll
      for(int p=0;p<2;p++)
        acc[mm][p] = __builtin_amdgcn_mfma_f32_16x16x32_bf16(va[mm], vb[p], acc[mm][p], 0,0,0);
    #pragma unroll
    for(int mm=0;mm<2;mm++)
      #pragma unroll
      for(int p=0;p<2;p++){
        const int c = (2*w+p)*16 + l16;
        float bb = b1[c];
        #pragma unroll
        for(int r=0;r<4;r++)
          sP[(mm*16+quad*4+r)*PW + c] = f16r(sspf(acc[mm][p][r] + bb));
      }
  }
  __syncthreads();
  {
    f32x4 acc[2][2];
    #pragma unroll
    for(int mm=0;mm<2;mm++){ acc[mm][0]=(f32x4){0,0,0,0}; acc[mm][1]=(f32x4){0,0,0,0}; }
    __builtin_amdgcn_s_setprio(1);
    #pragma unroll
    for(int ks=0;ks<4;ks++){
      bf16x8 va[2], vb[2];
      #pragma unroll
      for(int mm=0;mm<2;mm++)
        va[mm] = *(const bf16x8*)&sP[(mm*16+l16)*PW + ks*32 + quad*8];
      #pragma unroll
      for(int p=0;p<2;p++)
        vb[p] = *(const bf16x8*)(W2t + ((2*w+p)*16+l16)*128 + ks*32 + quad*8);
      #pragma unroll
      for(int mm=0;mm<2;mm++)
        #pragma unroll
        for(int p=0;p<2;p++)
          acc[mm][p] = __builtin_amdgcn_mfma_f32_16x16x32_bf16(va[mm], vb[p], acc[mm][p], 0,0,0);
    }
    __builtin_amdgcn_s_setprio(0);
    #pragma unroll
    for(int mm=0;mm<2;mm++)
      #pragma unroll
      for(int p=0;p<2;p++){
        const int f = (2*w+p)*16 + l16;
        float bb = b2[f];
        #pragma unroll
        for(int r=0;r<4;r++)
          sWf[(mm*16+quad*4+r)*PW + f] = f16r(acc[mm][p][r] + bb);
      }
  }
  __syncthreads();
  {
    float h0v[8], h1v[8], w0v[8], w1v[8], fcv[8];
    #pragma unroll
    for(int s=0;s<8;s++){
      int lt = w*8 + s;
      int j = (lt < APM-1) ? (lt + (lt >= a ? 1 : 0)) : 0;
      fcv[s] = fcutf(sD[lt]);
      const float* hr = h + (size_t)(a0 + j)*FD;
      h0v[s] = hr[lane];
      h1v[s] = hr[lane + 64];
      w0v[s] = u16f(sWf[lt*PW + lane]);
      w1v[s] = u16f(sWf[lt*PW + lane + 64]);
    }
    float r0 = 0.f, r1 = 0.f;
    #pragma unroll
    for(int s=0;s<8;s++){
      r0 += h0v[s] * w0v[s] * fcv[s];
      r1 += h1v[s] * w1v[s] * fcv[s];
    }
    sRed[w*128 + lane]      = r0;
    sRed[w*128 + lane + 64] = r1;
  }
  __syncthreads();
  if(tid < 128){
    float v = sRed[tid] + sRed[128+tid] + sRed[256+tid] + sRed[384+tid];
    agg[(size_t)(a0+a)*FD + tid] = v;
  }
}

// ---- Edge backward v12 (verified R19) + occupancy hint ----
__global__ __launch_bounds__(256, 8) void k_edge_bwd12(
    const float* __restrict__ h, const float* __restrict__ AB,
    const float* __restrict__ De,
    const u16* __restrict__ W1t, const float* __restrict__ b1,
    const u16* __restrict__ W1b, const u16* __restrict__ W2r,
    const u16* __restrict__ W2t, const float* __restrict__ b2,
    float* __restrict__ DBe, float* __restrict__ HB, int EPM){
  __shared__ u16 srbfb[32*32];
  __shared__ u16 sP [32*PW];
  __shared__ u16 sWf[32*PW];
  __shared__ float sD[32];
  __shared__ float sRed[4*128];
  __shared__ float sdb[32*2];
  __shared__ float sfb[32];
  const int tid = threadIdx.x;
  const int nb = gridDim.x;
  const int P = ((nb & 7) == 0) ? ((blockIdx.x & 7)*(nb >> 3) + (blockIdx.x >> 3)) : blockIdx.x;
  const int m = P >> 5, a = P & 31;
  const int a0 = m*APM;
  const int eb = m*EPM + a*(APM-1);
  if(tid < 32) sD[tid] = (tid < APM-1) ? De[eb + tid] : (CUTF + 1.f);
  __syncthreads();
  const float step = CUTF/19.0f;
  const float coef = -0.5f/(step*step);
  {
    #pragma unroll
    for(int q=0;q<4;q++){
      int idx = q*256 + tid;
      int lt = idx >> 5, k = idx & 31;
      float x = sD[lt] - step*(float)k;
      srbfb[idx] = (k < NRBF) ? f16r(__expf(coef*x*x)) : (u16)0;
    }
  }
  __syncthreads();
  const int w = tid >> 6, lane = tid & 63;
  const int quad = lane >> 4, l16 = lane & 15;
  {
    f32x4 acc[2][2];
    #pragma unroll
    for(int mm=0;mm<2;mm++){ acc[mm][0]=(f32x4){0,0,0,0}; acc[mm][1]=(f32x4){0,0,0,0}; }
    bf16x8 va[2], vb[2];
    #pragma unroll
    for(int mm=0;mm<2;mm++)
      va[mm] = *(const bf16x8*)&srbfb[(mm*16+l16)*32 + quad*8];
    #pragma unroll
    for(int p=0;p<2;p++)
      vb[p] = *(const bf16x8*)(W1t + ((2*w+p)*16+l16)*32 + quad*8);
    #pragma unroll
    for(int mm=0;mm<2;mm++)
      #pragma unroll
      for(int p=0;p<2;p++)
        acc[mm][p] = __builtin_amdgcn_mfma_f32_16x16x32_bf16(va[mm], vb[p], acc[mm][p], 0,0,0);
    #pragma unroll
    for(int mm=0;mm<2;mm++)
      #pragma unroll
      for(int p=0;p<2;p++){
        const int c = (2*w+p)*16 + l16;
        float bb = b1[c];
        #pragma unroll
        for(int r=0;r<4;r++)
          sP[(mm*16+quad*4+r)*PW + c] = f16r(sspf(acc[mm][p][r] + bb));
      }
  }
  __syncthreads();
  {
    f32x4 acc[2][2];
    #pragma unroll
    for(int mm=0;mm<2;mm++){ acc[mm][0]=(f32x4){0,0,0,0}; acc[mm][1]=(f32x4){0,0,0,0}; }
    __builtin_amdgcn_s_setprio(1);
    #pragma unroll
    for(int ks=0;ks<4;ks++){
      bf16x8 va[2], vb[2];
      #pragma unroll
      for(int mm=0;mm<2;mm++)
        va[mm] = *(const bf16x8*)&sP[(mm*16+l16)*PW + ks*32 + quad*8];
      #pragma unroll
      for(int p=0;p<2;p++)
        vb[p] = *(const bf16x8*)(W2t + ((2*w+p)*16+l16)*128 + ks*32 + quad*8);
      #pragma unroll
      for(int mm=0;mm<2;mm++)
        #pragma unroll
        for(int p=0;p<2;p++)
          acc[mm][p] = __builtin_amdgcn_mfma_f32_16x16x32_bf16(va[mm], vb[p], acc[mm][p], 0,0,0);
    }
    __builtin_amdgcn_s_setprio(0);
    #pragma unroll
    for(int mm=0;mm<2;mm++)
      #pragma unroll
      for(int p=0;p<2;p++){
        const int f = (2*w+p)*16 + l16;
        float bb = b2[f];
        #pragma unroll
        for(int r=0;r<4;r++)
          sWf[(mm*16+quad*4+r)*PW + f] = f16r(acc[mm][p][r] + bb);
      }
  }
  __syncthreads();
  {
    float ab0 = AB[(size_t)(a0+a)*FD + lane];
    float ab1 = AB[(size_t)(a0+a)*FD + lane + 64];
    float h0v[8], h1v[8], a0v[8], a1v[8], w0v[8], w1v[8], fcv[8];
    #pragma unroll
    for(int s=0;s<8;s++){
      int lt = w*8 + s;
      int j = (lt < APM-1) ? (lt + (lt >= a ? 1 : 0)) : 0;
      fcv[s] = fcutf(sD[lt]);
      const float* hr  = h  + (size_t)(a0 + j)*FD;
      const float* abr = AB + (size_t)(a0 + j)*FD;
      h0v[s] = hr[lane];
      h1v[s] = hr[lane + 64];
      a0v[s] = abr[lane];
      a1v[s] = abr[lane + 64];
      w0v[s] = u16f(sWf[lt*PW + lane]);
      w1v[s] = u16f(sWf[lt*PW + lane + 64]);
    }
    float r0 = 0.f, r1 = 0.f;
    float pfv[8];
    #pragma unroll
    for(int s=0;s<8;s++){
      int lt = w*8 + s;
      float fc = fcv[s];
      r0 += a0v[s] * w0v[s] * fc;
      r1 += a1v[s] * w1v[s] * fc;
      float g0 = ab0*h0v[s], g1 = ab1*h1v[s];
      sWf[lt*PW + lane]      = f16r(g0*fc);
      sWf[lt*PW + lane + 64] = f16r(g1*fc);
      pfv[s] = g0*w0v[s] + g1*w1v[s];
    }
    #pragma unroll
    for(int d2=1; d2<64; d2<<=1){
      #pragma unroll
      for(int s=0;s<8;s++) pfv[s] += __shfl_xor(pfv[s], d2);
    }
    if(lane == 0){
      #pragma unroll
      for(int s=0;s<8;s++) sfb[w*8 + s] = pfv[s];
    }
    sRed[w*128 + lane]      = r0;
    sRed[w*128 + lane + 64] = r1;
  }
  __syncthreads();
  if(tid < 128){
    float v = sRed[tid] + sRed[128+tid] + sRed[256+tid] + sRed[384+tid];
    HB[(size_t)(a0+a)*FD + tid] = v;
  }
  { // phase 5+6 merged: GEMM2; sigma-trick; tbar -> sP (thread-local RMW)
    f32x4 acc[2][2];
    #pragma unroll
    for(int mm=0;mm<2;mm++){ acc[mm][0]=(f32x4){0,0,0,0}; acc[mm][1]=(f32x4){0,0,0,0}; }
    __builtin_amdgcn_s_setprio(1);
    #pragma unroll
    for(int ks=0;ks<4;ks++){
      bf16x8 va[2], vb[2];
      #pragma unroll
      for(int mm=0;mm<2;mm++)
        va[mm] = *(const bf16x8*)&sWf[(mm*16+l16)*PW + ks*32 + quad*8];
      #pragma unroll
      for(int p=0;p<2;p++)
        vb[p] = *(const bf16x8*)(W2r + ((2*w+p)*16+l16)*128 + ks*32 + quad*8);
      #pragma unroll
      for(int mm=0;mm<2;mm++)
        #pragma unroll
        for(int p=0;p<2;p++)
          acc[mm][p] = __builtin_amdgcn_mfma_f32_16x16x32_bf16(va[mm], vb[p], acc[mm][p], 0,0,0);
    }
    __builtin_amdgcn_s_setprio(0);
    #pragma unroll
    for(int mm=0;mm<2;mm++)
      #pragma unroll
      for(int p=0;p<2;p++){
        const int c = (2*w+p)*16 + l16;
        #pragma unroll
        for(int r=0;r<4;r++){
          const int row = mm*16 + quad*4 + r;
          float Pv = u16f(sP[row*PW + c]);
          float sig = 1.0f - 0.5f*__expf(-Pv);
          sP[row*PW + c] = f16r(acc[mm][p][r] * sig);
        }
      }
  }
  __syncthreads();
  { // phase 7: GEMM3 (A from sP); dbar partials, rbf recomputed
    const int m3 = w >> 1, p3 = w & 1;
    f32x4 acc = (f32x4){0,0,0,0};
    #pragma unroll
    for(int ks=0;ks<4;ks++){
      bf16x8 va = *(const bf16x8*)&sP[(m3*16+l16)*PW + ks*32 + quad*8];
      bf16x8 vb = *(const bf16x8*)(W1b + (p3*16+l16)*128 + ks*32 + quad*8);
      acc = __builtin_amdgcn_mfma_f32_16x16x32_bf16(va, vb, acc, 0,0,0);
    }
    const int kr = p3*16 + l16;
    float s0[4];
    #pragma unroll
    for(int r=0;r<4;r++){
      int lt = m3*16 + quad*4 + r;
      float v = 0.f;
      if(kr < NRBF){
        float x = sD[lt] - step*(float)kr;
        float rb = __expf(coef*x*x);
        v = acc[r] * rb * (2.f*coef*x);
      }
      s0[r] = v;
    }
    #pragma unroll
    for(int d2=1; d2<16; d2<<=1){
      #pragma unroll
      for(int r=0;r<4;r++) s0[r] += __shfl_xor(s0[r], d2);
    }
    if(l16 == 0){
      #pragma unroll
      for(int r=0;r<4;r++) sdb[(m3*16+quad*4+r)*2 + p3] = s0[r];
    }
  }
  __syncthreads();
  if(tid < APM-1){
    const float d = sD[tid];
    float dfc = (d < CUTF) ? (-0.5f*(PI_F/CUTF)*__sinf(PI_F*d/CUTF)) : 0.f;
    DBe[eb + tid] += sdb[tid*2+0] + sdb[tid*2+1] + sfb[tid]*dfc;
  }
}

// ---- Head via MFMA (verified R19) ----
__global__ __launch_bounds__(256) void k_head_m(const float* __restrict__ X3,
    const u16* __restrict__ A1t, const u16* __restrict__ A1d,
    const float* __restrict__ ab1, const float* __restrict__ aW2,
    const float* __restrict__ ab2, const int* __restrict__ mol,
    float* __restrict__ Emol, float* __restrict__ XB, int N){
  __shared__ u16 sx[64*PW];
  __shared__ u16 sg[64*72];
  __shared__ float spe[64*4];
  const int tid = threadIdx.x;
  const int base = blockIdx.x*64;
  #pragma unroll
  for(int q=0;q<8;q++){
    int e = q*256 + tid;
    int r = e >> 5, c4 = (e & 31)*4;
    int row = base + r; if(row >= N) row = N-1;
    float4 v = *(const float4*)(X3 + (size_t)row*FD + c4);
    sx[r*PW + c4+0] = f16r(v.x);
    sx[r*PW + c4+1] = f16r(v.y);
    sx[r*PW + c4+2] = f16r(v.z);
    sx[r*PW + c4+3] = f16r(v.w);
  }
  __syncthreads();
  const int w = tid >> 6, lane = tid & 63;
  const int quad = lane >> 4, l16 = lane & 15;
  {
    f32x4 acc[4];
    #pragma unroll
    for(int mt=0;mt<4;mt++) acc[mt] = (f32x4){0,0,0,0};
    __builtin_amdgcn_s_setprio(1);
    #pragma unroll
    for(int ks=0;ks<4;ks++){
      bf16x8 vb = *(const bf16x8*)(A1t + (w*16+l16)*128 + ks*32 + quad*8);
      #pragma unroll
      for(int mt=0;mt<4;mt++){
        bf16x8 va = *(const bf16x8*)&sx[(mt*16+l16)*PW + ks*32 + quad*8];
        acc[mt] = __builtin_amdgcn_mfma_f32_16x16x32_bf16(va, vb, acc[mt], 0,0,0);
      }
    }
    __builtin_amdgcn_s_setprio(0);
    const int c = w*16 + l16;
    const float b1c = ab1[c];
    const float aw2c = aW2[c];
    float pv[16];
    #pragma unroll
    for(int mt=0;mt<4;mt++)
      #pragma unroll
      for(int r=0;r<4;r++){
        float y = acc[mt][r] + b1c;
        pv[mt*4+r] = sspf(y)*aw2c;
        sg[(mt*16+quad*4+r)*72 + c] = f16r(sigf(y)*aw2c);
      }
    #pragma unroll
    for(int d2=1; d2<16; d2<<=1){
      #pragma unroll
      for(int t2=0;t2<16;t2++) pv[t2] += __shfl_xor(pv[t2], d2);
    }
    if(l16 == 0){
      #pragma unroll
      for(int mt=0;mt<4;mt++)
        #pragma unroll
        for(int r=0;r<4;r++)
          spe[(mt*16+quad*4+r)*4 + w] = pv[mt*4+r];
    }
  }
  __syncthreads();
  if(tid < 64){
    int row = base + tid;
    if(row < N){
      float pe = spe[tid*4+0] + spe[tid*4+1] + spe[tid*4+2] + spe[tid*4+3] + ab2[0];
      atomicAdd(&Emol[mol[row]], pe);
    }
  }
  {
    f32x4 acc[4][2];
    #pragma unroll
    for(int mt=0;mt<4;mt++){ acc[mt][0]=(f32x4){0,0,0,0}; acc[mt][1]=(f32x4){0,0,0,0}; }
    __builtin_amdgcn_s_setprio(1);
    #pragma unroll
    for(int ks=0;ks<2;ks++){
      bf16x8 vb[2];
      #pragma unroll
      for(int p=0;p<2;p++)
        vb[p] = *(const bf16x8*)(A1d + ((2*w+p)*16+l16)*64 + ks*32 + quad*8);
      #pragma unroll
      for(int mt=0;mt<4;mt++){
        bf16x8 va = *(const bf16x8*)&sg[(mt*16+l16)*72 + ks*32 + quad*8];
        #pragma unroll
        for(int p=0;p<2;p++)
          acc[mt][p] = __builtin_amdgcn_mfma_f32_16x16x32_bf16(va, vb[p], acc[mt][p], 0,0,0);
      }
    }
    __builtin_amdgcn_s_setprio(0);
    #pragma unroll
    for(int mt=0;mt<4;mt++)
      #pragma unroll
      for(int p=0;p<2;p++){
        const int f = (2*w+p)*16 + l16;
        #pragma unroll
        for(int r=0;r<4;r++){
          int row = base + mt*16 + quad*4 + r;
          if(row < N) XB[(size_t)row*FD + f] = acc[mt][p][r];
        }
      }
  }
}

__global__ __launch_bounds__(256) void k_grad(const float* __restrict__ pos,
    const int* __restrict__ Ii, const int* __restrict__ Ij,
    const float* __restrict__ De, const float* __restrict__ DBe,
    float* __restrict__ G, int E){
  int e = blockIdx.x*256 + threadIdx.x;
  if(e >= E) return;
  if(De[e] >= CUTF) return;
  float s = DBe[e] / De[e];
  int i = Ii[e], j = Ij[e];
  float dx = s*(pos[i*3+0]-pos[j*3+0]);
  float dy = s*(pos[i*3+1]-pos[j*3+1]);
  float dz = s*(pos[i*3+2]-pos[j*3+2]);
  atomicAdd(&G[i*3+0], dx); atomicAdd(&G[i*3+1], dy); atomicAdd(&G[i*3+2], dz);
  atomicAdd(&G[j*3+0], -dx); atomicAdd(&G[j*3+1], -dy); atomicAdd(&G[j*3+2], -dz);
}

__global__ __launch_bounds__(256) void k_norm(const float* __restrict__ G,
    const int* __restrict__ mol, u32* __restrict__ maxnU, int N){
  int n = blockIdx.x*256 + threadIdx.x;
  if(n >= N) return;
  float ax = G[n*3], ay = G[n*3+1], az = G[n*3+2];
  float nrm = sqrtf(ax*ax+ay*ay+az*az);
  atomicMax(&maxnU[mol[n]], __float_as_uint(nrm));
}

__global__ __launch_bounds__(256) void k_apply(const float* __restrict__ G,
    const int* __restrict__ mol, const u32* __restrict__ maxnU,
    float* __restrict__ outA, int N){
  int n = blockIdx.x*256 + threadIdx.x;
  if(n >= N) return;
  float mx = __uint_as_float(maxnU[mol[n]]);
  float coefc = fminf(1.0f/fmaxf(mx, 1e-8f), 1.0f);
  outA[n*3+0] = -G[n*3+0]*coefc;
  outA[n*3+1] = -G[n*3+1]*coefc;
  outA[n*3+2] = -G[n*3+2]*coefc;
}

extern "C" void kernel_launch(void* const* d_in, const int* in_sizes, int n_in,
                              void* d_out, int out_size, void* d_ws, size_t ws_size,
                              hipStream_t stream) {
  (void)n_in;
  const float* pos  = (const float*)d_in[0];
  const float* emb  = (const float*)d_in[1];
  const float* in2f = (const float*)d_in[2];
  const float* fW1  = (const float*)d_in[3];
  const float* fb1  = (const float*)d_in[4];
  const float* fW2  = (const float*)d_in[5];
  const float* fb2  = (const float*)d_in[6];
  const float* oW1  = (const float*)d_in[7];
  const float* ob1  = (const float*)d_in[8];
  const float* oW2  = (const float*)d_in[9];
  const float* ob2  = (const float*)d_in[10];
  const float* aW1  = (const float*)d_in[11];
  const float* ab1  = (const float*)d_in[12];
  const float* aW2  = (const float*)d_in[13];
  const float* ab2  = (const float*)d_in[14];
  const int*   Z    = (const int*)d_in[15];
  const int*   Ii   = (const int*)d_in[16];
  const int*   Ij   = (const int*)d_in[17];
  const int*   mol  = (const int*)d_in[18];
  const int N = in_sizes[15];
  const int E = in_sizes[16];
  const int M = out_size - N*3;
  const int EPM = E / M;           // 992
  const size_t NFE = (size_t)N*FD;
  float* outF = (float*)d_out;
  float* outE = outF + (size_t)N*3;
  float* ws = (float*)d_ws;
  const size_t base_u32 = 11*NFE + 2*(size_t)E + 3*(WLSZ/2) + 3*(W2LSZ/2) + 8192 + 64;
  if(ws_size < base_u32*4) return;
  const int hsave = (ws_size >= (base_u32 + 3*NFE)*4);

  float* X0  = ws;
  float* SV0 = ws + 4*NFE;
  float* H   = ws + 7*NFE;
  float* AGG = ws + 8*NFE;
  float* XB  = ws + 9*NFE;
  float* HB  = ws + 10*NFE;
  float* De  = ws + 11*NFE;
  float* DBe = De + E;
  u16*   WB  = (u16*)(DBe + E);
  u16*   WB2 = WB + 3*WLSZ;
  u16*   WB3 = WB2 + 3*W2LSZ;             // 16384 u16 (head weights)
  float* Hsv = (float*)(WB3 + 16384);     // 3*NFE floats (hsave only)
  float* G    = AGG;
  u32*  maxnU = (u32*)H;

  const int gN   = (int)((NFE + 255)/256);
  const int gE   = (E + 255)/256;
  const int gRow = (N + 31)/32;
  const int gHead= (N + 63)/64;

  k_embed<<<gN,256,0,stream>>>(emb, Z, X0, (int)NFE);
  k_edge_geom<<<gE,256,0,stream>>>(pos, Ii, Ij, De, DBe, E);
  k_prep<<<(3*WLSZ+255)/256,256,0,stream>>>(fW1, fW2, WB);
  k_prep2<<<(3*W2LSZ+255)/256,256,0,stream>>>(in2f, oW1, oW2, WB2);
  k_prep3<<<64,256,0,stream>>>(aW1, WB3);
  for(int l=0;l<3;l++){
    float* Xl  = X0 + (size_t)l*NFE;
    float* Xn  = X0 + (size_t)(l+1)*NFE;
    float* SVl = SV0 + (size_t)l*NFE;
    const u16* W1t = WB + l*WLSZ;
    const u16* W2t = W1t + 24576;
    const u16* d = WB2 + l*W2LSZ;
    const u16 *in2f_t = d, *oW1_t = d + 32768, *oW2_t = d + 65536;
    float* Hl = hsave ? (Hsv + (size_t)l*NFE) : H;
    k_gemmb<<<gRow,256,0,stream>>>(Xl, in2f_t, nullptr, nullptr, nullptr, Hl, nullptr, 0, N);
    k_edge_fwd11<<<N,256,0,stream>>>(Hl, De, W1t, fb1 + l*128, W2t, fb2 + l*128, AGG, EPM);
    k_gemmf<<<gRow,256,0,stream>>>(AGG, oW1_t, ob1 + l*128, oW2_t, ob2 + l*128, Xl, nullptr, Xn, SVl, 1, N);
  }
  k_zero<<<(M+255)/256,256,0,stream>>>(outE, M);
  k_head_m<<<gHead,256,0,stream>>>(X0 + 3*NFE, WB3, WB3 + 8192, ab1, aW2, ab2, mol, outE, XB, N);
  for(int l=2;l>=0;l--){
    float* Xl  = X0 + (size_t)l*NFE;
    float* SVl = SV0 + (size_t)l*NFE;
    const u16* W1t = WB + l*WLSZ;
    const u16* W1b = W1t + 4096;
    const u16* W2r = W1t + 8192;
    const u16* W2t = W1t + 24576;
    const u16* d = WB2 + l*W2LSZ;
    const u16 *in2f_t = d, *in2f_d = d + 16384, *oW1_d = d + 49152, *oW2_d = d + 81920;
    k_gemmf<<<gRow,256,0,stream>>>(XB, oW2_d, nullptr, oW1_d, nullptr, nullptr, SVl, AGG, nullptr, 0, N);
    float* Hl;
    if(hsave){
      Hl = Hsv + (size_t)l*NFE;
    } else {
      Hl = H;
      k_gemmb<<<gRow,256,0,stream>>>(Xl, in2f_t, nullptr, nullptr, nullptr, H, nullptr, 0, N);
    }
    k_edge_bwd12<<<N,256,0,stream>>>(Hl, AGG, De, W1t, fb1 + l*128, W1b, W2r, W2t, fb2 + l*128, DBe, HB, EPM);
    k_gemmb<<<gRow,256,0,stream>>>(HB, in2f_d, nullptr, XB, nullptr, XB, nullptr, 0, N);
  }
  k_zero<<<(N*3+255)/256,256,0,stream>>>(G, N*3);
  k_zero<<<(M+255)/256,256,0,stream>>>((float*)maxnU, M);
  k_grad<<<gE,256,0,stream>>>(pos, Ii, Ij, De, DBe, G, E);
  k_norm<<<(N+255)/256,256,0,stream>>>(G, mol, maxnU, N);
  k_apply<<<(N+255)/256,256,0,stream>>>(G, mol, maxnU, outF, N);
}